// Round 1
// baseline (453.530 us; speedup 1.0000x reference)
//
#include <hip/hip_runtime.h>
#include <hip/hip_bf16.h>
#include <float.h>
#include <math.h>

#define N_NODES 50000
#define N_EDGES 500000
#define D 128
#define ED 10
#define EPS_PNA 1e-5f

typedef __hip_bfloat16 bf16;
typedef unsigned short ushort;
typedef unsigned int uint;
typedef __attribute__((ext_vector_type(8))) short short8;   // 8 bf16 (4 VGPRs)
typedef __attribute__((ext_vector_type(4))) float f32x4;    // MFMA C/D

__device__ __forceinline__ ushort f2bf(float f) {
    __hip_bfloat16 h = __float2bfloat16(f);
    return *reinterpret_cast<ushort*>(&h);
}
__device__ __forceinline__ float bf2f(ushort u) {
    return __uint_as_float(((uint)u) << 16);
}

// ---------------- K0: zero degree histogram ----------------
__global__ void k_init(int* __restrict__ cnt) {
    int i = blockIdx.x * blockDim.x + threadIdx.x;
    if (i < N_NODES) cnt[i] = 0;
}

// ---------------- K1: degree histogram ----------------
__global__ void k_hist(const int* __restrict__ ei, int* __restrict__ cnt) {
    int e = blockIdx.x * blockDim.x + threadIdx.x;
    if (e < N_EDGES) atomicAdd(&cnt[ei[N_EDGES + e]], 1);
}

// ---------------- K2: single-block prefix scan over degrees + avg_log ----------------
__global__ __launch_bounds__(1024) void k_scan(const int* __restrict__ cnt,
                                               int* __restrict__ rowstart,
                                               int* __restrict__ cursor,
                                               float* __restrict__ avglog) {
    const int t = threadIdx.x, lane = t & 63, wv = t >> 6;
    __shared__ int wtot[16], woff[16];
    __shared__ int btot_s;
    __shared__ float lred[16];
    int running = 0;
    float lsum = 0.f;
    for (int base = 0; base < N_NODES; base += 1024) {
        const int idx = base + t;
        int c = (idx < N_NODES) ? cnt[idx] : 0;
        if (idx < N_NODES) lsum += logf((float)c + 1.0f);
        int s = c;
        #pragma unroll
        for (int off = 1; off < 64; off <<= 1) {
            int v = __shfl_up(s, off, 64);
            if (lane >= off) s += v;
        }
        if (lane == 63) wtot[wv] = s;
        __syncthreads();
        if (t == 0) {
            int r = 0;
            #pragma unroll
            for (int i = 0; i < 16; ++i) { woff[i] = r; r += wtot[i]; }
            btot_s = r;
        }
        __syncthreads();
        if (idx < N_NODES) {
            const int excl = running + woff[wv] + (s - c);
            rowstart[idx] = excl;
            cursor[idx] = excl;
        }
        running += btot_s;
        __syncthreads();
    }
    if (t == 0) rowstart[N_NODES] = running;
    float v = lsum;
    for (int off = 32; off > 0; off >>= 1) v += __shfl_down(v, off, 64);
    if (lane == 0) lred[wv] = v;
    __syncthreads();
    if (t == 0) {
        float tt = 0.f;
        for (int i = 0; i < 16; ++i) tt += lred[i];
        avglog[0] = tt * (1.0f / (float)N_NODES);
    }
}

// ---------------- K3: bucket edges into CSR order (src,eid packed as int2) ----------------
__global__ void k_scatter(const int* __restrict__ ei, int* __restrict__ cursor,
                          int2* __restrict__ csr_se) {
    int e = blockIdx.x * blockDim.x + threadIdx.x;
    if (e < N_EDGES) {
        const int dst = ei[N_EDGES + e];
        const int pos = atomicAdd(&cursor[dst], 1);
        csr_se[pos] = make_int2(ei[e], e);
    }
}

// ---------------- K4: fold edge-encoder through W3 ----------------
__global__ __launch_bounds__(128) void k_small(const float* __restrict__ Wee,
                                               const float* __restrict__ bee,
                                               const float* __restrict__ Wpre,
                                               const float* __restrict__ bpre,
                                               float* __restrict__ W4,
                                               float* __restrict__ bp) {
    __shared__ float wee_s[ED * D];
    __shared__ float bee_s[D];
    const int t = threadIdx.x;
    for (int i = t; i < ED * D; i += 128) wee_s[i] = Wee[i];
    bee_s[t] = bee[t];
    __syncthreads();
    float acc[ED];
    #pragma unroll
    for (int r = 0; r < ED; ++r) acc[r] = 0.f;
    float bacc = 0.f;
    for (int k = 0; k < D; ++k) {
        const float w3 = Wpre[(size_t)(2 * D + k) * D + t];
        #pragma unroll
        for (int r = 0; r < ED; ++r) acc[r] += wee_s[r * D + k] * w3;
        bacc += bee_s[k] * w3;
    }
    #pragma unroll
    for (int r = 0; r < ED; ++r) W4[r * D + t] = acc[r];
    bp[t] = bpre[t] + bacc;
}

// ---------------- K5: transpose weight [K][128] fp32 -> [128][K] bf16 ----------------
__global__ void k_prep(const float* __restrict__ src, ushort* __restrict__ dst,
                       int K, int jobs) {
    int id = blockIdx.x * blockDim.x + threadIdx.x;
    if (id >= jobs) return;
    const int col = id & 127;
    const int k0 = (id >> 7) * 8;
    ushort tmp[8];
    #pragma unroll
    for (int r = 0; r < 8; ++r) tmp[r] = f2bf(src[(size_t)(k0 + r) * 128 + col]);
    *(uint4*)(dst + (size_t)col * K + k0) = *(uint4*)tmp;
}

// ---------------- K6: fold Wpost@Wlin -> Wc, routed into transposed bf16 layouts ----------------
// Wc rows: [0,128) -> WxT rows 256..383 (Y0 weights); [128,640) -> WaT slice0 (identity-agg);
// [640,1152) -> WaT slice1 (r1-agg); [1152,1664) -> WaT slice2 (r2-agg).
// Also b_comb = bpost@Wlin + blin.
__global__ __launch_bounds__(256) void k_fold(
    const float* __restrict__ Wpost, const float* __restrict__ bpost,
    const float* __restrict__ Wlin, const float* __restrict__ blin,
    ushort* __restrict__ WxT,     // [384][128]
    ushort* __restrict__ WaT,     // [384][512]
    float* __restrict__ b_comb)
{
    __shared__ float Wl[128 * 128];   // 64 KB fp32
    const int t = threadIdx.x;
    for (int i = t; i < 128 * 128 / 4; i += 256)
        ((float4*)Wl)[i] = ((const float4*)Wlin)[i];
    __syncthreads();
    const int j = t & 127, rp = t >> 7;
    const int kr0 = blockIdx.x * 16 + rp * 8;
    for (int r = 0; r < 8; ++r) {
        const int kr = kr0 + r;
        const float* wrow = Wpost + (size_t)kr * 128;
        float acc = 0.f;
        #pragma unroll 8
        for (int m = 0; m < 128; ++m) acc += wrow[m] * Wl[m * 128 + j];
        const ushort v = f2bf(acc);
        if (kr < 128)       WxT[(256 + j) * 128 + kr] = v;
        else if (kr < 640)  WaT[(size_t)j * 512 + (kr - 128)] = v;
        else if (kr < 1152) WaT[(size_t)(128 + j) * 512 + (kr - 640)] = v;
        else                WaT[(size_t)(256 + j) * 512 + (kr - 1152)] = v;
    }
    if (blockIdx.x == 0 && t < 128) {
        float acc = 0.f;
        #pragma unroll 8
        for (int m = 0; m < 128; ++m) acc += bpost[m] * Wl[m * 128 + t];
        b_comb[t] = acc + blin[t];
    }
}

// ---------------- K7: MFMA x-GEMMs: slice 0 -> Y1b=x@W1, 1 -> Y2b=x@W2, 2 -> Y0b=x@Wc0+b_comb ----------------
__global__ __launch_bounds__(256) void k_xgemm(
    const float* __restrict__ x, const ushort* __restrict__ WxT,
    const float* __restrict__ b_comb,
    ushort* __restrict__ Y1b, ushort* __restrict__ Y2b, ushort* __restrict__ Y0b)
{
    __shared__ __align__(16) ushort Alds[128 * 136];
    __shared__ __align__(16) ushort Hlds[128 * 136];
    const int t = threadIdx.x;
    const int nb = blockIdx.x * 128;
    const int sy = blockIdx.y;

    #pragma unroll
    for (int g = 0; g < 8; ++g) {
        const int idx = t + g * 256;
        const int row = idx >> 4, kk = (idx & 15) * 8;
        *(uint4*)&Alds[row * 136 + kk] =
            *(const uint4*)(WxT + ((size_t)sy * 128 + row) * 128 + kk);
        const int node = nb + row;
        uint4 v = make_uint4(0u, 0u, 0u, 0u);
        if (node < N_NODES) {
            const float4 f0 = *(const float4*)(x + (size_t)node * 128 + kk);
            const float4 f1 = *(const float4*)(x + (size_t)node * 128 + kk + 4);
            __hip_bfloat162 p0 = __float22bfloat162_rn(make_float2(f0.x, f0.y));
            __hip_bfloat162 p1 = __float22bfloat162_rn(make_float2(f0.z, f0.w));
            __hip_bfloat162 p2 = __float22bfloat162_rn(make_float2(f1.x, f1.y));
            __hip_bfloat162 p3 = __float22bfloat162_rn(make_float2(f1.z, f1.w));
            v.x = *(uint*)&p0; v.y = *(uint*)&p1; v.z = *(uint*)&p2; v.w = *(uint*)&p3;
        }
        *(uint4*)&Hlds[row * 136 + kk] = v;
    }
    __syncthreads();

    const int w = t >> 6, l = t & 63;
    const int wr = w >> 1, wc = w & 1;
    const int quad = l >> 4, lr = l & 15;

    f32x4 acc[4][4];
    #pragma unroll
    for (int i = 0; i < 4; ++i)
        #pragma unroll
        for (int j = 0; j < 4; ++j) acc[i][j] = (f32x4){0.f, 0.f, 0.f, 0.f};

    #pragma unroll
    for (int s = 0; s < 4; ++s) {
        short8 av[4], bv[4];
        #pragma unroll
        for (int i = 0; i < 4; ++i)
            av[i] = *(const short8*)&Alds[(wr * 64 + i * 16 + lr) * 136 + s * 32 + quad * 8];
        #pragma unroll
        for (int j = 0; j < 4; ++j)
            bv[j] = *(const short8*)&Hlds[(wc * 64 + j * 16 + lr) * 136 + s * 32 + quad * 8];
        #pragma unroll
        for (int i = 0; i < 4; ++i)
            #pragma unroll
            for (int j = 0; j < 4; ++j)
                acc[i][j] = __builtin_amdgcn_mfma_f32_16x16x32_bf16(av[i], bv[j], acc[i][j], 0, 0, 0);
    }

    ushort* dst = (sy == 0) ? Y1b : (sy == 1) ? Y2b : Y0b;
    #pragma unroll
    for (int i = 0; i < 4; ++i) {
        const int col = wr * 64 + i * 16 + quad * 4;
        float b0 = 0.f, b1 = 0.f, b2 = 0.f, b3 = 0.f;
        if (sy == 2) {
            b0 = b_comb[col]; b1 = b_comb[col + 1];
            b2 = b_comb[col + 2]; b3 = b_comb[col + 3];
        }
        #pragma unroll
        for (int j = 0; j < 4; ++j) {
            const int node = nb + wc * 64 + j * 16 + lr;
            if (node < N_NODES) {
                const f32x4 v = acc[i][j];
                ushort pk[4];
                pk[0] = f2bf(v.x + b0); pk[1] = f2bf(v.y + b1);
                pk[2] = f2bf(v.z + b2); pk[3] = f2bf(v.w + b3);
                *(uint2*)(dst + (size_t)node * 128 + col) = *(uint2*)pk;
            }
        }
    }
}

// ---------------- K8: CSR pull aggregation -> agg bf16 [N][512] ----------------
// One node per wave; W4 register-cached (20 VGPR/lane, no LDS); edges processed
// in batches of 4 with all loads issued before the 4 compute bodies (4x ILP on
// the gather latency chain). Tail masked by wave-uniform branches (no divergence).
__global__ __launch_bounds__(256) void k_pull(
    const float* __restrict__ eattr, const float* __restrict__ W4,
    const float* __restrict__ bp, const ushort* __restrict__ Y1b,
    const ushort* __restrict__ Y2b,
    const int* __restrict__ rowstart,
    const int2* __restrict__ csr_se,
    ushort* __restrict__ aggB)
{
    const int t = threadIdx.x;
    const int wv = t >> 6, l = t & 63;
    const int n = blockIdx.x * 4 + wv;

    // per-lane W4 slice: channels (2l, 2l+1); rows 0..9 -> 10 float2 = 20 VGPRs.
    // Coalesced global loads (512B/wave-instr), L2-hot after first block.
    float2 w4[ED];
    #pragma unroll
    for (int r = 0; r < ED; ++r)
        w4[r] = *(const float2*)(W4 + r * D + 2 * l);

    const int r0 = rowstart[n], r1 = rowstart[n + 1];
    const int d = r1 - r0;

    float s0 = 0.f, s1 = 0.f, ss0 = 0.f, ss1 = 0.f;
    float mx0 = -FLT_MAX, mx1 = -FLT_MAX, mn0 = FLT_MAX, mn1 = FLT_MAX;

    const __hip_bfloat162* Y2p = (const __hip_bfloat162*)Y2b;

    const int nbatch = (d + 3) >> 2;
    for (int b = 0; b < nbatch; ++b) {
        const int i0 = r0 + b * 4;
        // phase 1: index loads (independent)
        int2 se[4];
        #pragma unroll
        for (int k = 0; k < 4; ++k) {
            int idx = i0 + k;
            idx = (idx < r1) ? idx : (r1 - 1);   // clamp; d>0 guaranteed here
            se[k] = csr_se[idx];
        }
        // phase 2: dependent gathers, all in flight together
        __hip_bfloat162 yv[4];
        #pragma unroll
        for (int k = 0; k < 4; ++k)
            yv[k] = Y2p[(size_t)se[k].x * 64 + l];
        float2 ea[4][5];
        #pragma unroll
        for (int k = 0; k < 4; ++k) {
            const float2* e2 = (const float2*)(eattr + (size_t)se[k].y * ED);
            #pragma unroll
            for (int r = 0; r < 5; ++r) ea[k][r] = e2[r];
        }
        // phase 3: compute (guards are wave-uniform -> s_cbranch, no divergence)
        #pragma unroll
        for (int k = 0; k < 4; ++k) {
            if (i0 + k < r1) {
                const float2 y2 = __bfloat1622float2(yv[k]);
                float q0 = 0.f, q1 = 0.f;
                #pragma unroll
                for (int r = 0; r < 5; ++r) {
                    const float2 a = ea[k][r];
                    const float2 wA = w4[2 * r];
                    const float2 wB = w4[2 * r + 1];
                    q0 += a.x * wA.x + a.y * wB.x;
                    q1 += a.x * wA.y + a.y * wB.y;
                }
                const float z0 = y2.x + q0, z1 = y2.y + q1;
                s0 += z0; s1 += z1;
                ss0 += z0 * z0; ss1 += z1 * z1;
                mx0 = fmaxf(mx0, z0); mx1 = fmaxf(mx1, z1);
                mn0 = fminf(mn0, z0); mn1 = fminf(mn1, z1);
            }
        }
    }

    const float2 bpw = ((const float2*)bp)[l];
    const float2 y1 = __bfloat1622float2(((const __hip_bfloat162*)Y1b)[(size_t)n * 64 + l]);
    float mean0, mean1, vmx0, vmx1, vmn0, vmn1, st0, st1;
    if (d > 0) {
        const float inv = 1.f / (float)d;
        const float mz0 = s0 * inv, mz1 = s1 * inv;
        const float c0 = y1.x + bpw.x, c1 = y1.y + bpw.y;
        mean0 = mz0 + c0; mean1 = mz1 + c1;
        st0 = sqrtf(fmaxf(ss0 * inv - mz0 * mz0, 0.f) + EPS_PNA);
        st1 = sqrtf(fmaxf(ss1 * inv - mz1 * mz1, 0.f) + EPS_PNA);
        vmx0 = mx0 + c0; vmx1 = mx1 + c1;
        vmn0 = mn0 + c0; vmn1 = mn1 + c1;
    } else {
        mean0 = mean1 = 0.f;
        vmx0 = vmx1 = vmn0 = vmn1 = 0.f;
        st0 = st1 = sqrtf(EPS_PNA);
    }
    __hip_bfloat162* aggv = (__hip_bfloat162*)aggB;
    const size_t b0 = (size_t)n * 256;
    aggv[b0 + l]       = __float22bfloat162_rn(make_float2(mean0, mean1));
    aggv[b0 + 64 + l]  = __float22bfloat162_rn(make_float2(vmx0, vmx1));
    aggv[b0 + 128 + l] = __float22bfloat162_rn(make_float2(vmn0, vmn1));
    aggv[b0 + 192 + l] = __float22bfloat162_rn(make_float2(st0, st1));
}

// ---------------- K9: MFMA agg-GEMM with 3 in-register slices ----------------
// out[n][col] = Y0b[n][col] + G0 + r1[n]*G1 + r2[n]*G2,  G_s = agg @ Wc_s (K=512).
// 64 nodes/block, 128 cols, slice loop inside; grid 782.
__global__ __launch_bounds__(256) void k_agg(
    const ushort* __restrict__ aggB,  // [N][512] bf16
    const ushort* __restrict__ WaT,   // [384][512] bf16
    const ushort* __restrict__ Y0b,   // [N][128] bf16
    const int* __restrict__ cnt, const float* __restrict__ avglog,
    float* __restrict__ out)
{
    __shared__ __align__(16) ushort Alds[128 * 72];
    __shared__ __align__(16) ushort Hlds[64 * 72];
    __shared__ float r1s[64], r2s[64];

    const int t = threadIdx.x;
    const int nb = blockIdx.x * 64;
    if (t < 64) {
        const int node = nb + t;
        float deg = 1.f;
        if (node < N_NODES) deg = fmaxf((float)cnt[node], 1.f);
        const float sl = logf(deg + 1.f);
        const float al = avglog[0];
        r1s[t] = sl / al;
        r2s[t] = al / sl;
    }

    const int w = t >> 6, l = t & 63;
    const int wr = w >> 1, wc = w & 1;   // wr: col half (64), wc: node half (32)
    const int quad = l >> 4, lr = l & 15;

    f32x4 comb[4][2];
    #pragma unroll
    for (int i = 0; i < 4; ++i)
        #pragma unroll
        for (int j = 0; j < 2; ++j) comb[i][j] = (f32x4){0.f, 0.f, 0.f, 0.f};

    for (int sl = 0; sl < 3; ++sl) {
        f32x4 acc[4][2];
        #pragma unroll
        for (int i = 0; i < 4; ++i)
            #pragma unroll
            for (int j = 0; j < 2; ++j) acc[i][j] = (f32x4){0.f, 0.f, 0.f, 0.f};

        for (int kc = 0; kc < 8; ++kc) {
            const int k0 = kc * 64;
            __syncthreads();
            #pragma unroll
            for (int g = 0; g < 4; ++g) {      // A: 128 rows x 64 k
                const int idx = t + g * 256;
                const int row = idx >> 3, kk = (idx & 7) * 8;
                *(uint4*)&Alds[row * 72 + kk] =
                    *(const uint4*)(WaT + ((size_t)(sl * 128 + row)) * 512 + k0 + kk);
            }
            #pragma unroll
            for (int g = 0; g < 2; ++g) {      // H: 64 rows x 64 k
                const int idx = t + g * 256;
                const int row = idx >> 3, kk = (idx & 7) * 8;
                const int node = nb + row;
                uint4 v = make_uint4(0u, 0u, 0u, 0u);
                if (node < N_NODES)
                    v = *(const uint4*)(aggB + (size_t)node * 512 + k0 + kk);
                *(uint4*)&Hlds[row * 72 + kk] = v;
            }
            __syncthreads();
            #pragma unroll
            for (int s = 0; s < 2; ++s) {
                short8 av[4], bv[2];
                #pragma unroll
                for (int i = 0; i < 4; ++i)
                    av[i] = *(const short8*)&Alds[(wr * 64 + i * 16 + lr) * 72 + s * 32 + quad * 8];
                #pragma unroll
                for (int j = 0; j < 2; ++j)
                    bv[j] = *(const short8*)&Hlds[(wc * 32 + j * 16 + lr) * 72 + s * 32 + quad * 8];
                #pragma unroll
                for (int i = 0; i < 4; ++i)
                    #pragma unroll
                    for (int j = 0; j < 2; ++j)
                        acc[i][j] = __builtin_amdgcn_mfma_f32_16x16x32_bf16(av[i], bv[j], acc[i][j], 0, 0, 0);
            }
        }
        // fold slice into comb with per-node scale
        #pragma unroll
        for (int j = 0; j < 2; ++j) {
            const int nl = wc * 32 + j * 16 + lr;
            const float r = (sl == 0) ? 1.f : (sl == 1) ? r1s[nl] : r2s[nl];
            #pragma unroll
            for (int i = 0; i < 4; ++i) {
                comb[i][j].x += r * acc[i][j].x;
                comb[i][j].y += r * acc[i][j].y;
                comb[i][j].z += r * acc[i][j].z;
                comb[i][j].w += r * acc[i][j].w;
            }
        }
    }

    #pragma unroll
    for (int i = 0; i < 4; ++i) {
        const int col = wr * 64 + i * 16 + quad * 4;
        #pragma unroll
        for (int j = 0; j < 2; ++j) {
            const int node = nb + wc * 32 + j * 16 + lr;
            if (node < N_NODES) {
                const uint2 y0 = *(const uint2*)(Y0b + (size_t)node * 128 + col);
                const ushort* yp = (const ushort*)&y0;
                const f32x4 v = comb[i][j];
                *(float4*)(out + (size_t)node * 128 + col) =
                    make_float4(v.x + bf2f(yp[0]), v.y + bf2f(yp[1]),
                                v.z + bf2f(yp[2]), v.w + bf2f(yp[3]));
            }
        }
    }
}

extern "C" void kernel_launch(void* const* d_in, const int* in_sizes, int n_in,
                              void* d_out, int out_size, void* d_ws, size_t ws_size,
                              hipStream_t stream) {
    const float* x     = (const float*)d_in[0];
    const float* eattr = (const float*)d_in[1];
    const float* Wee   = (const float*)d_in[2];
    const float* bee   = (const float*)d_in[3];
    const float* Wpre  = (const float*)d_in[4];
    const float* bpre  = (const float*)d_in[5];
    const float* Wpost = (const float*)d_in[6];
    const float* bpost = (const float*)d_in[7];
    const float* Wlin  = (const float*)d_in[8];
    const float* blin  = (const float*)d_in[9];
    const int*   ei    = (const int*)d_in[10];
    float* out = (float*)d_out;

    // workspace layout (~94.5 MB; ws_size >= 102.6 MB proven previously)
    ushort* aggB = (ushort*)d_ws;                         // N*512 bf16 (51.2 MB)
    ushort* Y1b  = aggB + (size_t)N_NODES * 512;          // N*128 bf16
    ushort* Y2b  = Y1b  + (size_t)N_NODES * 128;          // N*128 bf16
    ushort* Y0b  = Y2b  + (size_t)N_NODES * 128;          // N*128 bf16
    ushort* WxT  = Y0b  + (size_t)N_NODES * 128;          // 384*128 bf16
    ushort* WaT  = WxT + 384 * 128;                       // 384*512 bf16
    float*  W4   = (float*)(WaT + 384 * 512);             // ED*D fp32
    float*  bp   = W4 + ED * D;                           // 128
    float*  b_comb = bp + D;                              // 128
    float*  avglog = b_comb + D;                          // 1 (+3 pad)
    int*   cnt      = (int*)(avglog + 4);
    int*   rowstart = cnt + N_NODES;
    int*   cursor   = rowstart + N_NODES + 2;
    int2*  csr_se   = (int2*)(cursor + N_NODES + 2);      // +2 pad keeps 8B align

    k_init<<<(N_NODES + 255) / 256, 256, 0, stream>>>(cnt);
    k_hist<<<(N_EDGES + 255) / 256, 256, 0, stream>>>(ei, cnt);
    k_scan<<<1, 1024, 0, stream>>>(cnt, rowstart, cursor, avglog);
    k_scatter<<<(N_EDGES + 255) / 256, 256, 0, stream>>>(ei, cursor, csr_se);
    k_small<<<1, 128, 0, stream>>>(Wee, bee, Wpre, bpre, W4, bp);
    k_prep<<<8, 256, 0, stream>>>(Wpre, WxT, 128, 2048);                    // W1^T
    k_prep<<<8, 256, 0, stream>>>(Wpre + 128 * 128, WxT + 128 * 128, 128, 2048); // W2^T
    k_fold<<<104, 256, 0, stream>>>(Wpost, bpost, Wlin, blin, WxT, WaT, b_comb);
    k_xgemm<<<dim3((N_NODES + 127) / 128, 3), 256, 0, stream>>>(x, WxT, b_comb,
                                                                Y1b, Y2b, Y0b);
    k_pull<<<N_NODES / 4, 256, 0, stream>>>(eattr, W4, bp, Y1b, Y2b,
                                            rowstart, csr_se, aggB);
    k_agg<<<(N_NODES + 63) / 64, 256, 0, stream>>>(aggB, WaT, Y0b, cnt, avglog, out);
}

// Round 2
// 446.781 us; speedup vs baseline: 1.0151x; 1.0151x over previous
//
#include <hip/hip_runtime.h>
#include <hip/hip_bf16.h>
#include <float.h>
#include <math.h>

#define N_NODES 50000
#define N_EDGES 500000
#define D 128
#define ED 10
#define EPS_PNA 1e-5f

typedef __hip_bfloat16 bf16;
typedef unsigned short ushort;
typedef unsigned int uint;
typedef __attribute__((ext_vector_type(8))) short short8;   // 8 bf16 (4 VGPRs)
typedef __attribute__((ext_vector_type(4))) float f32x4;    // MFMA C/D

__device__ __forceinline__ ushort f2bf(float f) {
    __hip_bfloat16 h = __float2bfloat16(f);
    return *reinterpret_cast<ushort*>(&h);
}
__device__ __forceinline__ float bf2f(ushort u) {
    return __uint_as_float(((uint)u) << 16);
}

// ---------------- K0: zero degree histogram ----------------
__global__ void k_init(int* __restrict__ cnt) {
    int i = blockIdx.x * blockDim.x + threadIdx.x;
    if (i < N_NODES) cnt[i] = 0;
}

// ---------------- K1: degree histogram ----------------
__global__ void k_hist(const int* __restrict__ ei, int* __restrict__ cnt) {
    int e = blockIdx.x * blockDim.x + threadIdx.x;
    if (e < N_EDGES) atomicAdd(&cnt[ei[N_EDGES + e]], 1);
}

// ---------------- K2: single-block prefix scan over degrees + avg_log ----------------
__global__ __launch_bounds__(1024) void k_scan(const int* __restrict__ cnt,
                                               int* __restrict__ rowstart,
                                               int* __restrict__ cursor,
                                               float* __restrict__ avglog) {
    const int t = threadIdx.x, lane = t & 63, wv = t >> 6;
    __shared__ int wtot[16], woff[16];
    __shared__ int btot_s;
    __shared__ float lred[16];
    int running = 0;
    float lsum = 0.f;
    for (int base = 0; base < N_NODES; base += 1024) {
        const int idx = base + t;
        int c = (idx < N_NODES) ? cnt[idx] : 0;
        if (idx < N_NODES) lsum += logf((float)c + 1.0f);
        int s = c;
        #pragma unroll
        for (int off = 1; off < 64; off <<= 1) {
            int v = __shfl_up(s, off, 64);
            if (lane >= off) s += v;
        }
        if (lane == 63) wtot[wv] = s;
        __syncthreads();
        if (t == 0) {
            int r = 0;
            #pragma unroll
            for (int i = 0; i < 16; ++i) { woff[i] = r; r += wtot[i]; }
            btot_s = r;
        }
        __syncthreads();
        if (idx < N_NODES) {
            const int excl = running + woff[wv] + (s - c);
            rowstart[idx] = excl;
            cursor[idx] = excl;
        }
        running += btot_s;
        __syncthreads();
    }
    if (t == 0) rowstart[N_NODES] = running;
    float v = lsum;
    for (int off = 32; off > 0; off >>= 1) v += __shfl_down(v, off, 64);
    if (lane == 0) lred[wv] = v;
    __syncthreads();
    if (t == 0) {
        float tt = 0.f;
        for (int i = 0; i < 16; ++i) tt += lred[i];
        avglog[0] = tt * (1.0f / (float)N_NODES);
    }
}

// ---------------- K3: bucket edges into CSR order (src,eid packed as int2) ----------------
__global__ void k_scatter(const int* __restrict__ ei, int* __restrict__ cursor,
                          int2* __restrict__ csr_se) {
    int e = blockIdx.x * blockDim.x + threadIdx.x;
    if (e < N_EDGES) {
        const int dst = ei[N_EDGES + e];
        const int pos = atomicAdd(&cursor[dst], 1);
        csr_se[pos] = make_int2(ei[e], e);
    }
}

// ---------------- K4: fold edge-encoder through W3 ----------------
__global__ __launch_bounds__(128) void k_small(const float* __restrict__ Wee,
                                               const float* __restrict__ bee,
                                               const float* __restrict__ Wpre,
                                               const float* __restrict__ bpre,
                                               float* __restrict__ W4,
                                               float* __restrict__ bp) {
    __shared__ float wee_s[ED * D];
    __shared__ float bee_s[D];
    const int t = threadIdx.x;
    for (int i = t; i < ED * D; i += 128) wee_s[i] = Wee[i];
    bee_s[t] = bee[t];
    __syncthreads();
    float acc[ED];
    #pragma unroll
    for (int r = 0; r < ED; ++r) acc[r] = 0.f;
    float bacc = 0.f;
    for (int k = 0; k < D; ++k) {
        const float w3 = Wpre[(size_t)(2 * D + k) * D + t];
        #pragma unroll
        for (int r = 0; r < ED; ++r) acc[r] += wee_s[r * D + k] * w3;
        bacc += bee_s[k] * w3;
    }
    #pragma unroll
    for (int r = 0; r < ED; ++r) W4[r * D + t] = acc[r];
    bp[t] = bpre[t] + bacc;
}

// ---------------- K5: transpose weight [K][128] fp32 -> [128][K] bf16 ----------------
__global__ void k_prep(const float* __restrict__ src, ushort* __restrict__ dst,
                       int K, int jobs) {
    int id = blockIdx.x * blockDim.x + threadIdx.x;
    if (id >= jobs) return;
    const int col = id & 127;
    const int k0 = (id >> 7) * 8;
    ushort tmp[8];
    #pragma unroll
    for (int r = 0; r < 8; ++r) tmp[r] = f2bf(src[(size_t)(k0 + r) * 128 + col]);
    *(uint4*)(dst + (size_t)col * K + k0) = *(uint4*)tmp;
}

// ---------------- K6: fold Wpost@Wlin -> Wc, routed into transposed bf16 layouts ----------------
// Wc rows: [0,128) -> WxT rows 256..383 (Y0 weights); [128,640) -> WaT slice0 (identity-agg);
// [640,1152) -> WaT slice1 (r1-agg); [1152,1664) -> WaT slice2 (r2-agg).
// Also b_comb = bpost@Wlin + blin.
__global__ __launch_bounds__(256) void k_fold(
    const float* __restrict__ Wpost, const float* __restrict__ bpost,
    const float* __restrict__ Wlin, const float* __restrict__ blin,
    ushort* __restrict__ WxT,     // [384][128]
    ushort* __restrict__ WaT,     // [384][512]
    float* __restrict__ b_comb)
{
    __shared__ float Wl[128 * 128];   // 64 KB fp32
    const int t = threadIdx.x;
    for (int i = t; i < 128 * 128 / 4; i += 256)
        ((float4*)Wl)[i] = ((const float4*)Wlin)[i];
    __syncthreads();
    const int j = t & 127, rp = t >> 7;
    const int kr0 = blockIdx.x * 16 + rp * 8;
    for (int r = 0; r < 8; ++r) {
        const int kr = kr0 + r;
        const float* wrow = Wpost + (size_t)kr * 128;
        float acc = 0.f;
        #pragma unroll 8
        for (int m = 0; m < 128; ++m) acc += wrow[m] * Wl[m * 128 + j];
        const ushort v = f2bf(acc);
        if (kr < 128)       WxT[(256 + j) * 128 + kr] = v;
        else if (kr < 640)  WaT[(size_t)j * 512 + (kr - 128)] = v;
        else if (kr < 1152) WaT[(size_t)(128 + j) * 512 + (kr - 640)] = v;
        else                WaT[(size_t)(256 + j) * 512 + (kr - 1152)] = v;
    }
    if (blockIdx.x == 0 && t < 128) {
        float acc = 0.f;
        #pragma unroll 8
        for (int m = 0; m < 128; ++m) acc += bpost[m] * Wl[m * 128 + t];
        b_comb[t] = acc + blin[t];
    }
}

// ---------------- K7: MFMA x-GEMMs: slice 0 -> Y1b=x@W1, 1 -> Y2b=x@W2, 2 -> Y0b=x@Wc0+b_comb ----------------
__global__ __launch_bounds__(256) void k_xgemm(
    const float* __restrict__ x, const ushort* __restrict__ WxT,
    const float* __restrict__ b_comb,
    ushort* __restrict__ Y1b, ushort* __restrict__ Y2b, ushort* __restrict__ Y0b)
{
    __shared__ __align__(16) ushort Alds[128 * 136];
    __shared__ __align__(16) ushort Hlds[128 * 136];
    const int t = threadIdx.x;
    const int nb = blockIdx.x * 128;
    const int sy = blockIdx.y;

    #pragma unroll
    for (int g = 0; g < 8; ++g) {
        const int idx = t + g * 256;
        const int row = idx >> 4, kk = (idx & 15) * 8;
        *(uint4*)&Alds[row * 136 + kk] =
            *(const uint4*)(WxT + ((size_t)sy * 128 + row) * 128 + kk);
        const int node = nb + row;
        uint4 v = make_uint4(0u, 0u, 0u, 0u);
        if (node < N_NODES) {
            const float4 f0 = *(const float4*)(x + (size_t)node * 128 + kk);
            const float4 f1 = *(const float4*)(x + (size_t)node * 128 + kk + 4);
            __hip_bfloat162 p0 = __float22bfloat162_rn(make_float2(f0.x, f0.y));
            __hip_bfloat162 p1 = __float22bfloat162_rn(make_float2(f0.z, f0.w));
            __hip_bfloat162 p2 = __float22bfloat162_rn(make_float2(f1.x, f1.y));
            __hip_bfloat162 p3 = __float22bfloat162_rn(make_float2(f1.z, f1.w));
            v.x = *(uint*)&p0; v.y = *(uint*)&p1; v.z = *(uint*)&p2; v.w = *(uint*)&p3;
        }
        *(uint4*)&Hlds[row * 136 + kk] = v;
    }
    __syncthreads();

    const int w = t >> 6, l = t & 63;
    const int wr = w >> 1, wc = w & 1;
    const int quad = l >> 4, lr = l & 15;

    f32x4 acc[4][4];
    #pragma unroll
    for (int i = 0; i < 4; ++i)
        #pragma unroll
        for (int j = 0; j < 4; ++j) acc[i][j] = (f32x4){0.f, 0.f, 0.f, 0.f};

    #pragma unroll
    for (int s = 0; s < 4; ++s) {
        short8 av[4], bv[4];
        #pragma unroll
        for (int i = 0; i < 4; ++i)
            av[i] = *(const short8*)&Alds[(wr * 64 + i * 16 + lr) * 136 + s * 32 + quad * 8];
        #pragma unroll
        for (int j = 0; j < 4; ++j)
            bv[j] = *(const short8*)&Hlds[(wc * 64 + j * 16 + lr) * 136 + s * 32 + quad * 8];
        #pragma unroll
        for (int i = 0; i < 4; ++i)
            #pragma unroll
            for (int j = 0; j < 4; ++j)
                acc[i][j] = __builtin_amdgcn_mfma_f32_16x16x32_bf16(av[i], bv[j], acc[i][j], 0, 0, 0);
    }

    ushort* dst = (sy == 0) ? Y1b : (sy == 1) ? Y2b : Y0b;
    #pragma unroll
    for (int i = 0; i < 4; ++i) {
        const int col = wr * 64 + i * 16 + quad * 4;
        float b0 = 0.f, b1 = 0.f, b2 = 0.f, b3 = 0.f;
        if (sy == 2) {
            b0 = b_comb[col]; b1 = b_comb[col + 1];
            b2 = b_comb[col + 2]; b3 = b_comb[col + 3];
        }
        #pragma unroll
        for (int j = 0; j < 4; ++j) {
            const int node = nb + wc * 64 + j * 16 + lr;
            if (node < N_NODES) {
                const f32x4 v = acc[i][j];
                ushort pk[4];
                pk[0] = f2bf(v.x + b0); pk[1] = f2bf(v.y + b1);
                pk[2] = f2bf(v.z + b2); pk[3] = f2bf(v.w + b3);
                *(uint2*)(dst + (size_t)node * 128 + col) = *(uint2*)pk;
            }
        }
    }
}

// ---------------- K8: CSR pull aggregation -> agg bf16 [N][512] ----------------
// 2 nodes per block, 2 waves per node (contiguous halves of the edge list).
// Round-0 proven serial body per wave (LDS W4, simple loop); odd wave dumps
// partials to LDS, even wave merges + finalizes. Halves the per-wave dependent
// gather chain (avg 10 -> 5 edges).
__global__ __launch_bounds__(256) void k_pull(
    const float* __restrict__ eattr, const float* __restrict__ W4,
    const float* __restrict__ bp, const ushort* __restrict__ Y1b,
    const ushort* __restrict__ Y2b,
    const int* __restrict__ rowstart,
    const int2* __restrict__ csr_se,
    ushort* __restrict__ aggB)
{
    __shared__ float2 w4s[ED][64];
    __shared__ __align__(16) float red[2][64][8];   // odd-wave partials, 4 KB
    const int t = threadIdx.x;
    for (int i = t; i < ED * 64; i += 256)
        w4s[i >> 6][i & 63] = ((const float2*)W4)[i];

    const int wv = t >> 6, l = t & 63;
    const int p = wv >> 1;          // node slot within block
    const int half = wv & 1;        // which half of the edge list
    const int n = blockIdx.x * 2 + p;

    const int r0 = rowstart[n], r1 = rowstart[n + 1];
    const int d = r1 - r0;
    const int h0 = (d + 1) >> 1;                    // even wave takes ceil(d/2)
    const int ib = half ? (r0 + h0) : r0;
    const int ie = half ? r1 : (r0 + h0);

    __syncthreads();                                // w4s ready

    float s0 = 0.f, s1 = 0.f, ss0 = 0.f, ss1 = 0.f;
    float mx0 = -FLT_MAX, mx1 = -FLT_MAX, mn0 = FLT_MAX, mn1 = FLT_MAX;
    const __hip_bfloat162* Y2p = (const __hip_bfloat162*)Y2b;

    for (int i = ib; i < ie; ++i) {
        const int2 se = csr_se[i];
        const float2 y2 = __bfloat1622float2(Y2p[(size_t)se.x * 64 + l]);
        const float2* ea2 = (const float2*)(eattr + (size_t)se.y * ED);
        float q0 = 0.f, q1 = 0.f;
        #pragma unroll
        for (int r = 0; r < 5; ++r) {
            const float2 a = ea2[r];
            const float2 wA = w4s[2 * r][l];
            const float2 wB = w4s[2 * r + 1][l];
            q0 += a.x * wA.x + a.y * wB.x;
            q1 += a.x * wA.y + a.y * wB.y;
        }
        const float z0 = y2.x + q0, z1 = y2.y + q1;
        s0 += z0; s1 += z1;
        ss0 += z0 * z0; ss1 += z1 * z1;
        mx0 = fmaxf(mx0, z0); mx1 = fmaxf(mx1, z1);
        mn0 = fminf(mn0, z0); mn1 = fminf(mn1, z1);
    }

    if (half) {
        float* rp = &red[p][l][0];
        *(float4*)(rp)     = make_float4(s0, s1, ss0, ss1);
        *(float4*)(rp + 4) = make_float4(mx0, mx1, mn0, mn1);
    }
    __syncthreads();
    if (half) return;

    {
        const float* rp = &red[p][l][0];
        const float4 pa = *(const float4*)(rp);
        const float4 pb = *(const float4*)(rp + 4);
        s0 += pa.x; s1 += pa.y; ss0 += pa.z; ss1 += pa.w;
        mx0 = fmaxf(mx0, pb.x); mx1 = fmaxf(mx1, pb.y);
        mn0 = fminf(mn0, pb.z); mn1 = fminf(mn1, pb.w);
    }

    const float2 bpw = ((const float2*)bp)[l];
    const float2 y1 = __bfloat1622float2(((const __hip_bfloat162*)Y1b)[(size_t)n * 64 + l]);
    float mean0, mean1, vmx0, vmx1, vmn0, vmn1, st0, st1;
    if (d > 0) {
        const float inv = 1.f / (float)d;
        const float mz0 = s0 * inv, mz1 = s1 * inv;
        const float c0 = y1.x + bpw.x, c1 = y1.y + bpw.y;
        mean0 = mz0 + c0; mean1 = mz1 + c1;
        st0 = sqrtf(fmaxf(ss0 * inv - mz0 * mz0, 0.f) + EPS_PNA);
        st1 = sqrtf(fmaxf(ss1 * inv - mz1 * mz1, 0.f) + EPS_PNA);
        vmx0 = mx0 + c0; vmx1 = mx1 + c1;
        vmn0 = mn0 + c0; vmn1 = mn1 + c1;
    } else {
        mean0 = mean1 = 0.f;
        vmx0 = vmx1 = vmn0 = vmn1 = 0.f;
        st0 = st1 = sqrtf(EPS_PNA);
    }
    __hip_bfloat162* aggv = (__hip_bfloat162*)aggB;
    const size_t b0 = (size_t)n * 256;
    aggv[b0 + l]       = __float22bfloat162_rn(make_float2(mean0, mean1));
    aggv[b0 + 64 + l]  = __float22bfloat162_rn(make_float2(vmx0, vmx1));
    aggv[b0 + 128 + l] = __float22bfloat162_rn(make_float2(vmn0, vmn1));
    aggv[b0 + 192 + l] = __float22bfloat162_rn(make_float2(st0, st1));
}

// ---------------- K9: MFMA agg-GEMM with 3 in-register slices ----------------
// out[n][col] = Y0b[n][col] + G0 + r1[n]*G1 + r2[n]*G2,  G_s = agg @ Wc_s (K=512).
// 64 nodes/block, 128 cols, slice loop inside; grid 782.
__global__ __launch_bounds__(256) void k_agg(
    const ushort* __restrict__ aggB,  // [N][512] bf16
    const ushort* __restrict__ WaT,   // [384][512] bf16
    const ushort* __restrict__ Y0b,   // [N][128] bf16
    const int* __restrict__ cnt, const float* __restrict__ avglog,
    float* __restrict__ out)
{
    __shared__ __align__(16) ushort Alds[128 * 72];
    __shared__ __align__(16) ushort Hlds[64 * 72];
    __shared__ float r1s[64], r2s[64];

    const int t = threadIdx.x;
    const int nb = blockIdx.x * 64;
    if (t < 64) {
        const int node = nb + t;
        float deg = 1.f;
        if (node < N_NODES) deg = fmaxf((float)cnt[node], 1.f);
        const float sl = logf(deg + 1.f);
        const float al = avglog[0];
        r1s[t] = sl / al;
        r2s[t] = al / sl;
    }

    const int w = t >> 6, l = t & 63;
    const int wr = w >> 1, wc = w & 1;   // wr: col half (64), wc: node half (32)
    const int quad = l >> 4, lr = l & 15;

    f32x4 comb[4][2];
    #pragma unroll
    for (int i = 0; i < 4; ++i)
        #pragma unroll
        for (int j = 0; j < 2; ++j) comb[i][j] = (f32x4){0.f, 0.f, 0.f, 0.f};

    for (int sl = 0; sl < 3; ++sl) {
        f32x4 acc[4][2];
        #pragma unroll
        for (int i = 0; i < 4; ++i)
            #pragma unroll
            for (int j = 0; j < 2; ++j) acc[i][j] = (f32x4){0.f, 0.f, 0.f, 0.f};

        for (int kc = 0; kc < 8; ++kc) {
            const int k0 = kc * 64;
            __syncthreads();
            #pragma unroll
            for (int g = 0; g < 4; ++g) {      // A: 128 rows x 64 k
                const int idx = t + g * 256;
                const int row = idx >> 3, kk = (idx & 7) * 8;
                *(uint4*)&Alds[row * 72 + kk] =
                    *(const uint4*)(WaT + ((size_t)(sl * 128 + row)) * 512 + k0 + kk);
            }
            #pragma unroll
            for (int g = 0; g < 2; ++g) {      // H: 64 rows x 64 k
                const int idx = t + g * 256;
                const int row = idx >> 3, kk = (idx & 7) * 8;
                const int node = nb + row;
                uint4 v = make_uint4(0u, 0u, 0u, 0u);
                if (node < N_NODES)
                    v = *(const uint4*)(aggB + (size_t)node * 512 + k0 + kk);
                *(uint4*)&Hlds[row * 72 + kk] = v;
            }
            __syncthreads();
            #pragma unroll
            for (int s = 0; s < 2; ++s) {
                short8 av[4], bv[2];
                #pragma unroll
                for (int i = 0; i < 4; ++i)
                    av[i] = *(const short8*)&Alds[(wr * 64 + i * 16 + lr) * 72 + s * 32 + quad * 8];
                #pragma unroll
                for (int j = 0; j < 2; ++j)
                    bv[j] = *(const short8*)&Hlds[(wc * 32 + j * 16 + lr) * 72 + s * 32 + quad * 8];
                #pragma unroll
                for (int i = 0; i < 4; ++i)
                    #pragma unroll
                    for (int j = 0; j < 2; ++j)
                        acc[i][j] = __builtin_amdgcn_mfma_f32_16x16x32_bf16(av[i], bv[j], acc[i][j], 0, 0, 0);
            }
        }
        // fold slice into comb with per-node scale
        #pragma unroll
        for (int j = 0; j < 2; ++j) {
            const int nl = wc * 32 + j * 16 + lr;
            const float r = (sl == 0) ? 1.f : (sl == 1) ? r1s[nl] : r2s[nl];
            #pragma unroll
            for (int i = 0; i < 4; ++i) {
                comb[i][j].x += r * acc[i][j].x;
                comb[i][j].y += r * acc[i][j].y;
                comb[i][j].z += r * acc[i][j].z;
                comb[i][j].w += r * acc[i][j].w;
            }
        }
    }

    #pragma unroll
    for (int i = 0; i < 4; ++i) {
        const int col = wr * 64 + i * 16 + quad * 4;
        #pragma unroll
        for (int j = 0; j < 2; ++j) {
            const int node = nb + wc * 32 + j * 16 + lr;
            if (node < N_NODES) {
                const uint2 y0 = *(const uint2*)(Y0b + (size_t)node * 128 + col);
                const ushort* yp = (const ushort*)&y0;
                const f32x4 v = comb[i][j];
                *(float4*)(out + (size_t)node * 128 + col) =
                    make_float4(v.x + bf2f(yp[0]), v.y + bf2f(yp[1]),
                                v.z + bf2f(yp[2]), v.w + bf2f(yp[3]));
            }
        }
    }
}

extern "C" void kernel_launch(void* const* d_in, const int* in_sizes, int n_in,
                              void* d_out, int out_size, void* d_ws, size_t ws_size,
                              hipStream_t stream) {
    const float* x     = (const float*)d_in[0];
    const float* eattr = (const float*)d_in[1];
    const float* Wee   = (const float*)d_in[2];
    const float* bee   = (const float*)d_in[3];
    const float* Wpre  = (const float*)d_in[4];
    const float* bpre  = (const float*)d_in[5];
    const float* Wpost = (const float*)d_in[6];
    const float* bpost = (const float*)d_in[7];
    const float* Wlin  = (const float*)d_in[8];
    const float* blin  = (const float*)d_in[9];
    const int*   ei    = (const int*)d_in[10];
    float* out = (float*)d_out;

    // workspace layout (~94.5 MB; ws_size >= 102.6 MB proven previously)
    ushort* aggB = (ushort*)d_ws;                         // N*512 bf16 (51.2 MB)
    ushort* Y1b  = aggB + (size_t)N_NODES * 512;          // N*128 bf16
    ushort* Y2b  = Y1b  + (size_t)N_NODES * 128;          // N*128 bf16
    ushort* Y0b  = Y2b  + (size_t)N_NODES * 128;          // N*128 bf16
    ushort* WxT  = Y0b  + (size_t)N_NODES * 128;          // 384*128 bf16
    ushort* WaT  = WxT + 384 * 128;                       // 384*512 bf16
    float*  W4   = (float*)(WaT + 384 * 512);             // ED*D fp32
    float*  bp   = W4 + ED * D;                           // 128
    float*  b_comb = bp + D;                              // 128
    float*  avglog = b_comb + D;                          // 1 (+3 pad)
    int*   cnt      = (int*)(avglog + 4);
    int*   rowstart = cnt + N_NODES;
    int*   cursor   = rowstart + N_NODES + 2;
    int2*  csr_se   = (int2*)(cursor + N_NODES + 2);      // +2 pad keeps 8B align

    k_init<<<(N_NODES + 255) / 256, 256, 0, stream>>>(cnt);
    k_hist<<<(N_EDGES + 255) / 256, 256, 0, stream>>>(ei, cnt);
    k_scan<<<1, 1024, 0, stream>>>(cnt, rowstart, cursor, avglog);
    k_scatter<<<(N_EDGES + 255) / 256, 256, 0, stream>>>(ei, cursor, csr_se);
    k_small<<<1, 128, 0, stream>>>(Wee, bee, Wpre, bpre, W4, bp);
    k_prep<<<8, 256, 0, stream>>>(Wpre, WxT, 128, 2048);                    // W1^T
    k_prep<<<8, 256, 0, stream>>>(Wpre + 128 * 128, WxT + 128 * 128, 128, 2048); // W2^T
    k_fold<<<104, 256, 0, stream>>>(Wpost, bpost, Wlin, blin, WxT, WaT, b_comb);
    k_xgemm<<<dim3((N_NODES + 127) / 128, 3), 256, 0, stream>>>(x, WxT, b_comb,
                                                                Y1b, Y2b, Y0b);
    k_pull<<<N_NODES / 2, 256, 0, stream>>>(eattr, W4, bp, Y1b, Y2b,
                                            rowstart, csr_se, aggB);
    k_agg<<<(N_NODES + 63) / 64, 256, 0, stream>>>(aggB, WaT, Y0b, cnt, avglog, out);
}

// Round 3
// 394.659 us; speedup vs baseline: 1.1492x; 1.1321x over previous
//
#include <hip/hip_runtime.h>
#include <hip/hip_bf16.h>
#include <float.h>
#include <math.h>

#define N_NODES 50000
#define N_EDGES 500000
#define D 128
#define ED 10
#define EPS_PNA 1e-5f
#define SCAN_NTILES 49   // ceil(50000 / 1024)

typedef __hip_bfloat16 bf16;
typedef unsigned short ushort;
typedef unsigned int uint;
typedef __attribute__((ext_vector_type(8))) short short8;   // 8 bf16 (4 VGPRs)
typedef __attribute__((ext_vector_type(4))) float f32x4;    // MFMA C/D

__device__ __forceinline__ ushort f2bf(float f) {
    __hip_bfloat16 h = __float2bfloat16(f);
    return *reinterpret_cast<ushort*>(&h);
}
__device__ __forceinline__ float bf2f(ushort u) {
    return __uint_as_float(((uint)u) << 16);
}

// ---------------- K0: zero degree histogram ----------------
__global__ void k_init(int* __restrict__ cnt) {
    int i = blockIdx.x * blockDim.x + threadIdx.x;
    if (i < N_NODES) cnt[i] = 0;
}

// ---------------- K1: degree histogram ----------------
__global__ void k_hist(const int* __restrict__ ei, int* __restrict__ cnt) {
    int e = blockIdx.x * blockDim.x + threadIdx.x;
    if (e < N_EDGES) atomicAdd(&cnt[ei[N_EDGES + e]], 1);
}

// ---------------- K2a: per-tile reduce (sum + logsum), 1024 nodes/tile ----------------
__global__ __launch_bounds__(256) void k_scanA(const int* __restrict__ cnt,
                                               int* __restrict__ bsum,
                                               float* __restrict__ blog) {
    const int t = threadIdx.x;
    const int base = blockIdx.x * 1024;
    int s = 0; float ls = 0.f;
    #pragma unroll
    for (int k = 0; k < 4; ++k) {
        const int idx = base + t + k * 256;
        if (idx < N_NODES) {
            const int c = cnt[idx];
            s += c;
            ls += logf((float)c + 1.0f);
        }
    }
    #pragma unroll
    for (int off = 32; off > 0; off >>= 1) {
        s += __shfl_down(s, off, 64);
        ls += __shfl_down(ls, off, 64);
    }
    __shared__ int ws[4]; __shared__ float wl[4];
    const int wv = t >> 6, l = t & 63;
    if (l == 0) { ws[wv] = s; wl[wv] = ls; }
    __syncthreads();
    if (t == 0) {
        bsum[blockIdx.x] = ws[0] + ws[1] + ws[2] + ws[3];
        blog[blockIdx.x] = wl[0] + wl[1] + wl[2] + wl[3];
    }
}

// ---------------- K2b: scan the 49 tile sums (one wave) + avg_log ----------------
__global__ void k_scanB(const int* __restrict__ bsum, const float* __restrict__ blog,
                        int* __restrict__ boff, int* __restrict__ rowstart,
                        float* __restrict__ avglog) {
    const int t = threadIdx.x;   // 64 threads
    const int v = (t < SCAN_NTILES) ? bsum[t] : 0;
    const float lg = (t < SCAN_NTILES) ? blog[t] : 0.f;
    int s = v;
    #pragma unroll
    for (int off = 1; off < 64; off <<= 1) {
        const int u = __shfl_up(s, off, 64);
        if (t >= off) s += u;
    }
    if (t < SCAN_NTILES) boff[t] = s - v;       // exclusive prefix
    if (t == 63) rowstart[N_NODES] = s;         // grand total
    float lt = lg;
    #pragma unroll
    for (int off = 32; off > 0; off >>= 1) lt += __shfl_down(lt, off, 64);
    if (t == 0) avglog[0] = lt * (1.0f / (float)N_NODES);
}

// ---------------- K2c: per-tile exclusive scan + tile offset ----------------
__global__ __launch_bounds__(256) void k_scanC(const int* __restrict__ cnt,
                                               const int* __restrict__ boff,
                                               int* __restrict__ rowstart,
                                               int* __restrict__ cursor) {
    const int t = threadIdx.x, lane = t & 63, wv = t >> 6;
    const int base = blockIdx.x * 1024;
    int c[4]; int ts = 0;
    #pragma unroll
    for (int k = 0; k < 4; ++k) {
        const int idx = base + t * 4 + k;
        c[k] = (idx < N_NODES) ? cnt[idx] : 0;
        ts += c[k];
    }
    int s = ts;
    #pragma unroll
    for (int off = 1; off < 64; off <<= 1) {
        const int u = __shfl_up(s, off, 64);
        if (lane >= off) s += u;
    }
    __shared__ int wtot[4], woff[4];
    if (lane == 63) wtot[wv] = s;
    __syncthreads();
    if (t == 0) {
        int r = 0;
        #pragma unroll
        for (int i = 0; i < 4; ++i) { woff[i] = r; r += wtot[i]; }
    }
    __syncthreads();
    int excl = boff[blockIdx.x] + woff[wv] + (s - ts);
    #pragma unroll
    for (int k = 0; k < 4; ++k) {
        const int idx = base + t * 4 + k;
        if (idx < N_NODES) { rowstart[idx] = excl; cursor[idx] = excl; }
        excl += c[k];
    }
}

// ---------------- K3: bucket edges into CSR order (src,eid packed as int2) ----------------
__global__ void k_scatter(const int* __restrict__ ei, int* __restrict__ cursor,
                          int2* __restrict__ csr_se) {
    int e = blockIdx.x * blockDim.x + threadIdx.x;
    if (e < N_EDGES) {
        const int dst = ei[N_EDGES + e];
        const int pos = atomicAdd(&cursor[dst], 1);
        csr_se[pos] = make_int2(ei[e], e);
    }
}

// ---------------- K4: fold edge-encoder through W3 ----------------
__global__ __launch_bounds__(128) void k_small(const float* __restrict__ Wee,
                                               const float* __restrict__ bee,
                                               const float* __restrict__ Wpre,
                                               const float* __restrict__ bpre,
                                               float* __restrict__ W4,
                                               float* __restrict__ bp) {
    __shared__ float wee_s[ED * D];
    __shared__ float bee_s[D];
    const int t = threadIdx.x;
    for (int i = t; i < ED * D; i += 128) wee_s[i] = Wee[i];
    bee_s[t] = bee[t];
    __syncthreads();
    float acc[ED];
    #pragma unroll
    for (int r = 0; r < ED; ++r) acc[r] = 0.f;
    float bacc = 0.f;
    for (int k = 0; k < D; ++k) {
        const float w3 = Wpre[(size_t)(2 * D + k) * D + t];
        #pragma unroll
        for (int r = 0; r < ED; ++r) acc[r] += wee_s[r * D + k] * w3;
        bacc += bee_s[k] * w3;
    }
    #pragma unroll
    for (int r = 0; r < ED; ++r) W4[r * D + t] = acc[r];
    bp[t] = bpre[t] + bacc;
}

// ---------------- K5: transpose weight [K][128] fp32 -> [128][K] bf16 ----------------
__global__ void k_prep(const float* __restrict__ src, ushort* __restrict__ dst,
                       int K, int jobs) {
    int id = blockIdx.x * blockDim.x + threadIdx.x;
    if (id >= jobs) return;
    const int col = id & 127;
    const int k0 = (id >> 7) * 8;
    ushort tmp[8];
    #pragma unroll
    for (int r = 0; r < 8; ++r) tmp[r] = f2bf(src[(size_t)(k0 + r) * 128 + col]);
    *(uint4*)(dst + (size_t)col * K + k0) = *(uint4*)tmp;
}

// ---------------- K6: fold Wpost@Wlin -> Wc, routed into transposed bf16 layouts ----------------
__global__ __launch_bounds__(256) void k_fold(
    const float* __restrict__ Wpost, const float* __restrict__ bpost,
    const float* __restrict__ Wlin, const float* __restrict__ blin,
    ushort* __restrict__ WxT,     // [384][128]
    ushort* __restrict__ WaT,     // [384][512]
    float* __restrict__ b_comb)
{
    __shared__ float Wl[128 * 128];   // 64 KB fp32
    const int t = threadIdx.x;
    for (int i = t; i < 128 * 128 / 4; i += 256)
        ((float4*)Wl)[i] = ((const float4*)Wlin)[i];
    __syncthreads();
    const int j = t & 127, rp = t >> 7;
    const int kr0 = blockIdx.x * 16 + rp * 8;
    for (int r = 0; r < 8; ++r) {
        const int kr = kr0 + r;
        const float* wrow = Wpost + (size_t)kr * 128;
        float acc = 0.f;
        #pragma unroll 8
        for (int m = 0; m < 128; ++m) acc += wrow[m] * Wl[m * 128 + j];
        const ushort v = f2bf(acc);
        if (kr < 128)       WxT[(256 + j) * 128 + kr] = v;
        else if (kr < 640)  WaT[(size_t)j * 512 + (kr - 128)] = v;
        else if (kr < 1152) WaT[(size_t)(128 + j) * 512 + (kr - 640)] = v;
        else                WaT[(size_t)(256 + j) * 512 + (kr - 1152)] = v;
    }
    if (blockIdx.x == 0 && t < 128) {
        float acc = 0.f;
        #pragma unroll 8
        for (int m = 0; m < 128; ++m) acc += bpost[m] * Wl[m * 128 + t];
        b_comb[t] = acc + blin[t];
    }
}

// ---------------- K7: MFMA x-GEMMs: slice 0 -> Y1b=x@W1, 1 -> Y2b=x@W2, 2 -> Y0b=x@Wc0+b_comb ----------------
__global__ __launch_bounds__(256) void k_xgemm(
    const float* __restrict__ x, const ushort* __restrict__ WxT,
    const float* __restrict__ b_comb,
    ushort* __restrict__ Y1b, ushort* __restrict__ Y2b, ushort* __restrict__ Y0b)
{
    __shared__ __align__(16) ushort Alds[128 * 136];
    __shared__ __align__(16) ushort Hlds[128 * 136];
    const int t = threadIdx.x;
    const int nb = blockIdx.x * 128;
    const int sy = blockIdx.y;

    #pragma unroll
    for (int g = 0; g < 8; ++g) {
        const int idx = t + g * 256;
        const int row = idx >> 4, kk = (idx & 15) * 8;
        *(uint4*)&Alds[row * 136 + kk] =
            *(const uint4*)(WxT + ((size_t)sy * 128 + row) * 128 + kk);
        const int node = nb + row;
        uint4 v = make_uint4(0u, 0u, 0u, 0u);
        if (node < N_NODES) {
            const float4 f0 = *(const float4*)(x + (size_t)node * 128 + kk);
            const float4 f1 = *(const float4*)(x + (size_t)node * 128 + kk + 4);
            __hip_bfloat162 p0 = __float22bfloat162_rn(make_float2(f0.x, f0.y));
            __hip_bfloat162 p1 = __float22bfloat162_rn(make_float2(f0.z, f0.w));
            __hip_bfloat162 p2 = __float22bfloat162_rn(make_float2(f1.x, f1.y));
            __hip_bfloat162 p3 = __float22bfloat162_rn(make_float2(f1.z, f1.w));
            v.x = *(uint*)&p0; v.y = *(uint*)&p1; v.z = *(uint*)&p2; v.w = *(uint*)&p3;
        }
        *(uint4*)&Hlds[row * 136 + kk] = v;
    }
    __syncthreads();

    const int w = t >> 6, l = t & 63;
    const int wr = w >> 1, wc = w & 1;
    const int quad = l >> 4, lr = l & 15;

    f32x4 acc[4][4];
    #pragma unroll
    for (int i = 0; i < 4; ++i)
        #pragma unroll
        for (int j = 0; j < 4; ++j) acc[i][j] = (f32x4){0.f, 0.f, 0.f, 0.f};

    #pragma unroll
    for (int s = 0; s < 4; ++s) {
        short8 av[4], bv[4];
        #pragma unroll
        for (int i = 0; i < 4; ++i)
            av[i] = *(const short8*)&Alds[(wr * 64 + i * 16 + lr) * 136 + s * 32 + quad * 8];
        #pragma unroll
        for (int j = 0; j < 4; ++j)
            bv[j] = *(const short8*)&Hlds[(wc * 64 + j * 16 + lr) * 136 + s * 32 + quad * 8];
        #pragma unroll
        for (int i = 0; i < 4; ++i)
            #pragma unroll
            for (int j = 0; j < 4; ++j)
                acc[i][j] = __builtin_amdgcn_mfma_f32_16x16x32_bf16(av[i], bv[j], acc[i][j], 0, 0, 0);
    }

    ushort* dst = (sy == 0) ? Y1b : (sy == 1) ? Y2b : Y0b;
    #pragma unroll
    for (int i = 0; i < 4; ++i) {
        const int col = wr * 64 + i * 16 + quad * 4;
        float b0 = 0.f, b1 = 0.f, b2 = 0.f, b3 = 0.f;
        if (sy == 2) {
            b0 = b_comb[col]; b1 = b_comb[col + 1];
            b2 = b_comb[col + 2]; b3 = b_comb[col + 3];
        }
        #pragma unroll
        for (int j = 0; j < 4; ++j) {
            const int node = nb + wc * 64 + j * 16 + lr;
            if (node < N_NODES) {
                const f32x4 v = acc[i][j];
                ushort pk[4];
                pk[0] = f2bf(v.x + b0); pk[1] = f2bf(v.y + b1);
                pk[2] = f2bf(v.z + b2); pk[3] = f2bf(v.w + b3);
                *(uint2*)(dst + (size_t)node * 128 + col) = *(uint2*)pk;
            }
        }
    }
}

// ---------------- K8: CSR pull aggregation -> agg bf16 [N][512] ----------------
// Round-0 proven structure: 1 wave per node, LDS-cached W4, serial edge loop.
// Single delta: 1-deep prefetch of csr_se removes the index load from the
// per-edge dependent chain (and exposes next-iter gathers to the scheduler).
__global__ __launch_bounds__(256) void k_pull(
    const float* __restrict__ eattr, const float* __restrict__ W4,
    const float* __restrict__ bp, const ushort* __restrict__ Y1b,
    const ushort* __restrict__ Y2b,
    const int* __restrict__ rowstart,
    const int2* __restrict__ csr_se,
    ushort* __restrict__ aggB)
{
    __shared__ float2 w4s[ED][64];
    const int t = threadIdx.x;
    for (int i = t; i < ED * 64; i += 256)
        w4s[i >> 6][i & 63] = ((const float2*)W4)[i];
    __syncthreads();

    const int wv = t >> 6, l = t & 63;
    const int n = blockIdx.x * 4 + wv;
    const int r0 = rowstart[n], r1 = rowstart[n + 1];
    const int d = r1 - r0;

    float s0 = 0.f, s1 = 0.f, ss0 = 0.f, ss1 = 0.f;
    float mx0 = -FLT_MAX, mx1 = -FLT_MAX, mn0 = FLT_MAX, mn1 = FLT_MAX;
    const __hip_bfloat162* Y2p = (const __hip_bfloat162*)Y2b;

    int2 se = (d > 0) ? csr_se[r0] : make_int2(0, 0);
    for (int i = r0; i < r1; ++i) {
        const int2 cur = se;
        const int inext = (i + 1 < r1) ? (i + 1) : i;   // branchless clamp
        se = csr_se[inext];                             // prefetch next index pair
        const float2 y2 = __bfloat1622float2(Y2p[(size_t)cur.x * 64 + l]);
        const float2* ea2 = (const float2*)(eattr + (size_t)cur.y * ED);
        float q0 = 0.f, q1 = 0.f;
        #pragma unroll
        for (int r = 0; r < 5; ++r) {
            const float2 a = ea2[r];
            const float2 wA = w4s[2 * r][l];
            const float2 wB = w4s[2 * r + 1][l];
            q0 += a.x * wA.x + a.y * wB.x;
            q1 += a.x * wA.y + a.y * wB.y;
        }
        const float z0 = y2.x + q0, z1 = y2.y + q1;
        s0 += z0; s1 += z1;
        ss0 += z0 * z0; ss1 += z1 * z1;
        mx0 = fmaxf(mx0, z0); mx1 = fmaxf(mx1, z1);
        mn0 = fminf(mn0, z0); mn1 = fminf(mn1, z1);
    }

    const float2 bpw = ((const float2*)bp)[l];
    const float2 y1 = __bfloat1622float2(((const __hip_bfloat162*)Y1b)[(size_t)n * 64 + l]);
    float mean0, mean1, vmx0, vmx1, vmn0, vmn1, st0, st1;
    if (d > 0) {
        const float inv = 1.f / (float)d;
        const float mz0 = s0 * inv, mz1 = s1 * inv;
        const float c0 = y1.x + bpw.x, c1 = y1.y + bpw.y;
        mean0 = mz0 + c0; mean1 = mz1 + c1;
        st0 = sqrtf(fmaxf(ss0 * inv - mz0 * mz0, 0.f) + EPS_PNA);
        st1 = sqrtf(fmaxf(ss1 * inv - mz1 * mz1, 0.f) + EPS_PNA);
        vmx0 = mx0 + c0; vmx1 = mx1 + c1;
        vmn0 = mn0 + c0; vmn1 = mn1 + c1;
    } else {
        mean0 = mean1 = 0.f;
        vmx0 = vmx1 = vmn0 = vmn1 = 0.f;
        st0 = st1 = sqrtf(EPS_PNA);
    }
    __hip_bfloat162* aggv = (__hip_bfloat162*)aggB;
    const size_t b0 = (size_t)n * 256;
    aggv[b0 + l]       = __float22bfloat162_rn(make_float2(mean0, mean1));
    aggv[b0 + 64 + l]  = __float22bfloat162_rn(make_float2(vmx0, vmx1));
    aggv[b0 + 128 + l] = __float22bfloat162_rn(make_float2(vmn0, vmn1));
    aggv[b0 + 192 + l] = __float22bfloat162_rn(make_float2(st0, st1));
}

// ---------------- K9: MFMA agg-GEMM with 3 in-register slices ----------------
__global__ __launch_bounds__(256) void k_agg(
    const ushort* __restrict__ aggB,  // [N][512] bf16
    const ushort* __restrict__ WaT,   // [384][512] bf16
    const ushort* __restrict__ Y0b,   // [N][128] bf16
    const int* __restrict__ cnt, const float* __restrict__ avglog,
    float* __restrict__ out)
{
    __shared__ __align__(16) ushort Alds[128 * 72];
    __shared__ __align__(16) ushort Hlds[64 * 72];
    __shared__ float r1s[64], r2s[64];

    const int t = threadIdx.x;
    const int nb = blockIdx.x * 64;
    if (t < 64) {
        const int node = nb + t;
        float deg = 1.f;
        if (node < N_NODES) deg = fmaxf((float)cnt[node], 1.f);
        const float sl = logf(deg + 1.f);
        const float al = avglog[0];
        r1s[t] = sl / al;
        r2s[t] = al / sl;
    }

    const int w = t >> 6, l = t & 63;
    const int wr = w >> 1, wc = w & 1;   // wr: col half (64), wc: node half (32)
    const int quad = l >> 4, lr = l & 15;

    f32x4 comb[4][2];
    #pragma unroll
    for (int i = 0; i < 4; ++i)
        #pragma unroll
        for (int j = 0; j < 2; ++j) comb[i][j] = (f32x4){0.f, 0.f, 0.f, 0.f};

    for (int sl = 0; sl < 3; ++sl) {
        f32x4 acc[4][2];
        #pragma unroll
        for (int i = 0; i < 4; ++i)
            #pragma unroll
            for (int j = 0; j < 2; ++j) acc[i][j] = (f32x4){0.f, 0.f, 0.f, 0.f};

        for (int kc = 0; kc < 8; ++kc) {
            const int k0 = kc * 64;
            __syncthreads();
            #pragma unroll
            for (int g = 0; g < 4; ++g) {      // A: 128 rows x 64 k
                const int idx = t + g * 256;
                const int row = idx >> 3, kk = (idx & 7) * 8;
                *(uint4*)&Alds[row * 72 + kk] =
                    *(const uint4*)(WaT + ((size_t)(sl * 128 + row)) * 512 + k0 + kk);
            }
            #pragma unroll
            for (int g = 0; g < 2; ++g) {      // H: 64 rows x 64 k
                const int idx = t + g * 256;
                const int row = idx >> 3, kk = (idx & 7) * 8;
                const int node = nb + row;
                uint4 v = make_uint4(0u, 0u, 0u, 0u);
                if (node < N_NODES)
                    v = *(const uint4*)(aggB + (size_t)node * 512 + k0 + kk);
                *(uint4*)&Hlds[row * 72 + kk] = v;
            }
            __syncthreads();
            #pragma unroll
            for (int s = 0; s < 2; ++s) {
                short8 av[4], bv[2];
                #pragma unroll
                for (int i = 0; i < 4; ++i)
                    av[i] = *(const short8*)&Alds[(wr * 64 + i * 16 + lr) * 72 + s * 32 + quad * 8];
                #pragma unroll
                for (int j = 0; j < 2; ++j)
                    bv[j] = *(const short8*)&Hlds[(wc * 32 + j * 16 + lr) * 72 + s * 32 + quad * 8];
                #pragma unroll
                for (int i = 0; i < 4; ++i)
                    #pragma unroll
                    for (int j = 0; j < 2; ++j)
                        acc[i][j] = __builtin_amdgcn_mfma_f32_16x16x32_bf16(av[i], bv[j], acc[i][j], 0, 0, 0);
            }
        }
        #pragma unroll
        for (int j = 0; j < 2; ++j) {
            const int nl = wc * 32 + j * 16 + lr;
            const float r = (sl == 0) ? 1.f : (sl == 1) ? r1s[nl] : r2s[nl];
            #pragma unroll
            for (int i = 0; i < 4; ++i) {
                comb[i][j].x += r * acc[i][j].x;
                comb[i][j].y += r * acc[i][j].y;
                comb[i][j].z += r * acc[i][j].z;
                comb[i][j].w += r * acc[i][j].w;
            }
        }
    }

    #pragma unroll
    for (int i = 0; i < 4; ++i) {
        const int col = wr * 64 + i * 16 + quad * 4;
        #pragma unroll
        for (int j = 0; j < 2; ++j) {
            const int node = nb + wc * 32 + j * 16 + lr;
            if (node < N_NODES) {
                const uint2 y0 = *(const uint2*)(Y0b + (size_t)node * 128 + col);
                const ushort* yp = (const ushort*)&y0;
                const f32x4 v = comb[i][j];
                *(float4*)(out + (size_t)node * 128 + col) =
                    make_float4(v.x + bf2f(yp[0]), v.y + bf2f(yp[1]),
                                v.z + bf2f(yp[2]), v.w + bf2f(yp[3]));
            }
        }
    }
}

extern "C" void kernel_launch(void* const* d_in, const int* in_sizes, int n_in,
                              void* d_out, int out_size, void* d_ws, size_t ws_size,
                              hipStream_t stream) {
    const float* x     = (const float*)d_in[0];
    const float* eattr = (const float*)d_in[1];
    const float* Wee   = (const float*)d_in[2];
    const float* bee   = (const float*)d_in[3];
    const float* Wpre  = (const float*)d_in[4];
    const float* bpre  = (const float*)d_in[5];
    const float* Wpost = (const float*)d_in[6];
    const float* bpost = (const float*)d_in[7];
    const float* Wlin  = (const float*)d_in[8];
    const float* blin  = (const float*)d_in[9];
    const int*   ei    = (const int*)d_in[10];
    float* out = (float*)d_out;

    // workspace layout (~94.7 MB; ws_size >= 102.6 MB proven previously)
    ushort* aggB = (ushort*)d_ws;                         // N*512 bf16 (51.2 MB)
    ushort* Y1b  = aggB + (size_t)N_NODES * 512;          // N*128 bf16
    ushort* Y2b  = Y1b  + (size_t)N_NODES * 128;          // N*128 bf16
    ushort* Y0b  = Y2b  + (size_t)N_NODES * 128;          // N*128 bf16
    ushort* WxT  = Y0b  + (size_t)N_NODES * 128;          // 384*128 bf16
    ushort* WaT  = WxT + 384 * 128;                       // 384*512 bf16
    float*  W4   = (float*)(WaT + 384 * 512);             // ED*D fp32
    float*  bp   = W4 + ED * D;                           // 128
    float*  b_comb = bp + D;                              // 128
    float*  avglog = b_comb + D;                          // 1 (+3 pad)
    int*   cnt      = (int*)(avglog + 4);
    int*   rowstart = cnt + N_NODES;
    int*   cursor   = rowstart + N_NODES + 2;
    int2*  csr_se   = (int2*)(cursor + N_NODES + 2);      // +2 pad keeps 8B align
    int*   bsum     = (int*)(csr_se + N_EDGES);           // 49
    float* blog     = (float*)(bsum + 64);                // 49
    int*   boff     = (int*)(blog + 64);                  // 49

    k_init<<<(N_NODES + 255) / 256, 256, 0, stream>>>(cnt);
    k_hist<<<(N_EDGES + 255) / 256, 256, 0, stream>>>(ei, cnt);
    k_scanA<<<SCAN_NTILES, 256, 0, stream>>>(cnt, bsum, blog);
    k_scanB<<<1, 64, 0, stream>>>(bsum, blog, boff, rowstart, avglog);
    k_scanC<<<SCAN_NTILES, 256, 0, stream>>>(cnt, boff, rowstart, cursor);
    k_scatter<<<(N_EDGES + 255) / 256, 256, 0, stream>>>(ei, cursor, csr_se);
    k_small<<<1, 128, 0, stream>>>(Wee, bee, Wpre, bpre, W4, bp);
    k_prep<<<8, 256, 0, stream>>>(Wpre, WxT, 128, 2048);                    // W1^T
    k_prep<<<8, 256, 0, stream>>>(Wpre + 128 * 128, WxT + 128 * 128, 128, 2048); // W2^T
    k_fold<<<104, 256, 0, stream>>>(Wpost, bpost, Wlin, blin, WxT, WaT, b_comb);
    k_xgemm<<<dim3((N_NODES + 127) / 128, 3), 256, 0, stream>>>(x, WxT, b_comb,
                                                                Y1b, Y2b, Y0b);
    k_pull<<<N_NODES / 4, 256, 0, stream>>>(eattr, W4, bp, Y1b, Y2b,
                                            rowstart, csr_se, aggB);
    k_agg<<<(N_NODES + 63) / 64, 256, 0, stream>>>(aggB, WaT, Y0b, cnt, avglog, out);
}

// Round 4
// 343.862 us; speedup vs baseline: 1.3189x; 1.1477x over previous
//
#include <hip/hip_runtime.h>
#include <hip/hip_bf16.h>
#include <float.h>
#include <math.h>

#define N_NODES 50000
#define N_EDGES 500000
#define D 128
#define ED 10
#define EPS_PNA 1e-5f
#define SCAN_NTILES 49   // ceil(50000 / 1024)

typedef __hip_bfloat16 bf16;
typedef unsigned short ushort;
typedef unsigned int uint;
typedef __attribute__((ext_vector_type(8))) short short8;   // 8 bf16 (4 VGPRs)
typedef __attribute__((ext_vector_type(4))) float f32x4;    // MFMA C/D

__device__ __forceinline__ ushort f2bf(float f) {
    __hip_bfloat16 h = __float2bfloat16(f);
    return *reinterpret_cast<ushort*>(&h);
}
__device__ __forceinline__ float bf2f(ushort u) {
    return __uint_as_float(((uint)u) << 16);
}

// ---------------- K1: degree histogram ----------------
__global__ void k_hist(const int* __restrict__ ei, int* __restrict__ cnt) {
    int e = blockIdx.x * blockDim.x + threadIdx.x;
    if (e < N_EDGES) atomicAdd(&cnt[ei[N_EDGES + e]], 1);
}

// ---------------- K2a: per-tile reduce (sum + logsum), 1024 nodes/tile ----------------
__global__ __launch_bounds__(256) void k_scanA(const int* __restrict__ cnt,
                                               int* __restrict__ bsum,
                                               float* __restrict__ blog) {
    const int t = threadIdx.x;
    const int base = blockIdx.x * 1024;
    int s = 0; float ls = 0.f;
    #pragma unroll
    for (int k = 0; k < 4; ++k) {
        const int idx = base + t + k * 256;
        if (idx < N_NODES) {
            const int c = cnt[idx];
            s += c;
            ls += logf((float)c + 1.0f);
        }
    }
    #pragma unroll
    for (int off = 32; off > 0; off >>= 1) {
        s += __shfl_down(s, off, 64);
        ls += __shfl_down(ls, off, 64);
    }
    __shared__ int ws[4]; __shared__ float wl[4];
    const int wv = t >> 6, l = t & 63;
    if (l == 0) { ws[wv] = s; wl[wv] = ls; }
    __syncthreads();
    if (t == 0) {
        bsum[blockIdx.x] = ws[0] + ws[1] + ws[2] + ws[3];
        blog[blockIdx.x] = wl[0] + wl[1] + wl[2] + wl[3];
    }
}

// ---------------- K2b: scan the 49 tile sums (one wave) + avg_log ----------------
__global__ void k_scanB(const int* __restrict__ bsum, const float* __restrict__ blog,
                        int* __restrict__ boff, int* __restrict__ rowstart,
                        float* __restrict__ avglog) {
    const int t = threadIdx.x;   // 64 threads
    const int v = (t < SCAN_NTILES) ? bsum[t] : 0;
    const float lg = (t < SCAN_NTILES) ? blog[t] : 0.f;
    int s = v;
    #pragma unroll
    for (int off = 1; off < 64; off <<= 1) {
        const int u = __shfl_up(s, off, 64);
        if (t >= off) s += u;
    }
    if (t < SCAN_NTILES) boff[t] = s - v;       // exclusive prefix
    if (t == 63) rowstart[N_NODES] = s;         // grand total
    float lt = lg;
    #pragma unroll
    for (int off = 32; off > 0; off >>= 1) lt += __shfl_down(lt, off, 64);
    if (t == 0) avglog[0] = lt * (1.0f / (float)N_NODES);
}

// ---------------- K2c: per-tile exclusive scan + tile offset ----------------
__global__ __launch_bounds__(256) void k_scanC(const int* __restrict__ cnt,
                                               const int* __restrict__ boff,
                                               int* __restrict__ rowstart,
                                               int* __restrict__ cursor) {
    const int t = threadIdx.x, lane = t & 63, wv = t >> 6;
    const int base = blockIdx.x * 1024;
    int c[4]; int ts = 0;
    #pragma unroll
    for (int k = 0; k < 4; ++k) {
        const int idx = base + t * 4 + k;
        c[k] = (idx < N_NODES) ? cnt[idx] : 0;
        ts += c[k];
    }
    int s = ts;
    #pragma unroll
    for (int off = 1; off < 64; off <<= 1) {
        const int u = __shfl_up(s, off, 64);
        if (lane >= off) s += u;
    }
    __shared__ int wtot[4], woff[4];
    if (lane == 63) wtot[wv] = s;
    __syncthreads();
    if (t == 0) {
        int r = 0;
        #pragma unroll
        for (int i = 0; i < 4; ++i) { woff[i] = r; r += wtot[i]; }
    }
    __syncthreads();
    int excl = boff[blockIdx.x] + woff[wv] + (s - ts);
    #pragma unroll
    for (int k = 0; k < 4; ++k) {
        const int idx = base + t * 4 + k;
        if (idx < N_NODES) { rowstart[idx] = excl; cursor[idx] = excl; }
        excl += c[k];
    }
}

// ---------------- K3: bucket edges into CSR order (src,eid packed as int2) ----------------
__global__ void k_scatter(const int* __restrict__ ei, int* __restrict__ cursor,
                          int2* __restrict__ csr_se) {
    int e = blockIdx.x * blockDim.x + threadIdx.x;
    if (e < N_EDGES) {
        const int dst = ei[N_EDGES + e];
        const int pos = atomicAdd(&cursor[dst], 1);
        csr_se[pos] = make_int2(ei[e], e);
    }
}

// ---------------- K_wprep: fused weight-prep + cnt-init (role-dispatched by blockIdx) ----
// bx [0,104)   : fold Wpost@Wlin -> WxT rows 256..383 / WaT slices + b_comb
// bx == 104    : fold edge-encoder through W3 -> W4, bp
// bx [105,113) : transpose W1 -> WxT[0..128)      (bf16)
// bx [113,121) : transpose W2 -> WxT[128..256)    (bf16)
// bx [121,317) : zero cnt[]
__global__ __launch_bounds__(256) void k_wprep(
    const float* __restrict__ Wee, const float* __restrict__ bee,
    const float* __restrict__ Wpre, const float* __restrict__ bpre,
    const float* __restrict__ Wpost, const float* __restrict__ bpost,
    const float* __restrict__ Wlin, const float* __restrict__ blin,
    float* __restrict__ W4, float* __restrict__ bp,
    ushort* __restrict__ WxT,     // [384][128]
    ushort* __restrict__ WaT,     // [384][512]
    float* __restrict__ b_comb,
    int* __restrict__ cnt)
{
    __shared__ float smem[128 * 128];   // 64 KB, aliased per role
    const int t = threadIdx.x;
    const int bx = blockIdx.x;

    if (bx < 104) {
        // ---- fold role: Wc = Wpost @ Wlin (rows kr0..kr0+15) ----
        float* Wl = smem;
        for (int i = t; i < 128 * 128 / 4; i += 256)
            ((float4*)Wl)[i] = ((const float4*)Wlin)[i];
        __syncthreads();
        const int j = t & 127, rp = t >> 7;
        const int kr0 = bx * 16 + rp * 8;
        for (int r = 0; r < 8; ++r) {
            const int kr = kr0 + r;
            const float* wrow = Wpost + (size_t)kr * 128;
            float acc = 0.f;
            #pragma unroll 8
            for (int m = 0; m < 128; ++m) acc += wrow[m] * Wl[m * 128 + j];
            const ushort v = f2bf(acc);
            if (kr < 128)       WxT[(256 + j) * 128 + kr] = v;
            else if (kr < 640)  WaT[(size_t)j * 512 + (kr - 128)] = v;
            else if (kr < 1152) WaT[(size_t)(128 + j) * 512 + (kr - 640)] = v;
            else                WaT[(size_t)(256 + j) * 512 + (kr - 1152)] = v;
        }
        if (bx == 0 && t < 128) {
            float acc = 0.f;
            #pragma unroll 8
            for (int m = 0; m < 128; ++m) acc += bpost[m] * Wl[m * 128 + t];
            b_comb[t] = acc + blin[t];
        }
    } else if (bx == 104) {
        // ---- small role: W4 = Wee @ W3, bp = bpre + bee @ W3 ----
        float* wee_s = smem;                 // ED*D
        float* bee_s = smem + ED * D;        // D
        for (int i = t; i < ED * D; i += 256) wee_s[i] = Wee[i];
        if (t < 128) bee_s[t] = bee[t];
        __syncthreads();
        if (t < 128) {
            float acc[ED];
            #pragma unroll
            for (int r = 0; r < ED; ++r) acc[r] = 0.f;
            float bacc = 0.f;
            for (int k = 0; k < D; ++k) {
                const float w3 = Wpre[(size_t)(2 * D + k) * D + t];
                #pragma unroll
                for (int r = 0; r < ED; ++r) acc[r] += wee_s[r * D + k] * w3;
                bacc += bee_s[k] * w3;
            }
            #pragma unroll
            for (int r = 0; r < ED; ++r) W4[r * D + t] = acc[r];
            bp[t] = bpre[t] + bacc;
        }
    } else if (bx < 121) {
        // ---- prep role: transpose [128][128] fp32 -> [128][128] bf16 ----
        const int slice = (bx < 113) ? 0 : 1;
        const int id = (bx - (slice ? 113 : 105)) * 256 + t;   // 0..2047
        const float* src = Wpre + (size_t)slice * 128 * 128;
        ushort* dst = WxT + (size_t)slice * 128 * 128;
        const int col = id & 127;
        const int k0 = (id >> 7) * 8;
        ushort tmp[8];
        #pragma unroll
        for (int r = 0; r < 8; ++r) tmp[r] = f2bf(src[(size_t)(k0 + r) * 128 + col]);
        *(uint4*)(dst + (size_t)col * 128 + k0) = *(uint4*)tmp;
    } else {
        // ---- init role: zero degree histogram ----
        const int i = (bx - 121) * 256 + t;
        if (i < N_NODES) cnt[i] = 0;
    }
}

// ---------------- K7: MFMA x-GEMMs, x staged ONCE, slice loop inside ----------------
// sy 0 -> Y1b=x@W1, 1 -> Y2b=x@W2, 2 -> Y0b=x@Wc0+b_comb
__global__ __launch_bounds__(256) void k_xgemm(
    const float* __restrict__ x, const ushort* __restrict__ WxT,
    const float* __restrict__ b_comb,
    ushort* __restrict__ Y1b, ushort* __restrict__ Y2b, ushort* __restrict__ Y0b)
{
    __shared__ __align__(16) ushort Alds[128 * 136];
    __shared__ __align__(16) ushort Hlds[128 * 136];
    const int t = threadIdx.x;
    const int nb = blockIdx.x * 128;

    // stage x tile once (fp32 -> bf16)
    #pragma unroll
    for (int g = 0; g < 8; ++g) {
        const int idx = t + g * 256;
        const int row = idx >> 4, kk = (idx & 15) * 8;
        const int node = nb + row;
        uint4 v = make_uint4(0u, 0u, 0u, 0u);
        if (node < N_NODES) {
            const float4 f0 = *(const float4*)(x + (size_t)node * 128 + kk);
            const float4 f1 = *(const float4*)(x + (size_t)node * 128 + kk + 4);
            __hip_bfloat162 p0 = __float22bfloat162_rn(make_float2(f0.x, f0.y));
            __hip_bfloat162 p1 = __float22bfloat162_rn(make_float2(f0.z, f0.w));
            __hip_bfloat162 p2 = __float22bfloat162_rn(make_float2(f1.x, f1.y));
            __hip_bfloat162 p3 = __float22bfloat162_rn(make_float2(f1.z, f1.w));
            v.x = *(uint*)&p0; v.y = *(uint*)&p1; v.z = *(uint*)&p2; v.w = *(uint*)&p3;
        }
        *(uint4*)&Hlds[row * 136 + kk] = v;
    }

    const int w = t >> 6, l = t & 63;
    const int wr = w >> 1, wc = w & 1;
    const int quad = l >> 4, lr = l & 15;

    for (int sy = 0; sy < 3; ++sy) {
        __syncthreads();   // iter 0: Hlds ready; iter>0: prior MFMA reads of Alds done
        #pragma unroll
        for (int g = 0; g < 8; ++g) {
            const int idx = t + g * 256;
            const int row = idx >> 4, kk = (idx & 15) * 8;
            *(uint4*)&Alds[row * 136 + kk] =
                *(const uint4*)(WxT + ((size_t)sy * 128 + row) * 128 + kk);
        }
        __syncthreads();

        f32x4 acc[4][4];
        #pragma unroll
        for (int i = 0; i < 4; ++i)
            #pragma unroll
            for (int j = 0; j < 4; ++j) acc[i][j] = (f32x4){0.f, 0.f, 0.f, 0.f};

        #pragma unroll
        for (int s = 0; s < 4; ++s) {
            short8 av[4], bv[4];
            #pragma unroll
            for (int i = 0; i < 4; ++i)
                av[i] = *(const short8*)&Alds[(wr * 64 + i * 16 + lr) * 136 + s * 32 + quad * 8];
            #pragma unroll
            for (int j = 0; j < 4; ++j)
                bv[j] = *(const short8*)&Hlds[(wc * 64 + j * 16 + lr) * 136 + s * 32 + quad * 8];
            #pragma unroll
            for (int i = 0; i < 4; ++i)
                #pragma unroll
                for (int j = 0; j < 4; ++j)
                    acc[i][j] = __builtin_amdgcn_mfma_f32_16x16x32_bf16(av[i], bv[j], acc[i][j], 0, 0, 0);
        }

        ushort* dst = (sy == 0) ? Y1b : (sy == 1) ? Y2b : Y0b;
        #pragma unroll
        for (int i = 0; i < 4; ++i) {
            const int col = wr * 64 + i * 16 + quad * 4;
            float b0 = 0.f, b1 = 0.f, b2 = 0.f, b3 = 0.f;
            if (sy == 2) {
                b0 = b_comb[col]; b1 = b_comb[col + 1];
                b2 = b_comb[col + 2]; b3 = b_comb[col + 3];
            }
            #pragma unroll
            for (int j = 0; j < 4; ++j) {
                const int node = nb + wc * 64 + j * 16 + lr;
                if (node < N_NODES) {
                    const f32x4 v = acc[i][j];
                    ushort pk[4];
                    pk[0] = f2bf(v.x + b0); pk[1] = f2bf(v.y + b1);
                    pk[2] = f2bf(v.z + b2); pk[3] = f2bf(v.w + b3);
                    *(uint2*)(dst + (size_t)node * 128 + col) = *(uint2*)pk;
                }
            }
        }
    }
}

// ---------------- K8: CSR pull aggregation -> agg bf16 [N][512] ----------------
// Round-3 proven structure (93 us): 1 wave/node, LDS W4, serial edge loop,
// 1-deep csr_se prefetch. UNCHANGED.
__global__ __launch_bounds__(256) void k_pull(
    const float* __restrict__ eattr, const float* __restrict__ W4,
    const float* __restrict__ bp, const ushort* __restrict__ Y1b,
    const ushort* __restrict__ Y2b,
    const int* __restrict__ rowstart,
    const int2* __restrict__ csr_se,
    ushort* __restrict__ aggB)
{
    __shared__ float2 w4s[ED][64];
    const int t = threadIdx.x;
    for (int i = t; i < ED * 64; i += 256)
        w4s[i >> 6][i & 63] = ((const float2*)W4)[i];
    __syncthreads();

    const int wv = t >> 6, l = t & 63;
    const int n = blockIdx.x * 4 + wv;
    const int r0 = rowstart[n], r1 = rowstart[n + 1];
    const int d = r1 - r0;

    float s0 = 0.f, s1 = 0.f, ss0 = 0.f, ss1 = 0.f;
    float mx0 = -FLT_MAX, mx1 = -FLT_MAX, mn0 = FLT_MAX, mn1 = FLT_MAX;
    const __hip_bfloat162* Y2p = (const __hip_bfloat162*)Y2b;

    int2 se = (d > 0) ? csr_se[r0] : make_int2(0, 0);
    for (int i = r0; i < r1; ++i) {
        const int2 cur = se;
        const int inext = (i + 1 < r1) ? (i + 1) : i;   // branchless clamp
        se = csr_se[inext];                             // prefetch next index pair
        const float2 y2 = __bfloat1622float2(Y2p[(size_t)cur.x * 64 + l]);
        const float2* ea2 = (const float2*)(eattr + (size_t)cur.y * ED);
        float q0 = 0.f, q1 = 0.f;
        #pragma unroll
        for (int r = 0; r < 5; ++r) {
            const float2 a = ea2[r];
            const float2 wA = w4s[2 * r][l];
            const float2 wB = w4s[2 * r + 1][l];
            q0 += a.x * wA.x + a.y * wB.x;
            q1 += a.x * wA.y + a.y * wB.y;
        }
        const float z0 = y2.x + q0, z1 = y2.y + q1;
        s0 += z0; s1 += z1;
        ss0 += z0 * z0; ss1 += z1 * z1;
        mx0 = fmaxf(mx0, z0); mx1 = fmaxf(mx1, z1);
        mn0 = fminf(mn0, z0); mn1 = fminf(mn1, z1);
    }

    const float2 bpw = ((const float2*)bp)[l];
    const float2 y1 = __bfloat1622float2(((const __hip_bfloat162*)Y1b)[(size_t)n * 64 + l]);
    float mean0, mean1, vmx0, vmx1, vmn0, vmn1, st0, st1;
    if (d > 0) {
        const float inv = 1.f / (float)d;
        const float mz0 = s0 * inv, mz1 = s1 * inv;
        const float c0 = y1.x + bpw.x, c1 = y1.y + bpw.y;
        mean0 = mz0 + c0; mean1 = mz1 + c1;
        st0 = sqrtf(fmaxf(ss0 * inv - mz0 * mz0, 0.f) + EPS_PNA);
        st1 = sqrtf(fmaxf(ss1 * inv - mz1 * mz1, 0.f) + EPS_PNA);
        vmx0 = mx0 + c0; vmx1 = mx1 + c1;
        vmn0 = mn0 + c0; vmn1 = mn1 + c1;
    } else {
        mean0 = mean1 = 0.f;
        vmx0 = vmx1 = vmn0 = vmn1 = 0.f;
        st0 = st1 = sqrtf(EPS_PNA);
    }
    __hip_bfloat162* aggv = (__hip_bfloat162*)aggB;
    const size_t b0 = (size_t)n * 256;
    aggv[b0 + l]       = __float22bfloat162_rn(make_float2(mean0, mean1));
    aggv[b0 + 64 + l]  = __float22bfloat162_rn(make_float2(vmx0, vmx1));
    aggv[b0 + 128 + l] = __float22bfloat162_rn(make_float2(vmn0, vmn1));
    aggv[b0 + 192 + l] = __float22bfloat162_rn(make_float2(st0, st1));
}

// ---------------- K9: MFMA agg-GEMM, kc-outer: aggB staged ONCE per kc ----------------
// out[n][col] = Y0b[n][col] + G0 + r1[n]*G1 + r2[n]*G2,  G_s = agg @ Wc_s (K=512).
// Slice partials fold linearly into comb per kc, so H (aggB tile) is staged 1x
// instead of 3x (saves ~100 MB of redundant aggB fetch).
__global__ __launch_bounds__(256) void k_agg(
    const ushort* __restrict__ aggB,  // [N][512] bf16
    const ushort* __restrict__ WaT,   // [384][512] bf16
    const ushort* __restrict__ Y0b,   // [N][128] bf16
    const int* __restrict__ cnt, const float* __restrict__ avglog,
    float* __restrict__ out)
{
    __shared__ __align__(16) ushort Alds[128 * 72];
    __shared__ __align__(16) ushort Hlds[64 * 72];
    __shared__ float r1s[64], r2s[64];

    const int t = threadIdx.x;
    const int nb = blockIdx.x * 64;
    if (t < 64) {
        const int node = nb + t;
        float deg = 1.f;
        if (node < N_NODES) deg = fmaxf((float)cnt[node], 1.f);
        const float sl = logf(deg + 1.f);
        const float al = avglog[0];
        r1s[t] = sl / al;
        r2s[t] = al / sl;
    }

    const int w = t >> 6, l = t & 63;
    const int wr = w >> 1, wc = w & 1;   // wr: col half (64), wc: node half (32)
    const int quad = l >> 4, lr = l & 15;

    f32x4 comb[4][2];
    #pragma unroll
    for (int i = 0; i < 4; ++i)
        #pragma unroll
        for (int j = 0; j < 2; ++j) comb[i][j] = (f32x4){0.f, 0.f, 0.f, 0.f};

    #define STAGE_A(SL)                                                           \
        _Pragma("unroll")                                                         \
        for (int g = 0; g < 4; ++g) {                                             \
            const int idx = t + g * 256;                                          \
            const int row = idx >> 3, kk = (idx & 7) * 8;                         \
            *(uint4*)&Alds[row * 72 + kk] =                                       \
                *(const uint4*)(WaT + ((size_t)((SL) * 128 + row)) * 512 + k0 + kk); \
        }

    #define MFMA_EPOCH(SL)                                                        \
        {                                                                         \
            f32x4 acc[4][2];                                                      \
            _Pragma("unroll")                                                     \
            for (int i = 0; i < 4; ++i)                                           \
                _Pragma("unroll")                                                 \
                for (int j = 0; j < 2; ++j) acc[i][j] = (f32x4){0.f,0.f,0.f,0.f}; \
            _Pragma("unroll")                                                     \
            for (int s = 0; s < 2; ++s) {                                         \
                short8 av[4], bv[2];                                              \
                _Pragma("unroll")                                                 \
                for (int i = 0; i < 4; ++i)                                       \
                    av[i] = *(const short8*)&Alds[(wr*64 + i*16 + lr)*72 + s*32 + quad*8]; \
                _Pragma("unroll")                                                 \
                for (int j = 0; j < 2; ++j)                                       \
                    bv[j] = *(const short8*)&Hlds[(wc*32 + j*16 + lr)*72 + s*32 + quad*8]; \
                _Pragma("unroll")                                                 \
                for (int i = 0; i < 4; ++i)                                       \
                    _Pragma("unroll")                                             \
                    for (int j = 0; j < 2; ++j)                                   \
                        acc[i][j] = __builtin_amdgcn_mfma_f32_16x16x32_bf16(av[i], bv[j], acc[i][j], 0, 0, 0); \
            }                                                                     \
            _Pragma("unroll")                                                     \
            for (int j = 0; j < 2; ++j) {                                         \
                const int nl = wc * 32 + j * 16 + lr;                             \
                const float r = ((SL) == 0) ? 1.f : ((SL) == 1) ? r1s[nl] : r2s[nl]; \
                _Pragma("unroll")                                                 \
                for (int i = 0; i < 4; ++i) {                                     \
                    comb[i][j].x += r * acc[i][j].x;                              \
                    comb[i][j].y += r * acc[i][j].y;                              \
                    comb[i][j].z += r * acc[i][j].z;                              \
                    comb[i][j].w += r * acc[i][j].w;                              \
                }                                                                 \
            }                                                                     \
        }

    for (int kc = 0; kc < 8; ++kc) {
        const int k0 = kc * 64;
        __syncthreads();                       // prior readers of Alds/Hlds done
        #pragma unroll
        for (int g = 0; g < 2; ++g) {          // H: 64 rows x 64 k (once per kc)
            const int idx = t + g * 256;
            const int row = idx >> 3, kk = (idx & 7) * 8;
            const int node = nb + row;
            uint4 v = make_uint4(0u, 0u, 0u, 0u);
            if (node < N_NODES)
                v = *(const uint4*)(aggB + (size_t)node * 512 + k0 + kk);
            *(uint4*)&Hlds[row * 72 + kk] = v;
        }
        STAGE_A(0);
        __syncthreads();
        MFMA_EPOCH(0);
        __syncthreads();
        STAGE_A(1);
        __syncthreads();
        MFMA_EPOCH(1);
        __syncthreads();
        STAGE_A(2);
        __syncthreads();
        MFMA_EPOCH(2);
    }
    #undef STAGE_A
    #undef MFMA_EPOCH

    #pragma unroll
    for (int i = 0; i < 4; ++i) {
        const int col = wr * 64 + i * 16 + quad * 4;
        #pragma unroll
        for (int j = 0; j < 2; ++j) {
            const int node = nb + wc * 32 + j * 16 + lr;
            if (node < N_NODES) {
                const uint2 y0 = *(const uint2*)(Y0b + (size_t)node * 128 + col);
                const ushort* yp = (const ushort*)&y0;
                const f32x4 v = comb[i][j];
                *(float4*)(out + (size_t)node * 128 + col) =
                    make_float4(v.x + bf2f(yp[0]), v.y + bf2f(yp[1]),
                                v.z + bf2f(yp[2]), v.w + bf2f(yp[3]));
            }
        }
    }
}

extern "C" void kernel_launch(void* const* d_in, const int* in_sizes, int n_in,
                              void* d_out, int out_size, void* d_ws, size_t ws_size,
                              hipStream_t stream) {
    const float* x     = (const float*)d_in[0];
    const float* eattr = (const float*)d_in[1];
    const float* Wee   = (const float*)d_in[2];
    const float* bee   = (const float*)d_in[3];
    const float* Wpre  = (const float*)d_in[4];
    const float* bpre  = (const float*)d_in[5];
    const float* Wpost = (const float*)d_in[6];
    const float* bpost = (const float*)d_in[7];
    const float* Wlin  = (const float*)d_in[8];
    const float* blin  = (const float*)d_in[9];
    const int*   ei    = (const int*)d_in[10];
    float* out = (float*)d_out;

    // workspace layout (~94.7 MB; ws_size >= 102.6 MB proven previously)
    ushort* aggB = (ushort*)d_ws;                         // N*512 bf16 (51.2 MB)
    ushort* Y1b  = aggB + (size_t)N_NODES * 512;          // N*128 bf16
    ushort* Y2b  = Y1b  + (size_t)N_NODES * 128;          // N*128 bf16
    ushort* Y0b  = Y2b  + (size_t)N_NODES * 128;          // N*128 bf16
    ushort* WxT  = Y0b  + (size_t)N_NODES * 128;          // 384*128 bf16
    ushort* WaT  = WxT + 384 * 128;                       // 384*512 bf16
    float*  W4   = (float*)(WaT + 384 * 512);             // ED*D fp32
    float*  bp   = W4 + ED * D;                           // 128
    float*  b_comb = bp + D;                              // 128
    float*  avglog = b_comb + D;                          // 1 (+3 pad)
    int*   cnt      = (int*)(avglog + 4);
    int*   rowstart = cnt + N_NODES;
    int*   cursor   = rowstart + N_NODES + 2;
    int2*  csr_se   = (int2*)(cursor + N_NODES + 2);      // +2 pad keeps 8B align
    int*   bsum     = (int*)(csr_se + N_EDGES);           // 49
    float* blog     = (float*)(bsum + 64);                // 49
    int*   boff     = (int*)(blog + 64);                  // 49

    // fused weight-prep + cnt zeroing (roles: 104 fold / 1 small / 16 prep / 196 init)
    k_wprep<<<317, 256, 0, stream>>>(Wee, bee, Wpre, bpre, Wpost, bpost, Wlin, blin,
                                     W4, bp, WxT, WaT, b_comb, cnt);
    k_hist<<<(N_EDGES + 255) / 256, 256, 0, stream>>>(ei, cnt);
    k_scanA<<<SCAN_NTILES, 256, 0, stream>>>(cnt, bsum, blog);
    k_scanB<<<1, 64, 0, stream>>>(bsum, blog, boff, rowstart, avglog);
    k_scanC<<<SCAN_NTILES, 256, 0, stream>>>(cnt, boff, rowstart, cursor);
    k_scatter<<<(N_EDGES + 255) / 256, 256, 0, stream>>>(ei, cursor, csr_se);
    k_xgemm<<<(N_NODES + 127) / 128, 256, 0, stream>>>(x, WxT, b_comb,
                                                       Y1b, Y2b, Y0b);
    k_pull<<<N_NODES / 4, 256, 0, stream>>>(eattr, W4, bp, Y1b, Y2b,
                                            rowstart, csr_se, aggB);
    k_agg<<<(N_NODES + 63) / 64, 256, 0, stream>>>(aggB, WaT, Y0b, cnt, avglog, out);
}

// Round 5
// 315.598 us; speedup vs baseline: 1.4370x; 1.0896x over previous
//
#include <hip/hip_runtime.h>
#include <hip/hip_bf16.h>
#include <float.h>
#include <math.h>

#define N_NODES 50000
#define N_EDGES 500000
#define D 128
#define ED 10
#define EPS_PNA 1e-5f
#define SCAN_NTILES 49     // ceil(50000 / 1024)
#define XGEMM_BLOCKS 391   // ceil(50000 / 128)
#define HIST_BLOCKS 1954   // ceil(500000 / 256)

typedef __hip_bfloat16 bf16;
typedef unsigned short ushort;
typedef unsigned int uint;
typedef __attribute__((ext_vector_type(8))) short short8;   // 8 bf16 (4 VGPRs)
typedef __attribute__((ext_vector_type(4))) float f32x4;    // MFMA C/D

__device__ __forceinline__ ushort f2bf(float f) {
    __hip_bfloat16 h = __float2bfloat16(f);
    return *reinterpret_cast<ushort*>(&h);
}
__device__ __forceinline__ float bf2f(ushort u) {
    return __uint_as_float(((uint)u) << 16);
}

// ---------------- K2a: per-tile reduce (sum + logsum), 1024 nodes/tile ----------------
__global__ __launch_bounds__(256) void k_scanA(const int* __restrict__ cnt,
                                               int* __restrict__ bsum,
                                               float* __restrict__ blog) {
    const int t = threadIdx.x;
    const int base = blockIdx.x * 1024;
    int s = 0; float ls = 0.f;
    #pragma unroll
    for (int k = 0; k < 4; ++k) {
        const int idx = base + t + k * 256;
        if (idx < N_NODES) {
            const int c = cnt[idx];
            s += c;
            ls += logf((float)c + 1.0f);
        }
    }
    #pragma unroll
    for (int off = 32; off > 0; off >>= 1) {
        s += __shfl_down(s, off, 64);
        ls += __shfl_down(ls, off, 64);
    }
    __shared__ int ws[4]; __shared__ float wl[4];
    const int wv = t >> 6, l = t & 63;
    if (l == 0) { ws[wv] = s; wl[wv] = ls; }
    __syncthreads();
    if (t == 0) {
        bsum[blockIdx.x] = ws[0] + ws[1] + ws[2] + ws[3];
        blog[blockIdx.x] = wl[0] + wl[1] + wl[2] + wl[3];
    }
}

// ---------------- K2b: scan the 49 tile sums (one wave) + avg_log ----------------
__global__ void k_scanB(const int* __restrict__ bsum, const float* __restrict__ blog,
                        int* __restrict__ boff, int* __restrict__ rowstart,
                        float* __restrict__ avglog) {
    const int t = threadIdx.x;   // 64 threads
    const int v = (t < SCAN_NTILES) ? bsum[t] : 0;
    const float lg = (t < SCAN_NTILES) ? blog[t] : 0.f;
    int s = v;
    #pragma unroll
    for (int off = 1; off < 64; off <<= 1) {
        const int u = __shfl_up(s, off, 64);
        if (t >= off) s += u;
    }
    if (t < SCAN_NTILES) boff[t] = s - v;       // exclusive prefix
    if (t == 63) rowstart[N_NODES] = s;         // grand total
    float lt = lg;
    #pragma unroll
    for (int off = 32; off > 0; off >>= 1) lt += __shfl_down(lt, off, 64);
    if (t == 0) avglog[0] = lt * (1.0f / (float)N_NODES);
}

// ---------------- K2c: per-tile exclusive scan + tile offset ----------------
__global__ __launch_bounds__(256) void k_scanC(const int* __restrict__ cnt,
                                               const int* __restrict__ boff,
                                               int* __restrict__ rowstart,
                                               int* __restrict__ cursor) {
    const int t = threadIdx.x, lane = t & 63, wv = t >> 6;
    const int base = blockIdx.x * 1024;
    int c[4]; int ts = 0;
    #pragma unroll
    for (int k = 0; k < 4; ++k) {
        const int idx = base + t * 4 + k;
        c[k] = (idx < N_NODES) ? cnt[idx] : 0;
        ts += c[k];
    }
    int s = ts;
    #pragma unroll
    for (int off = 1; off < 64; off <<= 1) {
        const int u = __shfl_up(s, off, 64);
        if (lane >= off) s += u;
    }
    __shared__ int wtot[4], woff[4];
    if (lane == 63) wtot[wv] = s;
    __syncthreads();
    if (t == 0) {
        int r = 0;
        #pragma unroll
        for (int i = 0; i < 4; ++i) { woff[i] = r; r += wtot[i]; }
    }
    __syncthreads();
    int excl = boff[blockIdx.x] + woff[wv] + (s - ts);
    #pragma unroll
    for (int k = 0; k < 4; ++k) {
        const int idx = base + t * 4 + k;
        if (idx < N_NODES) { rowstart[idx] = excl; cursor[idx] = excl; }
        excl += c[k];
    }
}

// ---------------- K3: bucket edges into CSR order as 48B self-contained records ----
// record = { float ea[10]; int src; int pad }  (3 x uint4, 16B aligned)
// eattr is read SEQUENTIALLY here (coalesced); k_pull then streams records in
// CSR order, eliminating the random eattr gather from the pull hot loop.
__global__ void k_scatter(const int* __restrict__ ei, const float* __restrict__ eattr,
                          int* __restrict__ cursor, uint4* __restrict__ csr_rec) {
    int e = blockIdx.x * blockDim.x + threadIdx.x;
    if (e < N_EDGES) {
        const int dst = ei[N_EDGES + e];
        const int src = ei[e];
        const float2* ea2 = (const float2*)(eattr + (size_t)e * ED);
        const float2 a0 = ea2[0], a1 = ea2[1], a2 = ea2[2], a3 = ea2[3], a4 = ea2[4];
        const int pos = atomicAdd(&cursor[dst], 1);
        uint4* o = csr_rec + (size_t)pos * 3;
        o[0] = make_uint4(__float_as_uint(a0.x), __float_as_uint(a0.y),
                          __float_as_uint(a1.x), __float_as_uint(a1.y));
        o[1] = make_uint4(__float_as_uint(a2.x), __float_as_uint(a2.y),
                          __float_as_uint(a3.x), __float_as_uint(a3.y));
        o[2] = make_uint4(__float_as_uint(a4.x), __float_as_uint(a4.y), (uint)src, 0u);
    }
}

// ---------------- K_wprep: fused weight-prep + cnt-init (role-dispatched by blockIdx) ----
// bx [0,104)   : fold Wpost@Wlin -> WxT rows 256..383 / WaT slices + b_comb
// bx == 104    : fold edge-encoder through W3 -> W4, bp
// bx [105,113) : transpose W1 -> WxT[0..128)      (bf16)
// bx [113,121) : transpose W2 -> WxT[128..256)    (bf16)
// bx [121,317) : zero cnt[]
__global__ __launch_bounds__(256) void k_wprep(
    const float* __restrict__ Wee, const float* __restrict__ bee,
    const float* __restrict__ Wpre, const float* __restrict__ bpre,
    const float* __restrict__ Wpost, const float* __restrict__ bpost,
    const float* __restrict__ Wlin, const float* __restrict__ blin,
    float* __restrict__ W4, float* __restrict__ bp,
    ushort* __restrict__ WxT,     // [384][128]
    ushort* __restrict__ WaT,     // [384][512]
    float* __restrict__ b_comb,
    int* __restrict__ cnt)
{
    __shared__ float smem[128 * 128];   // 64 KB, aliased per role
    const int t = threadIdx.x;
    const int bx = blockIdx.x;

    if (bx < 104) {
        // ---- fold role: Wc = Wpost @ Wlin (rows kr0..kr0+15) ----
        float* Wl = smem;
        for (int i = t; i < 128 * 128 / 4; i += 256)
            ((float4*)Wl)[i] = ((const float4*)Wlin)[i];
        __syncthreads();
        const int j = t & 127, rp = t >> 7;
        const int kr0 = bx * 16 + rp * 8;
        for (int r = 0; r < 8; ++r) {
            const int kr = kr0 + r;
            const float* wrow = Wpost + (size_t)kr * 128;
            float acc = 0.f;
            #pragma unroll 8
            for (int m = 0; m < 128; ++m) acc += wrow[m] * Wl[m * 128 + j];
            const ushort v = f2bf(acc);
            if (kr < 128)       WxT[(256 + j) * 128 + kr] = v;
            else if (kr < 640)  WaT[(size_t)j * 512 + (kr - 128)] = v;
            else if (kr < 1152) WaT[(size_t)(128 + j) * 512 + (kr - 640)] = v;
            else                WaT[(size_t)(256 + j) * 512 + (kr - 1152)] = v;
        }
        if (bx == 0 && t < 128) {
            float acc = 0.f;
            #pragma unroll 8
            for (int m = 0; m < 128; ++m) acc += bpost[m] * Wl[m * 128 + t];
            b_comb[t] = acc + blin[t];
        }
    } else if (bx == 104) {
        // ---- small role: W4 = Wee @ W3, bp = bpre + bee @ W3 ----
        float* wee_s = smem;                 // ED*D
        float* bee_s = smem + ED * D;        // D
        for (int i = t; i < ED * D; i += 256) wee_s[i] = Wee[i];
        if (t < 128) bee_s[t] = bee[t];
        __syncthreads();
        if (t < 128) {
            float acc[ED];
            #pragma unroll
            for (int r = 0; r < ED; ++r) acc[r] = 0.f;
            float bacc = 0.f;
            for (int k = 0; k < D; ++k) {
                const float w3 = Wpre[(size_t)(2 * D + k) * D + t];
                #pragma unroll
                for (int r = 0; r < ED; ++r) acc[r] += wee_s[r * D + k] * w3;
                bacc += bee_s[k] * w3;
            }
            #pragma unroll
            for (int r = 0; r < ED; ++r) W4[r * D + t] = acc[r];
            bp[t] = bpre[t] + bacc;
        }
    } else if (bx < 121) {
        // ---- prep role: transpose [128][128] fp32 -> [128][128] bf16 ----
        const int slice = (bx < 113) ? 0 : 1;
        const int id = (bx - (slice ? 113 : 105)) * 256 + t;   // 0..2047
        const float* src = Wpre + (size_t)slice * 128 * 128;
        ushort* dst = WxT + (size_t)slice * 128 * 128;
        const int col = id & 127;
        const int k0 = (id >> 7) * 8;
        ushort tmp[8];
        #pragma unroll
        for (int r = 0; r < 8; ++r) tmp[r] = f2bf(src[(size_t)(k0 + r) * 128 + col]);
        *(uint4*)(dst + (size_t)col * 128 + k0) = *(uint4*)tmp;
    } else {
        // ---- init role: zero degree histogram ----
        const int i = (bx - 121) * 256 + t;
        if (i < N_NODES) cnt[i] = 0;
    }
}

// ---------------- K_hx: fused hist + xgemm (both depend only on k_wprep) -------------
// bx [0,391)      : MFMA x-GEMMs, x staged once, slice loop inside.
//                   sy 0 -> Y1b=x@W1, 1 -> Y2b=x@W2, 2 -> out=x@Wc0+b_comb (fp32!)
// bx [391,2345)   : degree histogram (atomics overlap with MFMA phase)
__global__ __launch_bounds__(256) void k_hx(
    const int* __restrict__ ei, int* __restrict__ cnt,
    const float* __restrict__ x, const ushort* __restrict__ WxT,
    const float* __restrict__ b_comb,
    ushort* __restrict__ Y1b, ushort* __restrict__ Y2b, float* __restrict__ out)
{
    const int t = threadIdx.x;
    if (blockIdx.x >= XGEMM_BLOCKS) {
        const int e = (blockIdx.x - XGEMM_BLOCKS) * 256 + t;
        if (e < N_EDGES) atomicAdd(&cnt[ei[N_EDGES + e]], 1);
        return;
    }

    __shared__ __align__(16) ushort Alds[128 * 136];
    __shared__ __align__(16) ushort Hlds[128 * 136];
    const int nb = blockIdx.x * 128;

    // stage x tile once (fp32 -> bf16)
    #pragma unroll
    for (int g = 0; g < 8; ++g) {
        const int idx = t + g * 256;
        const int row = idx >> 4, kk = (idx & 15) * 8;
        const int node = nb + row;
        uint4 v = make_uint4(0u, 0u, 0u, 0u);
        if (node < N_NODES) {
            const float4 f0 = *(const float4*)(x + (size_t)node * 128 + kk);
            const float4 f1 = *(const float4*)(x + (size_t)node * 128 + kk + 4);
            __hip_bfloat162 p0 = __float22bfloat162_rn(make_float2(f0.x, f0.y));
            __hip_bfloat162 p1 = __float22bfloat162_rn(make_float2(f0.z, f0.w));
            __hip_bfloat162 p2 = __float22bfloat162_rn(make_float2(f1.x, f1.y));
            __hip_bfloat162 p3 = __float22bfloat162_rn(make_float2(f1.z, f1.w));
            v.x = *(uint*)&p0; v.y = *(uint*)&p1; v.z = *(uint*)&p2; v.w = *(uint*)&p3;
        }
        *(uint4*)&Hlds[row * 136 + kk] = v;
    }

    const int w = t >> 6, l = t & 63;
    const int wr = w >> 1, wc = w & 1;
    const int quad = l >> 4, lr = l & 15;

    for (int sy = 0; sy < 3; ++sy) {
        __syncthreads();   // iter 0: Hlds ready; iter>0: prior MFMA reads of Alds done
        #pragma unroll
        for (int g = 0; g < 8; ++g) {
            const int idx = t + g * 256;
            const int row = idx >> 4, kk = (idx & 15) * 8;
            *(uint4*)&Alds[row * 136 + kk] =
                *(const uint4*)(WxT + ((size_t)sy * 128 + row) * 128 + kk);
        }
        __syncthreads();

        f32x4 acc[4][4];
        #pragma unroll
        for (int i = 0; i < 4; ++i)
            #pragma unroll
            for (int j = 0; j < 4; ++j) acc[i][j] = (f32x4){0.f, 0.f, 0.f, 0.f};

        #pragma unroll
        for (int s = 0; s < 4; ++s) {
            short8 av[4], bv[4];
            #pragma unroll
            for (int i = 0; i < 4; ++i)
                av[i] = *(const short8*)&Alds[(wr * 64 + i * 16 + lr) * 136 + s * 32 + quad * 8];
            #pragma unroll
            for (int j = 0; j < 4; ++j)
                bv[j] = *(const short8*)&Hlds[(wc * 64 + j * 16 + lr) * 136 + s * 32 + quad * 8];
            #pragma unroll
            for (int i = 0; i < 4; ++i)
                #pragma unroll
                for (int j = 0; j < 4; ++j)
                    acc[i][j] = __builtin_amdgcn_mfma_f32_16x16x32_bf16(av[i], bv[j], acc[i][j], 0, 0, 0);
        }

        #pragma unroll
        for (int i = 0; i < 4; ++i) {
            const int col = wr * 64 + i * 16 + quad * 4;
            #pragma unroll
            for (int j = 0; j < 4; ++j) {
                const int node = nb + wc * 64 + j * 16 + lr;
                if (node < N_NODES) {
                    const f32x4 v = acc[i][j];
                    if (sy == 2) {
                        // Y0 contribution straight to out in fp32 (no bf16 round-trip)
                        *(float4*)(out + (size_t)node * 128 + col) =
                            make_float4(v.x + b_comb[col],     v.y + b_comb[col + 1],
                                        v.z + b_comb[col + 2], v.w + b_comb[col + 3]);
                    } else {
                        ushort* dst = (sy == 0) ? Y1b : Y2b;
                        ushort pk[4];
                        pk[0] = f2bf(v.x); pk[1] = f2bf(v.y);
                        pk[2] = f2bf(v.z); pk[3] = f2bf(v.w);
                        *(uint2*)(dst + (size_t)node * 128 + col) = *(uint2*)pk;
                    }
                }
            }
        }
    }
}

// ---------------- K8: CSR pull aggregation -> agg bf16 [N][512] ----------------
// 1 wave/node, LDS W4, serial edge loop, 1-deep RECORD prefetch.
// Records are self-contained (ea + src) and streamed sequentially; the only
// random access left in the chain is the Y2b row gather.
__global__ __launch_bounds__(256) void k_pull(
    const uint4* __restrict__ csr_rec, const float* __restrict__ W4,
    const float* __restrict__ bp, const ushort* __restrict__ Y1b,
    const ushort* __restrict__ Y2b,
    const int* __restrict__ rowstart,
    ushort* __restrict__ aggB)
{
    __shared__ float2 w4s[ED][64];
    const int t = threadIdx.x;
    for (int i = t; i < ED * 64; i += 256)
        w4s[i >> 6][i & 63] = ((const float2*)W4)[i];
    __syncthreads();

    const int wv = t >> 6, l = t & 63;
    const int n = blockIdx.x * 4 + wv;
    const int r0 = rowstart[n], r1 = rowstart[n + 1];
    const int d = r1 - r0;

    float s0 = 0.f, s1 = 0.f, ss0 = 0.f, ss1 = 0.f;
    float mx0 = -FLT_MAX, mx1 = -FLT_MAX, mn0 = FLT_MAX, mn1 = FLT_MAX;
    const __hip_bfloat162* Y2p = (const __hip_bfloat162*)Y2b;

    uint4 ra, rb, rc;
    if (d > 0) {
        const uint4* rp = csr_rec + (size_t)r0 * 3;
        ra = rp[0]; rb = rp[1]; rc = rp[2];
    }
    for (int i = r0; i < r1; ++i) {
        const int inext = (i + 1 < r1) ? (i + 1) : i;
        const uint4* rp = csr_rec + (size_t)inext * 3;
        const uint4 na = rp[0], nb = rp[1], nc = rp[2];

        const int src = (int)rc.z;
        const float2 y2 = __bfloat1622float2(Y2p[(size_t)src * 64 + l]);

        float ea[10];
        ea[0] = __uint_as_float(ra.x); ea[1] = __uint_as_float(ra.y);
        ea[2] = __uint_as_float(ra.z); ea[3] = __uint_as_float(ra.w);
        ea[4] = __uint_as_float(rb.x); ea[5] = __uint_as_float(rb.y);
        ea[6] = __uint_as_float(rb.z); ea[7] = __uint_as_float(rb.w);
        ea[8] = __uint_as_float(rc.x); ea[9] = __uint_as_float(rc.y);

        float q0 = 0.f, q1 = 0.f;
        #pragma unroll
        for (int r = 0; r < ED; ++r) {
            const float2 wv2 = w4s[r][l];
            q0 += ea[r] * wv2.x;
            q1 += ea[r] * wv2.y;
        }
        const float z0 = y2.x + q0, z1 = y2.y + q1;
        s0 += z0; s1 += z1;
        ss0 += z0 * z0; ss1 += z1 * z1;
        mx0 = fmaxf(mx0, z0); mx1 = fmaxf(mx1, z1);
        mn0 = fminf(mn0, z0); mn1 = fminf(mn1, z1);

        ra = na; rb = nb; rc = nc;
    }

    const float2 bpw = ((const float2*)bp)[l];
    const float2 y1 = __bfloat1622float2(((const __hip_bfloat162*)Y1b)[(size_t)n * 64 + l]);
    float mean0, mean1, vmx0, vmx1, vmn0, vmn1, st0, st1;
    if (d > 0) {
        const float inv = 1.f / (float)d;
        const float mz0 = s0 * inv, mz1 = s1 * inv;
        const float c0 = y1.x + bpw.x, c1 = y1.y + bpw.y;
        mean0 = mz0 + c0; mean1 = mz1 + c1;
        st0 = sqrtf(fmaxf(ss0 * inv - mz0 * mz0, 0.f) + EPS_PNA);
        st1 = sqrtf(fmaxf(ss1 * inv - mz1 * mz1, 0.f) + EPS_PNA);
        vmx0 = mx0 + c0; vmx1 = mx1 + c1;
        vmn0 = mn0 + c0; vmn1 = mn1 + c1;
    } else {
        mean0 = mean1 = 0.f;
        vmx0 = vmx1 = vmn0 = vmn1 = 0.f;
        st0 = st1 = sqrtf(EPS_PNA);
    }
    __hip_bfloat162* aggv = (__hip_bfloat162*)aggB;
    const size_t b0 = (size_t)n * 256;
    aggv[b0 + l]       = __float22bfloat162_rn(make_float2(mean0, mean1));
    aggv[b0 + 64 + l]  = __float22bfloat162_rn(make_float2(vmx0, vmx1));
    aggv[b0 + 128 + l] = __float22bfloat162_rn(make_float2(vmn0, vmn1));
    aggv[b0 + 192 + l] = __float22bfloat162_rn(make_float2(st0, st1));
}

// ---------------- K9: MFMA agg-GEMM, kc-outer; accumulates INTO out (fp32 RMW) ------
// out[n][col] += G0 + r1[n]*G1 + r2[n]*G2,  G_s = agg @ Wc_s (K=512).
// (out already holds the x@Wc0 + b_comb contribution from k_hx, in fp32.)
__global__ __launch_bounds__(256) void k_agg(
    const ushort* __restrict__ aggB,  // [N][512] bf16
    const ushort* __restrict__ WaT,   // [384][512] bf16
    const int* __restrict__ cnt, const float* __restrict__ avglog,
    float* __restrict__ out)
{
    __shared__ __align__(16) ushort Alds[128 * 72];
    __shared__ __align__(16) ushort Hlds[64 * 72];
    __shared__ float r1s[64], r2s[64];

    const int t = threadIdx.x;
    const int nb = blockIdx.x * 64;
    if (t < 64) {
        const int node = nb + t;
        float deg = 1.f;
        if (node < N_NODES) deg = fmaxf((float)cnt[node], 1.f);
        const float sl = logf(deg + 1.f);
        const float al = avglog[0];
        r1s[t] = sl / al;
        r2s[t] = al / sl;
    }

    const int w = t >> 6, l = t & 63;
    const int wr = w >> 1, wc = w & 1;   // wr: col half (64), wc: node half (32)
    const int quad = l >> 4, lr = l & 15;

    f32x4 comb[4][2];
    #pragma unroll
    for (int i = 0; i < 4; ++i)
        #pragma unroll
        for (int j = 0; j < 2; ++j) comb[i][j] = (f32x4){0.f, 0.f, 0.f, 0.f};

    #define STAGE_A(SL)                                                           \
        _Pragma("unroll")                                                         \
        for (int g = 0; g < 4; ++g) {                                             \
            const int idx = t + g * 256;                                          \
            const int row = idx >> 3, kk = (idx & 7) * 8;                         \
            *(uint4*)&Alds[row * 72 + kk] =                                       \
                *(const uint4*)(WaT + ((size_t)((SL) * 128 + row)) * 512 + k0 + kk); \
        }

    #define MFMA_EPOCH(SL)                                                        \
        {                                                                         \
            f32x4 acc[4][2];                                                      \
            _Pragma("unroll")                                                     \
            for (int i = 0; i < 4; ++i)                                           \
                _Pragma("unroll")                                                 \
                for (int j = 0; j < 2; ++j) acc[i][j] = (f32x4){0.f,0.f,0.f,0.f}; \
            _Pragma("unroll")                                                     \
            for (int s = 0; s < 2; ++s) {                                         \
                short8 av[4], bv[2];                                              \
                _Pragma("unroll")                                                 \
                for (int i = 0; i < 4; ++i)                                       \
                    av[i] = *(const short8*)&Alds[(wr*64 + i*16 + lr)*72 + s*32 + quad*8]; \
                _Pragma("unroll")                                                 \
                for (int j = 0; j < 2; ++j)                                       \
                    bv[j] = *(const short8*)&Hlds[(wc*32 + j*16 + lr)*72 + s*32 + quad*8]; \
                _Pragma("unroll")                                                 \
                for (int i = 0; i < 4; ++i)                                       \
                    _Pragma("unroll")                                             \
                    for (int j = 0; j < 2; ++j)                                   \
                        acc[i][j] = __builtin_amdgcn_mfma_f32_16x16x32_bf16(av[i], bv[j], acc[i][j], 0, 0, 0); \
            }                                                                     \
            _Pragma("unroll")                                                     \
            for (int j = 0; j < 2; ++j) {                                         \
                const int nl = wc * 32 + j * 16 + lr;                             \
                const float r = ((SL) == 0) ? 1.f : ((SL) == 1) ? r1s[nl] : r2s[nl]; \
                _Pragma("unroll")                                                 \
                for (int i = 0; i < 4; ++i) {                                     \
                    comb[i][j].x += r * acc[i][j].x;                              \
                    comb[i][j].y += r * acc[i][j].y;                              \
                    comb[i][j].z += r * acc[i][j].z;                              \
                    comb[i][j].w += r * acc[i][j].w;                              \
                }                                                                 \
            }                                                                     \
        }

    for (int kc = 0; kc < 8; ++kc) {
        const int k0 = kc * 64;
        __syncthreads();                       // prior readers of Alds/Hlds done
        #pragma unroll
        for (int g = 0; g < 2; ++g) {          // H: 64 rows x 64 k (once per kc)
            const int idx = t + g * 256;
            const int row = idx >> 3, kk = (idx & 7) * 8;
            const int node = nb + row;
            uint4 v = make_uint4(0u, 0u, 0u, 0u);
            if (node < N_NODES)
                v = *(const uint4*)(aggB + (size_t)node * 512 + k0 + kk);
            *(uint4*)&Hlds[row * 72 + kk] = v;
        }
        STAGE_A(0);
        __syncthreads();
        MFMA_EPOCH(0);
        __syncthreads();
        STAGE_A(1);
        __syncthreads();
        MFMA_EPOCH(1);
        __syncthreads();
        STAGE_A(2);
        __syncthreads();
        MFMA_EPOCH(2);
    }
    #undef STAGE_A
    #undef MFMA_EPOCH

    #pragma unroll
    for (int i = 0; i < 4; ++i) {
        const int col = wr * 64 + i * 16 + quad * 4;
        #pragma unroll
        for (int j = 0; j < 2; ++j) {
            const int node = nb + wc * 32 + j * 16 + lr;
            if (node < N_NODES) {
                float* op = out + (size_t)node * 128 + col;
                const float4 cur = *(const float4*)op;
                const f32x4 v = comb[i][j];
                *(float4*)op = make_float4(cur.x + v.x, cur.y + v.y,
                                           cur.z + v.z, cur.w + v.w);
            }
        }
    }
}

extern "C" void kernel_launch(void* const* d_in, const int* in_sizes, int n_in,
                              void* d_out, int out_size, void* d_ws, size_t ws_size,
                              hipStream_t stream) {
    const float* x     = (const float*)d_in[0];
    const float* eattr = (const float*)d_in[1];
    const float* Wee   = (const float*)d_in[2];
    const float* bee   = (const float*)d_in[3];
    const float* Wpre  = (const float*)d_in[4];
    const float* bpre  = (const float*)d_in[5];
    const float* Wpost = (const float*)d_in[6];
    const float* bpost = (const float*)d_in[7];
    const float* Wlin  = (const float*)d_in[8];
    const float* blin  = (const float*)d_in[9];
    const int*   ei    = (const int*)d_in[10];
    float* out = (float*)d_out;

    // workspace layout (~101.9 MB; ws_size >= 102.6 MB proven previously)
    ushort* aggB = (ushort*)d_ws;                         // N*512 bf16 (51.2 MB)
    ushort* Y1b  = aggB + (size_t)N_NODES * 512;          // N*128 bf16 (12.8 MB)
    ushort* Y2b  = Y1b  + (size_t)N_NODES * 128;          // N*128 bf16 (12.8 MB)
    ushort* WxT  = Y2b  + (size_t)N_NODES * 128;          // 384*128 bf16
    ushort* WaT  = WxT + 384 * 128;                       // 384*512 bf16
    float*  W4   = (float*)(WaT + 384 * 512);             // ED*D fp32
    float*  bp   = W4 + ED * D;                           // 128
    float*  b_comb = bp + D;                              // 128
    float*  avglog = b_comb + D;                          // 1 (+3 pad)
    int*   cnt      = (int*)(avglog + 4);                 // 50000
    int*   rowstart = cnt + N_NODES;                      // 50001 (+3 pad)
    int*   cursor   = rowstart + N_NODES + 4;             // 50000
    uint4* csr_rec  = (uint4*)(cursor + N_NODES);         // E*48B (24.0 MB), 16B-aligned
    int*   bsum     = (int*)(csr_rec + (size_t)N_EDGES * 3);  // 49
    float* blog     = (float*)(bsum + 64);                // 49
    int*   boff     = (int*)(blog + 64);                  // 49

    // fused weight-prep + cnt zeroing (roles: 104 fold / 1 small / 16 prep / 196 init)
    k_wprep<<<317, 256, 0, stream>>>(Wee, bee, Wpre, bpre, Wpost, bpost, Wlin, blin,
                                     W4, bp, WxT, WaT, b_comb, cnt);
    // fused hist + x-GEMMs (both depend only on k_wprep)
    k_hx<<<XGEMM_BLOCKS + HIST_BLOCKS, 256, 0, stream>>>(ei, cnt, x, WxT, b_comb,
                                                         Y1b, Y2b, out);
    k_scanA<<<SCAN_NTILES, 256, 0, stream>>>(cnt, bsum, blog);
    k_scanB<<<1, 64, 0, stream>>>(bsum, blog, boff, rowstart, avglog);
    k_scanC<<<SCAN_NTILES, 256, 0, stream>>>(cnt, boff, rowstart, cursor);
    k_scatter<<<(N_EDGES + 255) / 256, 256, 0, stream>>>(ei, eattr, cursor, csr_rec);
    k_pull<<<N_NODES / 4, 256, 0, stream>>>(csr_rec, W4, bp, Y1b, Y2b,
                                            rowstart, aggB);
    k_agg<<<(N_NODES + 63) / 64, 256, 0, stream>>>(aggB, WaT, cnt, avglog, out);
}

// Round 6
// 300.380 us; speedup vs baseline: 1.5099x; 1.0507x over previous
//
#include <hip/hip_runtime.h>
#include <hip/hip_bf16.h>
#include <float.h>
#include <math.h>

#define N_NODES 50000
#define N_EDGES 500000
#define D 128
#define ED 10
#define EPS_PNA 1e-5f
#define SCAN_NTILES 49     // ceil(50000 / 1024)
#define XGEMM_BLOCKS 391   // ceil(50000 / 128)
#define HIST_BLOCKS 1954   // ceil(500000 / 256)

typedef __hip_bfloat16 bf16;
typedef unsigned short ushort;
typedef unsigned int uint;
typedef __attribute__((ext_vector_type(8))) short short8;   // 8 bf16 (4 VGPRs)
typedef __attribute__((ext_vector_type(4))) float f32x4;    // MFMA C/D

__device__ __forceinline__ ushort f2bf(float f) {
    __hip_bfloat16 h = __float2bfloat16(f);
    return *reinterpret_cast<ushort*>(&h);
}
__device__ __forceinline__ float bf2f(ushort u) {
    return __uint_as_float(((uint)u) << 16);
}

// ---------------- K2a: per-tile reduce (sum + logsum), 1024 nodes/tile ----------------
__global__ __launch_bounds__(256) void k_scanA(const int* __restrict__ cnt,
                                               int* __restrict__ bsum,
                                               float* __restrict__ blog) {
    const int t = threadIdx.x;
    const int base = blockIdx.x * 1024;
    int s = 0; float ls = 0.f;
    #pragma unroll
    for (int k = 0; k < 4; ++k) {
        const int idx = base + t + k * 256;
        if (idx < N_NODES) {
            const int c = cnt[idx];
            s += c;
            ls += logf((float)c + 1.0f);
        }
    }
    #pragma unroll
    for (int off = 32; off > 0; off >>= 1) {
        s += __shfl_down(s, off, 64);
        ls += __shfl_down(ls, off, 64);
    }
    __shared__ int ws[4]; __shared__ float wl[4];
    const int wv = t >> 6, l = t & 63;
    if (l == 0) { ws[wv] = s; wl[wv] = ls; }
    __syncthreads();
    if (t == 0) {
        bsum[blockIdx.x] = ws[0] + ws[1] + ws[2] + ws[3];
        blog[blockIdx.x] = wl[0] + wl[1] + wl[2] + wl[3];
    }
}

// ---------------- K2c: per-tile scan; each block re-scans the 49 tile sums locally ----
// (absorbs old k_scanB: block 0 also writes avglog + rowstart[N_NODES])
__global__ __launch_bounds__(256) void k_scanC(const int* __restrict__ cnt,
                                               const int* __restrict__ bsum,
                                               const float* __restrict__ blog,
                                               int* __restrict__ rowstart,
                                               int* __restrict__ cursor,
                                               float* __restrict__ avglog) {
    const int t = threadIdx.x, lane = t & 63, wv = t >> 6;
    __shared__ int sboff;
    // wave 0: local scan of the 49 tile sums (cheap, redundant per block)
    if (t < 64) {
        const int v = (t < SCAN_NTILES) ? bsum[t] : 0;
        int s = v;
        #pragma unroll
        for (int off = 1; off < 64; off <<= 1) {
            const int u = __shfl_up(s, off, 64);
            if (t >= off) s += u;
        }
        if (t == blockIdx.x) sboff = s - v;                    // exclusive prefix
        if (blockIdx.x == 0 && t == SCAN_NTILES - 1)
            rowstart[N_NODES] = s;                             // grand total
        if (blockIdx.x == 0) {
            float lg = (t < SCAN_NTILES) ? blog[t] : 0.f;
            #pragma unroll
            for (int off = 32; off > 0; off >>= 1) lg += __shfl_down(lg, off, 64);
            if (t == 0) avglog[0] = lg * (1.0f / (float)N_NODES);
        }
    }
    const int base = blockIdx.x * 1024;
    int c[4]; int ts = 0;
    #pragma unroll
    for (int k = 0; k < 4; ++k) {
        const int idx = base + t * 4 + k;
        c[k] = (idx < N_NODES) ? cnt[idx] : 0;
        ts += c[k];
    }
    int s = ts;
    #pragma unroll
    for (int off = 1; off < 64; off <<= 1) {
        const int u = __shfl_up(s, off, 64);
        if (lane >= off) s += u;
    }
    __shared__ int wtot[4], woff[4];
    if (lane == 63) wtot[wv] = s;
    __syncthreads();
    if (t == 0) {
        int r = 0;
        #pragma unroll
        for (int i = 0; i < 4; ++i) { woff[i] = r; r += wtot[i]; }
    }
    __syncthreads();
    int excl = sboff + woff[wv] + (s - ts);
    #pragma unroll
    for (int k = 0; k < 4; ++k) {
        const int idx = base + t * 4 + k;
        if (idx < N_NODES) { rowstart[idx] = excl; cursor[idx] = excl; }
        excl += c[k];
    }
}

// ---------------- K3: bucket edges into CSR order as 48B self-contained records ----
// record = { float ea[10]; int src; int pad }  (3 x uint4, 16B aligned)
__global__ void k_scatter(const int* __restrict__ ei, const float* __restrict__ eattr,
                          int* __restrict__ cursor, uint4* __restrict__ csr_rec) {
    int e = blockIdx.x * blockDim.x + threadIdx.x;
    if (e < N_EDGES) {
        const int dst = ei[N_EDGES + e];
        const int src = ei[e];
        const float2* ea2 = (const float2*)(eattr + (size_t)e * ED);
        const float2 a0 = ea2[0], a1 = ea2[1], a2 = ea2[2], a3 = ea2[3], a4 = ea2[4];
        const int pos = atomicAdd(&cursor[dst], 1);
        uint4* o = csr_rec + (size_t)pos * 3;
        o[0] = make_uint4(__float_as_uint(a0.x), __float_as_uint(a0.y),
                          __float_as_uint(a1.x), __float_as_uint(a1.y));
        o[1] = make_uint4(__float_as_uint(a2.x), __float_as_uint(a2.y),
                          __float_as_uint(a3.x), __float_as_uint(a3.y));
        o[2] = make_uint4(__float_as_uint(a4.x), __float_as_uint(a4.y), (uint)src, 0u);
    }
}

// ---------------- K_wprep: fused weight-prep + cnt-init (role-dispatched by blockIdx) ----
__global__ __launch_bounds__(256) void k_wprep(
    const float* __restrict__ Wee, const float* __restrict__ bee,
    const float* __restrict__ Wpre, const float* __restrict__ bpre,
    const float* __restrict__ Wpost, const float* __restrict__ bpost,
    const float* __restrict__ Wlin, const float* __restrict__ blin,
    float* __restrict__ W4, float* __restrict__ bp,
    ushort* __restrict__ WxT,     // [384][128]
    ushort* __restrict__ WaT,     // [384][512]
    float* __restrict__ b_comb,
    int* __restrict__ cnt)
{
    __shared__ float smem[128 * 128];   // 64 KB, aliased per role
    const int t = threadIdx.x;
    const int bx = blockIdx.x;

    if (bx < 104) {
        float* Wl = smem;
        for (int i = t; i < 128 * 128 / 4; i += 256)
            ((float4*)Wl)[i] = ((const float4*)Wlin)[i];
        __syncthreads();
        const int j = t & 127, rp = t >> 7;
        const int kr0 = bx * 16 + rp * 8;
        for (int r = 0; r < 8; ++r) {
            const int kr = kr0 + r;
            const float* wrow = Wpost + (size_t)kr * 128;
            float acc = 0.f;
            #pragma unroll 8
            for (int m = 0; m < 128; ++m) acc += wrow[m] * Wl[m * 128 + j];
            const ushort v = f2bf(acc);
            if (kr < 128)       WxT[(256 + j) * 128 + kr] = v;
            else if (kr < 640)  WaT[(size_t)j * 512 + (kr - 128)] = v;
            else if (kr < 1152) WaT[(size_t)(128 + j) * 512 + (kr - 640)] = v;
            else                WaT[(size_t)(256 + j) * 512 + (kr - 1152)] = v;
        }
        if (bx == 0 && t < 128) {
            float acc = 0.f;
            #pragma unroll 8
            for (int m = 0; m < 128; ++m) acc += bpost[m] * Wl[m * 128 + t];
            b_comb[t] = acc + blin[t];
        }
    } else if (bx == 104) {
        float* wee_s = smem;                 // ED*D
        float* bee_s = smem + ED * D;        // D
        for (int i = t; i < ED * D; i += 256) wee_s[i] = Wee[i];
        if (t < 128) bee_s[t] = bee[t];
        __syncthreads();
        if (t < 128) {
            float acc[ED];
            #pragma unroll
            for (int r = 0; r < ED; ++r) acc[r] = 0.f;
            float bacc = 0.f;
            for (int k = 0; k < D; ++k) {
                const float w3 = Wpre[(size_t)(2 * D + k) * D + t];
                #pragma unroll
                for (int r = 0; r < ED; ++r) acc[r] += wee_s[r * D + k] * w3;
                bacc += bee_s[k] * w3;
            }
            #pragma unroll
            for (int r = 0; r < ED; ++r) W4[r * D + t] = acc[r];
            bp[t] = bpre[t] + bacc;
        }
    } else if (bx < 121) {
        const int slice = (bx < 113) ? 0 : 1;
        const int id = (bx - (slice ? 113 : 105)) * 256 + t;   // 0..2047
        const float* src = Wpre + (size_t)slice * 128 * 128;
        ushort* dst = WxT + (size_t)slice * 128 * 128;
        const int col = id & 127;
        const int k0 = (id >> 7) * 8;
        ushort tmp[8];
        #pragma unroll
        for (int r = 0; r < 8; ++r) tmp[r] = f2bf(src[(size_t)(k0 + r) * 128 + col]);
        *(uint4*)(dst + (size_t)col * 128 + k0) = *(uint4*)tmp;
    } else {
        const int i = (bx - 121) * 256 + t;
        if (i < N_NODES) cnt[i] = 0;
    }
}

// ---------------- K_hx: fused hist + xgemm (both depend only on k_wprep) -------------
__global__ __launch_bounds__(256) void k_hx(
    const int* __restrict__ ei, int* __restrict__ cnt,
    const float* __restrict__ x, const ushort* __restrict__ WxT,
    const float* __restrict__ b_comb,
    ushort* __restrict__ Y1b, ushort* __restrict__ Y2b, float* __restrict__ out)
{
    const int t = threadIdx.x;
    if (blockIdx.x >= XGEMM_BLOCKS) {
        const int e = (blockIdx.x - XGEMM_BLOCKS) * 256 + t;
        if (e < N_EDGES) atomicAdd(&cnt[ei[N_EDGES + e]], 1);
        return;
    }

    __shared__ __align__(16) ushort Alds[128 * 136];
    __shared__ __align__(16) ushort Hlds[128 * 136];
    const int nb = blockIdx.x * 128;

    #pragma unroll
    for (int g = 0; g < 8; ++g) {
        const int idx = t + g * 256;
        const int row = idx >> 4, kk = (idx & 15) * 8;
        const int node = nb + row;
        uint4 v = make_uint4(0u, 0u, 0u, 0u);
        if (node < N_NODES) {
            const float4 f0 = *(const float4*)(x + (size_t)node * 128 + kk);
            const float4 f1 = *(const float4*)(x + (size_t)node * 128 + kk + 4);
            __hip_bfloat162 p0 = __float22bfloat162_rn(make_float2(f0.x, f0.y));
            __hip_bfloat162 p1 = __float22bfloat162_rn(make_float2(f0.z, f0.w));
            __hip_bfloat162 p2 = __float22bfloat162_rn(make_float2(f1.x, f1.y));
            __hip_bfloat162 p3 = __float22bfloat162_rn(make_float2(f1.z, f1.w));
            v.x = *(uint*)&p0; v.y = *(uint*)&p1; v.z = *(uint*)&p2; v.w = *(uint*)&p3;
        }
        *(uint4*)&Hlds[row * 136 + kk] = v;
    }

    const int w = t >> 6, l = t & 63;
    const int wr = w >> 1, wc = w & 1;
    const int quad = l >> 4, lr = l & 15;

    for (int sy = 0; sy < 3; ++sy) {
        __syncthreads();
        #pragma unroll
        for (int g = 0; g < 8; ++g) {
            const int idx = t + g * 256;
            const int row = idx >> 4, kk = (idx & 15) * 8;
            *(uint4*)&Alds[row * 136 + kk] =
                *(const uint4*)(WxT + ((size_t)sy * 128 + row) * 128 + kk);
        }
        __syncthreads();

        f32x4 acc[4][4];
        #pragma unroll
        for (int i = 0; i < 4; ++i)
            #pragma unroll
            for (int j = 0; j < 4; ++j) acc[i][j] = (f32x4){0.f, 0.f, 0.f, 0.f};

        #pragma unroll
        for (int s = 0; s < 4; ++s) {
            short8 av[4], bv[4];
            #pragma unroll
            for (int i = 0; i < 4; ++i)
                av[i] = *(const short8*)&Alds[(wr * 64 + i * 16 + lr) * 136 + s * 32 + quad * 8];
            #pragma unroll
            for (int j = 0; j < 4; ++j)
                bv[j] = *(const short8*)&Hlds[(wc * 64 + j * 16 + lr) * 136 + s * 32 + quad * 8];
            #pragma unroll
            for (int i = 0; i < 4; ++i)
                #pragma unroll
                for (int j = 0; j < 4; ++j)
                    acc[i][j] = __builtin_amdgcn_mfma_f32_16x16x32_bf16(av[i], bv[j], acc[i][j], 0, 0, 0);
        }

        #pragma unroll
        for (int i = 0; i < 4; ++i) {
            const int col = wr * 64 + i * 16 + quad * 4;
            #pragma unroll
            for (int j = 0; j < 4; ++j) {
                const int node = nb + wc * 64 + j * 16 + lr;
                if (node < N_NODES) {
                    const f32x4 v = acc[i][j];
                    if (sy == 2) {
                        *(float4*)(out + (size_t)node * 128 + col) =
                            make_float4(v.x + b_comb[col],     v.y + b_comb[col + 1],
                                        v.z + b_comb[col + 2], v.w + b_comb[col + 3]);
                    } else {
                        ushort* dst = (sy == 0) ? Y1b : Y2b;
                        ushort pk[4];
                        pk[0] = f2bf(v.x); pk[1] = f2bf(v.y);
                        pk[2] = f2bf(v.z); pk[3] = f2bf(v.w);
                        *(uint2*)(dst + (size_t)node * 128 + col) = *(uint2*)pk;
                    }
                }
            }
        }
    }
}

// ---------------- K8: CSR pull aggregation -> agg bf16 [N][512] ----------------
// 1 wave/node, LDS W4, serial edge loop, 1-deep RECORD prefetch.
// r0/r1 forced wave-uniform via readfirstlane: loop counter, record loads and
// record registers move to the SCALAR pipe (s_load/SGPR), the Y2b gather gets a
// scalar row base, and each dot-product FMA takes one SGPR operand. Cuts per-edge
// VALU issue roughly in half.
__global__ __launch_bounds__(256) void k_pull(
    const uint4* __restrict__ csr_rec, const float* __restrict__ W4,
    const float* __restrict__ bp, const ushort* __restrict__ Y1b,
    const ushort* __restrict__ Y2b,
    const int* __restrict__ rowstart,
    ushort* __restrict__ aggB)
{
    __shared__ float2 w4s[ED][64];
    const int t = threadIdx.x;
    for (int i = t; i < ED * 64; i += 256)
        w4s[i >> 6][i & 63] = ((const float2*)W4)[i];
    __syncthreads();

    const int wv = t >> 6, l = t & 63;
    const int n = blockIdx.x * 4 + wv;
    const int r0 = __builtin_amdgcn_readfirstlane(rowstart[n]);
    const int r1 = __builtin_amdgcn_readfirstlane(rowstart[n + 1]);
    const int d = r1 - r0;

    float s0 = 0.f, s1 = 0.f, ss0 = 0.f, ss1 = 0.f;
    float mx0 = -FLT_MAX, mx1 = -FLT_MAX, mn0 = FLT_MAX, mn1 = FLT_MAX;
    const __hip_bfloat162* Y2p = (const __hip_bfloat162*)Y2b;

    uint4 ra, rb, rc;
    if (d > 0) {
        const uint4* rp = csr_rec + (size_t)r0 * 3;
        ra = rp[0]; rb = rp[1]; rc = rp[2];
    }
    for (int i = r0; i < r1; ++i) {
        const int inext = (i + 1 < r1) ? (i + 1) : i;   // uniform, branchless clamp
        const uint4* rp = csr_rec + (size_t)inext * 3;
        const uint4 na = rp[0], nb4 = rp[1], nc = rp[2];

        const int src = (int)rc.z;                       // uniform -> scalar row base
        const float2 y2 = __bfloat1622float2(Y2p[(size_t)src * 64 + l]);

        float ea[10];
        ea[0] = __uint_as_float(ra.x); ea[1] = __uint_as_float(ra.y);
        ea[2] = __uint_as_float(ra.z); ea[3] = __uint_as_float(ra.w);
        ea[4] = __uint_as_float(rb.x); ea[5] = __uint_as_float(rb.y);
        ea[6] = __uint_as_float(rb.z); ea[7] = __uint_as_float(rb.w);
        ea[8] = __uint_as_float(rc.x); ea[9] = __uint_as_float(rc.y);

        float q0 = 0.f, q1 = 0.f;
        #pragma unroll
        for (int r = 0; r < ED; ++r) {
            const float2 wv2 = w4s[r][l];
            q0 += ea[r] * wv2.x;
            q1 += ea[r] * wv2.y;
        }
        const float z0 = y2.x + q0, z1 = y2.y + q1;
        s0 += z0; s1 += z1;
        ss0 += z0 * z0; ss1 += z1 * z1;
        mx0 = fmaxf(mx0, z0); mx1 = fmaxf(mx1, z1);
        mn0 = fminf(mn0, z0); mn1 = fminf(mn1, z1);

        ra = na; rb = nb4; rc = nc;
    }

    const float2 bpw = ((const float2*)bp)[l];
    const float2 y1 = __bfloat1622float2(((const __hip_bfloat162*)Y1b)[(size_t)n * 64 + l]);
    float mean0, mean1, vmx0, vmx1, vmn0, vmn1, st0, st1;
    if (d > 0) {
        const float inv = 1.f / (float)d;
        const float mz0 = s0 * inv, mz1 = s1 * inv;
        const float c0 = y1.x + bpw.x, c1 = y1.y + bpw.y;
        mean0 = mz0 + c0; mean1 = mz1 + c1;
        st0 = sqrtf(fmaxf(ss0 * inv - mz0 * mz0, 0.f) + EPS_PNA);
        st1 = sqrtf(fmaxf(ss1 * inv - mz1 * mz1, 0.f) + EPS_PNA);
        vmx0 = mx0 + c0; vmx1 = mx1 + c1;
        vmn0 = mn0 + c0; vmn1 = mn1 + c1;
    } else {
        mean0 = mean1 = 0.f;
        vmx0 = vmx1 = vmn0 = vmn1 = 0.f;
        st0 = st1 = sqrtf(EPS_PNA);
    }
    __hip_bfloat162* aggv = (__hip_bfloat162*)aggB;
    const size_t b0 = (size_t)n * 256;
    aggv[b0 + l]       = __float22bfloat162_rn(make_float2(mean0, mean1));
    aggv[b0 + 64 + l]  = __float22bfloat162_rn(make_float2(vmx0, vmx1));
    aggv[b0 + 128 + l] = __float22bfloat162_rn(make_float2(vmn0, vmn1));
    aggv[b0 + 192 + l] = __float22bfloat162_rn(make_float2(st0, st1));
}

// ---------------- K9: MFMA agg-GEMM, kc-outer; accumulates INTO out (fp32 RMW) ------
__global__ __launch_bounds__(256) void k_agg(
    const ushort* __restrict__ aggB,  // [N][512] bf16
    const ushort* __restrict__ WaT,   // [384][512] bf16
    const int* __restrict__ cnt, const float* __restrict__ avglog,
    float* __restrict__ out)
{
    __shared__ __align__(16) ushort Alds[128 * 72];
    __shared__ __align__(16) ushort Hlds[64 * 72];
    __shared__ float r1s[64], r2s[64];

    const int t = threadIdx.x;
    const int nb = blockIdx.x * 64;
    if (t < 64) {
        const int node = nb + t;
        float deg = 1.f;
        if (node < N_NODES) deg = fmaxf((float)cnt[node], 1.f);
        const float sl = logf(deg + 1.f);
        const float al = avglog[0];
        r1s[t] = sl / al;
        r2s[t] = al / sl;
    }

    const int w = t >> 6, l = t & 63;
    const int wr = w >> 1, wc = w & 1;   // wr: col half (64), wc: node half (32)
    const int quad = l >> 4, lr = l & 15;

    f32x4 comb[4][2];
    #pragma unroll
    for (int i = 0; i < 4; ++i)
        #pragma unroll
        for (int j = 0; j < 2; ++j) comb[i][j] = (f32x4){0.f, 0.f, 0.f, 0.f};

    #define STAGE_A(SL)                                                           \
        _Pragma("unroll")                                                         \
        for (int g = 0; g < 4; ++g) {                                             \
            const int idx = t + g * 256;                                          \
            const int row = idx >> 3, kk = (idx & 7) * 8;                         \
            *(uint4*)&Alds[row * 72 + kk] =                                       \
                *(const uint4*)(WaT + ((size_t)((SL) * 128 + row)) * 512 + k0 + kk); \
        }

    #define MFMA_EPOCH(SL)                                                        \
        {                                                                         \
            f32x4 acc[4][2];                                                      \
            _Pragma("unroll")                                                     \
            for (int i = 0; i < 4; ++i)                                           \
                _Pragma("unroll")                                                 \
                for (int j = 0; j < 2; ++j) acc[i][j] = (f32x4){0.f,0.f,0.f,0.f}; \
            _Pragma("unroll")                                                     \
            for (int s = 0; s < 2; ++s) {                                         \
                short8 av[4], bv[2];                                              \
                _Pragma("unroll")                                                 \
                for (int i = 0; i < 4; ++i)                                       \
                    av[i] = *(const short8*)&Alds[(wr*64 + i*16 + lr)*72 + s*32 + quad*8]; \
                _Pragma("unroll")                                                 \
                for (int j = 0; j < 2; ++j)                                       \
                    bv[j] = *(const short8*)&Hlds[(wc*32 + j*16 + lr)*72 + s*32 + quad*8]; \
                _Pragma("unroll")                                                 \
                for (int i = 0; i < 4; ++i)                                       \
                    _Pragma("unroll")                                             \
                    for (int j = 0; j < 2; ++j)                                   \
                        acc[i][j] = __builtin_amdgcn_mfma_f32_16x16x32_bf16(av[i], bv[j], acc[i][j], 0, 0, 0); \
            }                                                                     \
            _Pragma("unroll")                                                     \
            for (int j = 0; j < 2; ++j) {                                         \
                const int nl = wc * 32 + j * 16 + lr;                             \
                const float r = ((SL) == 0) ? 1.f : ((SL) == 1) ? r1s[nl] : r2s[nl]; \
                _Pragma("unroll")                                                 \
                for (int i = 0; i < 4; ++i) {                                     \
                    comb[i][j].x += r * acc[i][j].x;                              \
                    comb[i][j].y += r * acc[i][j].y;                              \
                    comb[i][j].z += r * acc[i][j].z;                              \
                    comb[i][j].w += r * acc[i][j].w;                              \
                }                                                                 \
            }                                                                     \
        }

    for (int kc = 0; kc < 8; ++kc) {
        const int k0 = kc * 64;
        __syncthreads();
        #pragma unroll
        for (int g = 0; g < 2; ++g) {          // H: 64 rows x 64 k (once per kc)
            const int idx = t + g * 256;
            const int row = idx >> 3, kk = (idx & 7) * 8;
            const int node = nb + row;
            uint4 v = make_uint4(0u, 0u, 0u, 0u);
            if (node < N_NODES)
                v = *(const uint4*)(aggB + (size_t)node * 512 + k0 + kk);
            *(uint4*)&Hlds[row * 72 + kk] = v;
        }
        STAGE_A(0);
        __syncthreads();
        MFMA_EPOCH(0);
        __syncthreads();
        STAGE_A(1);
        __syncthreads();
        MFMA_EPOCH(1);
        __syncthreads();
        STAGE_A(2);
        __syncthreads();
        MFMA_EPOCH(2);
    }
    #undef STAGE_A
    #undef MFMA_EPOCH

    #pragma unroll
    for (int i = 0; i < 4; ++i) {
        const int col = wr * 64 + i * 16 + quad * 4;
        #pragma unroll
        for (int j = 0; j < 2; ++j) {
            const int node = nb + wc * 32 + j * 16 + lr;
            if (node < N_NODES) {
                float* op = out + (size_t)node * 128 + col;
                const float4 cur = *(const float4*)op;
                const f32x4 v = comb[i][j];
                *(float4*)op = make_float4(cur.x + v.x, cur.y + v.y,
                                           cur.z + v.z, cur.w + v.w);
            }
        }
    }
}

extern "C" void kernel_launch(void* const* d_in, const int* in_sizes, int n_in,
                              void* d_out, int out_size, void* d_ws, size_t ws_size,
                              hipStream_t stream) {
    const float* x     = (const float*)d_in[0];
    const float* eattr = (const float*)d_in[1];
    const float* Wee   = (const float*)d_in[2];
    const float* bee   = (const float*)d_in[3];
    const float* Wpre  = (const float*)d_in[4];
    const float* bpre  = (const float*)d_in[5];
    const float* Wpost = (const float*)d_in[6];
    const float* bpost = (const float*)d_in[7];
    const float* Wlin  = (const float*)d_in[8];
    const float* blin  = (const float*)d_in[9];
    const int*   ei    = (const int*)d_in[10];
    float* out = (float*)d_out;

    // workspace layout (~101.9 MB; ws_size >= 102.6 MB proven previously)
    ushort* aggB = (ushort*)d_ws;                         // N*512 bf16 (51.2 MB)
    ushort* Y1b  = aggB + (size_t)N_NODES * 512;          // N*128 bf16 (12.8 MB)
    ushort* Y2b  = Y1b  + (size_t)N_NODES * 128;          // N*128 bf16 (12.8 MB)
    ushort* WxT  = Y2b  + (size_t)N_NODES * 128;          // 384*128 bf16
    ushort* WaT  = WxT + 384 * 128;                       // 384*512 bf16
    float*  W4   = (float*)(WaT + 384 * 512);             // ED*D fp32
    float*  bp   = W4 + ED * D;                           // 128
    float*  b_comb = bp + D;                              // 128
    float*  avglog = b_comb + D;                          // 1 (+3 pad)
    int*   cnt      = (int*)(avglog + 4);                 // 50000
    int*   rowstart = cnt + N_NODES;                      // 50001 (+3 pad)
    int*   cursor   = rowstart + N_NODES + 4;             // 50000
    uint4* csr_rec  = (uint4*)(cursor + N_NODES);         // E*48B (24.0 MB), 16B-aligned
    int*   bsum     = (int*)(csr_rec + (size_t)N_EDGES * 3);  // 49
    float* blog     = (float*)(bsum + 64);                // 49

    k_wprep<<<317, 256, 0, stream>>>(Wee, bee, Wpre, bpre, Wpost, bpost, Wlin, blin,
                                     W4, bp, WxT, WaT, b_comb, cnt);
    k_hx<<<XGEMM_BLOCKS + HIST_BLOCKS, 256, 0, stream>>>(ei, cnt, x, WxT, b_comb,
                                                         Y1b, Y2b, out);
    k_scanA<<<SCAN_NTILES, 256, 0, stream>>>(cnt, bsum, blog);
    k_scanC<<<SCAN_NTILES, 256, 0, stream>>>(cnt, bsum, blog, rowstart, cursor, avglog);
    k_scatter<<<(N_EDGES + 255) / 256, 256, 0, stream>>>(ei, eattr, cursor, csr_rec);
    k_pull<<<N_NODES / 4, 256, 0, stream>>>(csr_rec, W4, bp, Y1b, Y2b,
                                            rowstart, aggB);
    k_agg<<<(N_NODES + 63) / 64, 256, 0, stream>>>(aggB, WaT, cnt, avglog, out);
}

// Round 7
// 293.868 us; speedup vs baseline: 1.5433x; 1.0222x over previous
//
#include <hip/hip_runtime.h>
#include <hip/hip_bf16.h>
#include <float.h>
#include <math.h>

#define N_NODES 50000
#define N_EDGES 500000
#define D 128
#define ED 10
#define EPS_PNA 1e-5f
#define SCAN_NTILES 49     // ceil(50000 / 1024)
#define XGEMM_BLOCKS 391   // ceil(50000 / 128)
#define HIST_BLOCKS 1954   // ceil(500000 / 256)

typedef __hip_bfloat16 bf16;
typedef unsigned short ushort;
typedef unsigned int uint;
typedef __attribute__((ext_vector_type(8))) short short8;   // 8 bf16 (4 VGPRs)
typedef __attribute__((ext_vector_type(4))) float f32x4;    // MFMA C/D

__device__ __forceinline__ ushort f2bf(float f) {
    __hip_bfloat16 h = __float2bfloat16(f);
    return *reinterpret_cast<ushort*>(&h);
}
__device__ __forceinline__ float bf2f(ushort u) {
    return __uint_as_float(((uint)u) << 16);
}

// ---------------- K2a: per-tile reduce (sum + logsum), 1024 nodes/tile ----------------
__global__ __launch_bounds__(256) void k_scanA(const int* __restrict__ cnt,
                                               int* __restrict__ bsum,
                                               float* __restrict__ blog) {
    const int t = threadIdx.x;
    const int base = blockIdx.x * 1024;
    int s = 0; float ls = 0.f;
    #pragma unroll
    for (int k = 0; k < 4; ++k) {
        const int idx = base + t + k * 256;
        if (idx < N_NODES) {
            const int c = cnt[idx];
            s += c;
            ls += logf((float)c + 1.0f);
        }
    }
    #pragma unroll
    for (int off = 32; off > 0; off >>= 1) {
        s += __shfl_down(s, off, 64);
        ls += __shfl_down(ls, off, 64);
    }
    __shared__ int ws[4]; __shared__ float wl[4];
    const int wv = t >> 6, l = t & 63;
    if (l == 0) { ws[wv] = s; wl[wv] = ls; }
    __syncthreads();
    if (t == 0) {
        bsum[blockIdx.x] = ws[0] + ws[1] + ws[2] + ws[3];
        blog[blockIdx.x] = wl[0] + wl[1] + wl[2] + wl[3];
    }
}

// ---------------- K2c: per-tile scan; each block re-scans the 49 tile sums locally ----
__global__ __launch_bounds__(256) void k_scanC(const int* __restrict__ cnt,
                                               const int* __restrict__ bsum,
                                               const float* __restrict__ blog,
                                               int* __restrict__ rowstart,
                                               int* __restrict__ cursor,
                                               float* __restrict__ avglog) {
    const int t = threadIdx.x, lane = t & 63, wv = t >> 6;
    __shared__ int sboff;
    if (t < 64) {
        const int v = (t < SCAN_NTILES) ? bsum[t] : 0;
        int s = v;
        #pragma unroll
        for (int off = 1; off < 64; off <<= 1) {
            const int u = __shfl_up(s, off, 64);
            if (t >= off) s += u;
        }
        if (t == blockIdx.x) sboff = s - v;                    // exclusive prefix
        if (blockIdx.x == 0 && t == SCAN_NTILES - 1)
            rowstart[N_NODES] = s;                             // grand total
        if (blockIdx.x == 0) {
            float lg = (t < SCAN_NTILES) ? blog[t] : 0.f;
            #pragma unroll
            for (int off = 32; off > 0; off >>= 1) lg += __shfl_down(lg, off, 64);
            if (t == 0) avglog[0] = lg * (1.0f / (float)N_NODES);
        }
    }
    const int base = blockIdx.x * 1024;
    int c[4]; int ts = 0;
    #pragma unroll
    for (int k = 0; k < 4; ++k) {
        const int idx = base + t * 4 + k;
        c[k] = (idx < N_NODES) ? cnt[idx] : 0;
        ts += c[k];
    }
    int s = ts;
    #pragma unroll
    for (int off = 1; off < 64; off <<= 1) {
        const int u = __shfl_up(s, off, 64);
        if (lane >= off) s += u;
    }
    __shared__ int wtot[4], woff[4];
    if (lane == 63) wtot[wv] = s;
    __syncthreads();
    if (t == 0) {
        int r = 0;
        #pragma unroll
        for (int i = 0; i < 4; ++i) { woff[i] = r; r += wtot[i]; }
    }
    __syncthreads();
    int excl = sboff + woff[wv] + (s - ts);
    #pragma unroll
    for (int k = 0; k < 4; ++k) {
        const int idx = base + t * 4 + k;
        if (idx < N_NODES) { rowstart[idx] = excl; cursor[idx] = excl; }
        excl += c[k];
    }
}

// ---------------- K3: bucket edges into CSR order as 48B self-contained records ----
__global__ void k_scatter(const int* __restrict__ ei, const float* __restrict__ eattr,
                          int* __restrict__ cursor, uint4* __restrict__ csr_rec) {
    int e = blockIdx.x * blockDim.x + threadIdx.x;
    if (e < N_EDGES) {
        const int dst = ei[N_EDGES + e];
        const int src = ei[e];
        const float2* ea2 = (const float2*)(eattr + (size_t)e * ED);
        const float2 a0 = ea2[0], a1 = ea2[1], a2 = ea2[2], a3 = ea2[3], a4 = ea2[4];
        const int pos = atomicAdd(&cursor[dst], 1);
        uint4* o = csr_rec + (size_t)pos * 3;
        o[0] = make_uint4(__float_as_uint(a0.x), __float_as_uint(a0.y),
                          __float_as_uint(a1.x), __float_as_uint(a1.y));
        o[1] = make_uint4(__float_as_uint(a2.x), __float_as_uint(a2.y),
                          __float_as_uint(a3.x), __float_as_uint(a3.y));
        o[2] = make_uint4(__float_as_uint(a4.x), __float_as_uint(a4.y), (uint)src, 0u);
    }
}

// ---------------- K_wprep: fused weight-prep + cnt-init (role-dispatched by blockIdx) ----
__global__ __launch_bounds__(256) void k_wprep(
    const float* __restrict__ Wee, const float* __restrict__ bee,
    const float* __restrict__ Wpre, const float* __restrict__ bpre,
    const float* __restrict__ Wpost, const float* __restrict__ bpost,
    const float* __restrict__ Wlin, const float* __restrict__ blin,
    float* __restrict__ W4, float* __restrict__ bp,
    ushort* __restrict__ WxT,     // [384][128]
    ushort* __restrict__ WaT,     // [384][512]
    float* __restrict__ b_comb,
    int* __restrict__ cnt)
{
    __shared__ float smem[128 * 128];   // 64 KB, aliased per role
    const int t = threadIdx.x;
    const int bx = blockIdx.x;

    if (bx < 104) {
        float* Wl = smem;
        for (int i = t; i < 128 * 128 / 4; i += 256)
            ((float4*)Wl)[i] = ((const float4*)Wlin)[i];
        __syncthreads();
        const int j = t & 127, rp = t >> 7;
        const int kr0 = bx * 16 + rp * 8;
        for (int r = 0; r < 8; ++r) {
            const int kr = kr0 + r;
            const float* wrow = Wpost + (size_t)kr * 128;
            float acc = 0.f;
            #pragma unroll 8
            for (int m = 0; m < 128; ++m) acc += wrow[m] * Wl[m * 128 + j];
            const ushort v = f2bf(acc);
            if (kr < 128)       WxT[(256 + j) * 128 + kr] = v;
            else if (kr < 640)  WaT[(size_t)j * 512 + (kr - 128)] = v;
            else if (kr < 1152) WaT[(size_t)(128 + j) * 512 + (kr - 640)] = v;
            else                WaT[(size_t)(256 + j) * 512 + (kr - 1152)] = v;
        }
        if (bx == 0 && t < 128) {
            float acc = 0.f;
            #pragma unroll 8
            for (int m = 0; m < 128; ++m) acc += bpost[m] * Wl[m * 128 + t];
            b_comb[t] = acc + blin[t];
        }
    } else if (bx == 104) {
        float* wee_s = smem;                 // ED*D
        float* bee_s = smem + ED * D;        // D
        for (int i = t; i < ED * D; i += 256) wee_s[i] = Wee[i];
        if (t < 128) bee_s[t] = bee[t];
        __syncthreads();
        if (t < 128) {
            float acc[ED];
            #pragma unroll
            for (int r = 0; r < ED; ++r) acc[r] = 0.f;
            float bacc = 0.f;
            for (int k = 0; k < D; ++k) {
                const float w3 = Wpre[(size_t)(2 * D + k) * D + t];
                #pragma unroll
                for (int r = 0; r < ED; ++r) acc[r] += wee_s[r * D + k] * w3;
                bacc += bee_s[k] * w3;
            }
            #pragma unroll
            for (int r = 0; r < ED; ++r) W4[r * D + t] = acc[r];
            bp[t] = bpre[t] + bacc;
        }
    } else if (bx < 121) {
        const int slice = (bx < 113) ? 0 : 1;
        const int id = (bx - (slice ? 113 : 105)) * 256 + t;   // 0..2047
        const float* src = Wpre + (size_t)slice * 128 * 128;
        ushort* dst = WxT + (size_t)slice * 128 * 128;
        const int col = id & 127;
        const int k0 = (id >> 7) * 8;
        ushort tmp[8];
        #pragma unroll
        for (int r = 0; r < 8; ++r) tmp[r] = f2bf(src[(size_t)(k0 + r) * 128 + col]);
        *(uint4*)(dst + (size_t)col * 128 + k0) = *(uint4*)tmp;
    } else {
        const int i = (bx - 121) * 256 + t;
        if (i < N_NODES) cnt[i] = 0;
    }
}

// ---------------- K_hx: fused hist + xgemm (both depend only on k_wprep) -------------
__global__ __launch_bounds__(256) void k_hx(
    const int* __restrict__ ei, int* __restrict__ cnt,
    const float* __restrict__ x, const ushort* __restrict__ WxT,
    const float* __restrict__ b_comb,
    ushort* __restrict__ Y1b, ushort* __restrict__ Y2b, float* __restrict__ out)
{
    const int t = threadIdx.x;
    if (blockIdx.x >= XGEMM_BLOCKS) {
        const int e = (blockIdx.x - XGEMM_BLOCKS) * 256 + t;
        if (e < N_EDGES) atomicAdd(&cnt[ei[N_EDGES + e]], 1);
        return;
    }

    __shared__ __align__(16) ushort Alds[128 * 136];
    __shared__ __align__(16) ushort Hlds[128 * 136];
    const int nb = blockIdx.x * 128;

    #pragma unroll
    for (int g = 0; g < 8; ++g) {
        const int idx = t + g * 256;
        const int row = idx >> 4, kk = (idx & 15) * 8;
        const int node = nb + row;
        uint4 v = make_uint4(0u, 0u, 0u, 0u);
        if (node < N_NODES) {
            const float4 f0 = *(const float4*)(x + (size_t)node * 128 + kk);
            const float4 f1 = *(const float4*)(x + (size_t)node * 128 + kk + 4);
            __hip_bfloat162 p0 = __float22bfloat162_rn(make_float2(f0.x, f0.y));
            __hip_bfloat162 p1 = __float22bfloat162_rn(make_float2(f0.z, f0.w));
            __hip_bfloat162 p2 = __float22bfloat162_rn(make_float2(f1.x, f1.y));
            __hip_bfloat162 p3 = __float22bfloat162_rn(make_float2(f1.z, f1.w));
            v.x = *(uint*)&p0; v.y = *(uint*)&p1; v.z = *(uint*)&p2; v.w = *(uint*)&p3;
        }
        *(uint4*)&Hlds[row * 136 + kk] = v;
    }

    const int w = t >> 6, l = t & 63;
    const int wr = w >> 1, wc = w & 1;
    const int quad = l >> 4, lr = l & 15;

    for (int sy = 0; sy < 3; ++sy) {
        __syncthreads();
        #pragma unroll
        for (int g = 0; g < 8; ++g) {
            const int idx = t + g * 256;
            const int row = idx >> 4, kk = (idx & 15) * 8;
            *(uint4*)&Alds[row * 136 + kk] =
                *(const uint4*)(WxT + ((size_t)sy * 128 + row) * 128 + kk);
        }
        __syncthreads();

        f32x4 acc[4][4];
        #pragma unroll
        for (int i = 0; i < 4; ++i)
            #pragma unroll
            for (int j = 0; j < 4; ++j) acc[i][j] = (f32x4){0.f, 0.f, 0.f, 0.f};

        #pragma unroll
        for (int s = 0; s < 4; ++s) {
            short8 av[4], bv[4];
            #pragma unroll
            for (int i = 0; i < 4; ++i)
                av[i] = *(const short8*)&Alds[(wr * 64 + i * 16 + lr) * 136 + s * 32 + quad * 8];
            #pragma unroll
            for (int j = 0; j < 4; ++j)
                bv[j] = *(const short8*)&Hlds[(wc * 64 + j * 16 + lr) * 136 + s * 32 + quad * 8];
            #pragma unroll
            for (int i = 0; i < 4; ++i)
                #pragma unroll
                for (int j = 0; j < 4; ++j)
                    acc[i][j] = __builtin_amdgcn_mfma_f32_16x16x32_bf16(av[i], bv[j], acc[i][j], 0, 0, 0);
        }

        #pragma unroll
        for (int i = 0; i < 4; ++i) {
            const int col = wr * 64 + i * 16 + quad * 4;
            #pragma unroll
            for (int j = 0; j < 4; ++j) {
                const int node = nb + wc * 64 + j * 16 + lr;
                if (node < N_NODES) {
                    const f32x4 v = acc[i][j];
                    if (sy == 2) {
                        *(float4*)(out + (size_t)node * 128 + col) =
                            make_float4(v.x + b_comb[col],     v.y + b_comb[col + 1],
                                        v.z + b_comb[col + 2], v.w + b_comb[col + 3]);
                    } else {
                        ushort* dst = (sy == 0) ? Y1b : Y2b;
                        ushort pk[4];
                        pk[0] = f2bf(v.x); pk[1] = f2bf(v.y);
                        pk[2] = f2bf(v.z); pk[3] = f2bf(v.w);
                        *(uint2*)(dst + (size_t)node * 128 + col) = *(uint2*)pk;
                    }
                }
            }
        }
    }
}

// ---------------- K8: CSR pull aggregation -> agg bf16 [N][512] ----------------
// Round-6 proven structure (scalarized records). UNCHANGED.
__global__ __launch_bounds__(256) void k_pull(
    const uint4* __restrict__ csr_rec, const float* __restrict__ W4,
    const float* __restrict__ bp, const ushort* __restrict__ Y1b,
    const ushort* __restrict__ Y2b,
    const int* __restrict__ rowstart,
    ushort* __restrict__ aggB)
{
    __shared__ float2 w4s[ED][64];
    const int t = threadIdx.x;
    for (int i = t; i < ED * 64; i += 256)
        w4s[i >> 6][i & 63] = ((const float2*)W4)[i];
    __syncthreads();

    const int wv = t >> 6, l = t & 63;
    const int n = blockIdx.x * 4 + wv;
    const int r0 = __builtin_amdgcn_readfirstlane(rowstart[n]);
    const int r1 = __builtin_amdgcn_readfirstlane(rowstart[n + 1]);
    const int d = r1 - r0;

    float s0 = 0.f, s1 = 0.f, ss0 = 0.f, ss1 = 0.f;
    float mx0 = -FLT_MAX, mx1 = -FLT_MAX, mn0 = FLT_MAX, mn1 = FLT_MAX;
    const __hip_bfloat162* Y2p = (const __hip_bfloat162*)Y2b;

    uint4 ra, rb, rc;
    if (d > 0) {
        const uint4* rp = csr_rec + (size_t)r0 * 3;
        ra = rp[0]; rb = rp[1]; rc = rp[2];
    }
    for (int i = r0; i < r1; ++i) {
        const int inext = (i + 1 < r1) ? (i + 1) : i;   // uniform, branchless clamp
        const uint4* rp = csr_rec + (size_t)inext * 3;
        const uint4 na = rp[0], nb4 = rp[1], nc = rp[2];

        const int src = (int)rc.z;                       // uniform -> scalar row base
        const float2 y2 = __bfloat1622float2(Y2p[(size_t)src * 64 + l]);

        float ea[10];
        ea[0] = __uint_as_float(ra.x); ea[1] = __uint_as_float(ra.y);
        ea[2] = __uint_as_float(ra.z); ea[3] = __uint_as_float(ra.w);
        ea[4] = __uint_as_float(rb.x); ea[5] = __uint_as_float(rb.y);
        ea[6] = __uint_as_float(rb.z); ea[7] = __uint_as_float(rb.w);
        ea[8] = __uint_as_float(rc.x); ea[9] = __uint_as_float(rc.y);

        float q0 = 0.f, q1 = 0.f;
        #pragma unroll
        for (int r = 0; r < ED; ++r) {
            const float2 wv2 = w4s[r][l];
            q0 += ea[r] * wv2.x;
            q1 += ea[r] * wv2.y;
        }
        const float z0 = y2.x + q0, z1 = y2.y + q1;
        s0 += z0; s1 += z1;
        ss0 += z0 * z0; ss1 += z1 * z1;
        mx0 = fmaxf(mx0, z0); mx1 = fmaxf(mx1, z1);
        mn0 = fminf(mn0, z0); mn1 = fminf(mn1, z1);

        ra = na; rb = nb4; rc = nc;
    }

    const float2 bpw = ((const float2*)bp)[l];
    const float2 y1 = __bfloat1622float2(((const __hip_bfloat162*)Y1b)[(size_t)n * 64 + l]);
    float mean0, mean1, vmx0, vmx1, vmn0, vmn1, st0, st1;
    if (d > 0) {
        const float inv = 1.f / (float)d;
        const float mz0 = s0 * inv, mz1 = s1 * inv;
        const float c0 = y1.x + bpw.x, c1 = y1.y + bpw.y;
        mean0 = mz0 + c0; mean1 = mz1 + c1;
        st0 = sqrtf(fmaxf(ss0 * inv - mz0 * mz0, 0.f) + EPS_PNA);
        st1 = sqrtf(fmaxf(ss1 * inv - mz1 * mz1, 0.f) + EPS_PNA);
        vmx0 = mx0 + c0; vmx1 = mx1 + c1;
        vmn0 = mn0 + c0; vmn1 = mn1 + c1;
    } else {
        mean0 = mean1 = 0.f;
        vmx0 = vmx1 = vmn0 = vmn1 = 0.f;
        st0 = st1 = sqrtf(EPS_PNA);
    }
    __hip_bfloat162* aggv = (__hip_bfloat162*)aggB;
    const size_t b0 = (size_t)n * 256;
    aggv[b0 + l]       = __float22bfloat162_rn(make_float2(mean0, mean1));
    aggv[b0 + 64 + l]  = __float22bfloat162_rn(make_float2(vmx0, vmx1));
    aggv[b0 + 128 + l] = __float22bfloat162_rn(make_float2(vmn0, vmn1));
    aggv[b0 + 192 + l] = __float22bfloat162_rn(make_float2(st0, st1));
}

// ---------------- K9: MFMA agg-GEMM v2 -------------------------------------------
// All 3 A-slices staged per kc (one barrier pair, 48 MFMA/wave between barriers);
// three persistent accumulators acc[3][4][2] (statically indexed), scale fold
// moved entirely to the epilogue: out += acc0 + r1*acc1 + r2*acc2.
__global__ __launch_bounds__(256) void k_agg(
    const ushort* __restrict__ aggB,  // [N][512] bf16
    const ushort* __restrict__ WaT,   // [384][512] bf16
    const int* __restrict__ cnt, const float* __restrict__ avglog,
    float* __restrict__ out)
{
    __shared__ __align__(16) ushort Alds[3][128 * 72];   // 55.3 KB
    __shared__ __align__(16) ushort Hlds[64 * 72];       //  9.2 KB
    __shared__ float r1s[64], r2s[64];

    const int t = threadIdx.x;
    const int nb = blockIdx.x * 64;
    if (t < 64) {
        const int node = nb + t;
        float deg = 1.f;
        if (node < N_NODES) deg = fmaxf((float)cnt[node], 1.f);
        const float sl = logf(deg + 1.f);
        const float al = avglog[0];
        r1s[t] = sl / al;
        r2s[t] = al / sl;
    }

    const int w = t >> 6, l = t & 63;
    const int wr = w >> 1, wc = w & 1;   // wr: col half (64), wc: node half (32)
    const int quad = l >> 4, lr = l & 15;

    f32x4 acc[3][4][2];
    #pragma unroll
    for (int sl = 0; sl < 3; ++sl)
        #pragma unroll
        for (int i = 0; i < 4; ++i)
            #pragma unroll
            for (int j = 0; j < 2; ++j) acc[sl][i][j] = (f32x4){0.f, 0.f, 0.f, 0.f};

    for (int kc = 0; kc < 8; ++kc) {
        const int k0 = kc * 64;
        __syncthreads();                       // prior epoch's LDS reads done
        #pragma unroll
        for (int g = 0; g < 2; ++g) {          // H: 64 rows x 64 k
            const int idx = t + g * 256;
            const int row = idx >> 3, kk = (idx & 7) * 8;
            const int node = nb + row;
            uint4 v = make_uint4(0u, 0u, 0u, 0u);
            if (node < N_NODES)
                v = *(const uint4*)(aggB + (size_t)node * 512 + k0 + kk);
            *(uint4*)&Hlds[row * 72 + kk] = v;
        }
        #pragma unroll
        for (int sl = 0; sl < 3; ++sl) {       // A: 3 x (128 rows x 64 k)
            #pragma unroll
            for (int g = 0; g < 4; ++g) {
                const int idx = t + g * 256;
                const int row = idx >> 3, kk = (idx & 7) * 8;
                *(uint4*)&Alds[sl][row * 72 + kk] =
                    *(const uint4*)(WaT + ((size_t)(sl * 128 + row)) * 512 + k0 + kk);
            }
        }
        __syncthreads();                       // staged data visible
        #pragma unroll
        for (int sl = 0; sl < 3; ++sl) {
            #pragma unroll
            for (int s = 0; s < 2; ++s) {
                short8 av[4], bv[2];
                #pragma unroll
                for (int i = 0; i < 4; ++i)
                    av[i] = *(const short8*)&Alds[sl][(wr * 64 + i * 16 + lr) * 72 + s * 32 + quad * 8];
                #pragma unroll
                for (int j = 0; j < 2; ++j)
                    bv[j] = *(const short8*)&Hlds[(wc * 32 + j * 16 + lr) * 72 + s * 32 + quad * 8];
                #pragma unroll
                for (int i = 0; i < 4; ++i)
                    #pragma unroll
                    for (int j = 0; j < 2; ++j)
                        acc[sl][i][j] = __builtin_amdgcn_mfma_f32_16x16x32_bf16(av[i], bv[j], acc[sl][i][j], 0, 0, 0);
            }
        }
    }

    #pragma unroll
    for (int i = 0; i < 4; ++i) {
        const int col = wr * 64 + i * 16 + quad * 4;
        #pragma unroll
        for (int j = 0; j < 2; ++j) {
            const int node = nb + wc * 32 + j * 16 + lr;
            if (node < N_NODES) {
                const int nl = wc * 32 + j * 16 + lr;
                const float r1 = r1s[nl], r2 = r2s[nl];
                float* op = out + (size_t)node * 128 + col;
                const float4 cur = *(const float4*)op;
                const f32x4 a0 = acc[0][i][j];
                const f32x4 a1 = acc[1][i][j];
                const f32x4 a2 = acc[2][i][j];
                *(float4*)op = make_float4(
                    cur.x + a0.x + r1 * a1.x + r2 * a2.x,
                    cur.y + a0.y + r1 * a1.y + r2 * a2.y,
                    cur.z + a0.z + r1 * a1.z + r2 * a2.z,
                    cur.w + a0.w + r1 * a1.w + r2 * a2.w);
            }
        }
    }
}

extern "C" void kernel_launch(void* const* d_in, const int* in_sizes, int n_in,
                              void* d_out, int out_size, void* d_ws, size_t ws_size,
                              hipStream_t stream) {
    const float* x     = (const float*)d_in[0];
    const float* eattr = (const float*)d_in[1];
    const float* Wee   = (const float*)d_in[2];
    const float* bee   = (const float*)d_in[3];
    const float* Wpre  = (const float*)d_in[4];
    const float* bpre  = (const float*)d_in[5];
    const float* Wpost = (const float*)d_in[6];
    const float* bpost = (const float*)d_in[7];
    const float* Wlin  = (const float*)d_in[8];
    const float* blin  = (const float*)d_in[9];
    const int*   ei    = (const int*)d_in[10];
    float* out = (float*)d_out;

    // workspace layout (~101.9 MB; ws_size >= 102.6 MB proven previously)
    ushort* aggB = (ushort*)d_ws;                         // N*512 bf16 (51.2 MB)
    ushort* Y1b  = aggB + (size_t)N_NODES * 512;          // N*128 bf16 (12.8 MB)
    ushort* Y2b  = Y1b  + (size_t)N_NODES * 128;          // N*128 bf16 (12.8 MB)
    ushort* WxT  = Y2b  + (size_t)N_NODES * 128;          // 384*128 bf16
    ushort* WaT  = WxT + 384 * 128;                       // 384*512 bf16
    float*  W4   = (float*)(WaT + 384 * 512);             // ED*D fp32
    float*  bp   = W4 + ED * D;                           // 128
    float*  b_comb = bp + D;                              // 128
    float*  avglog = b_comb + D;                          // 1 (+3 pad)
    int*   cnt      = (int*)(avglog + 4);                 // 50000
    int*   rowstart = cnt + N_NODES;                      // 50001 (+3 pad)
    int*   cursor   = rowstart + N_NODES + 4;             // 50000
    uint4* csr_rec  = (uint4*)(cursor + N_NODES);         // E*48B (24.0 MB), 16B-aligned
    int*   bsum     = (int*)(csr_rec + (size_t)N_EDGES * 3);  // 49
    float* blog     = (float*)(bsum + 64);                // 49

    k_wprep<<<317, 256, 0, stream>>>(Wee, bee, Wpre, bpre, Wpost, bpost, Wlin, blin,
                                     W4, bp, WxT, WaT, b_comb, cnt);
    k_hx<<<XGEMM_BLOCKS + HIST_BLOCKS, 256, 0, stream>>>(ei, cnt, x, WxT, b_comb,
                                                         Y1b, Y2b, out);
    k_scanA<<<SCAN_NTILES, 256, 0, stream>>>(cnt, bsum, blog);
    k_scanC<<<SCAN_NTILES, 256, 0, stream>>>(cnt, bsum, blog, rowstart, cursor, avglog);
    k_scatter<<<(N_EDGES + 255) / 256, 256, 0, stream>>>(ei, eattr, cursor, csr_rec);
    k_pull<<<N_NODES / 4, 256, 0, stream>>>(csr_rec, W4, bp, Y1b, Y2b,
                                            rowstart, aggB);
    k_agg<<<(N_NODES + 63) / 64, 256, 0, stream>>>(aggB, WaT, cnt, avglog, out);
}

// Round 8
// 288.941 us; speedup vs baseline: 1.5696x; 1.0171x over previous
//
#include <hip/hip_runtime.h>
#include <hip/hip_bf16.h>
#include <float.h>
#include <math.h>

#define N_NODES 50000
#define N_EDGES 500000
#define D 128
#define ED 10
#define EPS_PNA 1e-5f
#define SCAN_NTILES 49     // ceil(50000 / 1024)
#define XGEMM_BLOCKS 391   // ceil(50000 / 128)
#define HIST_BLOCKS 1954   // ceil(500000 / 256)

typedef __hip_bfloat16 bf16;
typedef unsigned short ushort;
typedef unsigned int uint;
typedef __attribute__((ext_vector_type(8))) short short8;   // 8 bf16 (4 VGPRs)
typedef __attribute__((ext_vector_type(4))) float f32x4;    // MFMA C/D

__device__ __forceinline__ ushort f2bf(float f) {
    __hip_bfloat16 h = __float2bfloat16(f);
    return *reinterpret_cast<ushort*>(&h);
}
__device__ __forceinline__ float bf2f(ushort u) {
    return __uint_as_float(((uint)u) << 16);
}

// ---------------- K2a: per-tile reduce (sum + logsum), 1024 nodes/tile ----------------
__global__ __launch_bounds__(256) void k_scanA(const int* __restrict__ cnt,
                                               int* __restrict__ bsum,
                                               float* __restrict__ blog) {
    const int t = threadIdx.x;
    const int base = blockIdx.x * 1024;
    int s = 0; float ls = 0.f;
    #pragma unroll
    for (int k = 0; k < 4; ++k) {
        const int idx = base + t + k * 256;
        if (idx < N_NODES) {
            const int c = cnt[idx];
            s += c;
            ls += logf((float)c + 1.0f);
        }
    }
    #pragma unroll
    for (int off = 32; off > 0; off >>= 1) {
        s += __shfl_down(s, off, 64);
        ls += __shfl_down(ls, off, 64);
    }
    __shared__ int ws[4]; __shared__ float wl[4];
    const int wv = t >> 6, l = t & 63;
    if (l == 0) { ws[wv] = s; wl[wv] = ls; }
    __syncthreads();
    if (t == 0) {
        bsum[blockIdx.x] = ws[0] + ws[1] + ws[2] + ws[3];
        blog[blockIdx.x] = wl[0] + wl[1] + wl[2] + wl[3];
    }
}

// ---------------- K2c: per-tile scan; each block re-scans the 49 tile sums locally ----
__global__ __launch_bounds__(256) void k_scanC(const int* __restrict__ cnt,
                                               const int* __restrict__ bsum,
                                               const float* __restrict__ blog,
                                               int* __restrict__ rowstart,
                                               int* __restrict__ cursor,
                                               float* __restrict__ avglog) {
    const int t = threadIdx.x, lane = t & 63, wv = t >> 6;
    __shared__ int sboff;
    if (t < 64) {
        const int v = (t < SCAN_NTILES) ? bsum[t] : 0;
        int s = v;
        #pragma unroll
        for (int off = 1; off < 64; off <<= 1) {
            const int u = __shfl_up(s, off, 64);
            if (t >= off) s += u;
        }
        if (t == blockIdx.x) sboff = s - v;                    // exclusive prefix
        if (blockIdx.x == 0 && t == SCAN_NTILES - 1)
            rowstart[N_NODES] = s;                             // grand total
        if (blockIdx.x == 0) {
            float lg = (t < SCAN_NTILES) ? blog[t] : 0.f;
            #pragma unroll
            for (int off = 32; off > 0; off >>= 1) lg += __shfl_down(lg, off, 64);
            if (t == 0) avglog[0] = lg * (1.0f / (float)N_NODES);
        }
    }
    const int base = blockIdx.x * 1024;
    int c[4]; int ts = 0;
    #pragma unroll
    for (int k = 0; k < 4; ++k) {
        const int idx = base + t * 4 + k;
        c[k] = (idx < N_NODES) ? cnt[idx] : 0;
        ts += c[k];
    }
    int s = ts;
    #pragma unroll
    for (int off = 1; off < 64; off <<= 1) {
        const int u = __shfl_up(s, off, 64);
        if (lane >= off) s += u;
    }
    __shared__ int wtot[4], woff[4];
    if (lane == 63) wtot[wv] = s;
    __syncthreads();
    if (t == 0) {
        int r = 0;
        #pragma unroll
        for (int i = 0; i < 4; ++i) { woff[i] = r; r += wtot[i]; }
    }
    __syncthreads();
    int excl = sboff + woff[wv] + (s - ts);
    #pragma unroll
    for (int k = 0; k < 4; ++k) {
        const int idx = base + t * 4 + k;
        if (idx < N_NODES) { rowstart[idx] = excl; cursor[idx] = excl; }
        excl += c[k];
    }
}

// ---------------- K3: bucket edges into CSR order as 48B self-contained records ----
__global__ void k_scatter(const int* __restrict__ ei, const float* __restrict__ eattr,
                          int* __restrict__ cursor, uint4* __restrict__ csr_rec) {
    int e = blockIdx.x * blockDim.x + threadIdx.x;
    if (e < N_EDGES) {
        const int dst = ei[N_EDGES + e];
        const int src = ei[e];
        const float2* ea2 = (const float2*)(eattr + (size_t)e * ED);
        const float2 a0 = ea2[0], a1 = ea2[1], a2 = ea2[2], a3 = ea2[3], a4 = ea2[4];
        const int pos = atomicAdd(&cursor[dst], 1);
        uint4* o = csr_rec + (size_t)pos * 3;
        o[0] = make_uint4(__float_as_uint(a0.x), __float_as_uint(a0.y),
                          __float_as_uint(a1.x), __float_as_uint(a1.y));
        o[1] = make_uint4(__float_as_uint(a2.x), __float_as_uint(a2.y),
                          __float_as_uint(a3.x), __float_as_uint(a3.y));
        o[2] = make_uint4(__float_as_uint(a4.x), __float_as_uint(a4.y), (uint)src, 0u);
    }
}

// ---------------- K_wprep: fused weight-prep + cnt-init (role-dispatched by blockIdx) ----
__global__ __launch_bounds__(256) void k_wprep(
    const float* __restrict__ Wee, const float* __restrict__ bee,
    const float* __restrict__ Wpre, const float* __restrict__ bpre,
    const float* __restrict__ Wpost, const float* __restrict__ bpost,
    const float* __restrict__ Wlin, const float* __restrict__ blin,
    float* __restrict__ W4, float* __restrict__ bp,
    ushort* __restrict__ WxT,     // [384][128]
    ushort* __restrict__ WaT,     // [384][512]
    float* __restrict__ b_comb,
    int* __restrict__ cnt)
{
    __shared__ float smem[128 * 128];   // 64 KB, aliased per role
    const int t = threadIdx.x;
    const int bx = blockIdx.x;

    if (bx < 104) {
        float* Wl = smem;
        for (int i = t; i < 128 * 128 / 4; i += 256)
            ((float4*)Wl)[i] = ((const float4*)Wlin)[i];
        __syncthreads();
        const int j = t & 127, rp = t >> 7;
        const int kr0 = bx * 16 + rp * 8;
        for (int r = 0; r < 8; ++r) {
            const int kr = kr0 + r;
            const float* wrow = Wpost + (size_t)kr * 128;
            float acc = 0.f;
            #pragma unroll 8
            for (int m = 0; m < 128; ++m) acc += wrow[m] * Wl[m * 128 + j];
            const ushort v = f2bf(acc);
            if (kr < 128)       WxT[(256 + j) * 128 + kr] = v;
            else if (kr < 640)  WaT[(size_t)j * 512 + (kr - 128)] = v;
            else if (kr < 1152) WaT[(size_t)(128 + j) * 512 + (kr - 640)] = v;
            else                WaT[(size_t)(256 + j) * 512 + (kr - 1152)] = v;
        }
        if (bx == 0 && t < 128) {
            float acc = 0.f;
            #pragma unroll 8
            for (int m = 0; m < 128; ++m) acc += bpost[m] * Wl[m * 128 + t];
            b_comb[t] = acc + blin[t];
        }
    } else if (bx == 104) {
        float* wee_s = smem;                 // ED*D
        float* bee_s = smem + ED * D;        // D
        for (int i = t; i < ED * D; i += 256) wee_s[i] = Wee[i];
        if (t < 128) bee_s[t] = bee[t];
        __syncthreads();
        if (t < 128) {
            float acc[ED];
            #pragma unroll
            for (int r = 0; r < ED; ++r) acc[r] = 0.f;
            float bacc = 0.f;
            for (int k = 0; k < D; ++k) {
                const float w3 = Wpre[(size_t)(2 * D + k) * D + t];
                #pragma unroll
                for (int r = 0; r < ED; ++r) acc[r] += wee_s[r * D + k] * w3;
                bacc += bee_s[k] * w3;
            }
            #pragma unroll
            for (int r = 0; r < ED; ++r) W4[r * D + t] = acc[r];
            bp[t] = bpre[t] + bacc;
        }
    } else if (bx < 121) {
        const int slice = (bx < 113) ? 0 : 1;
        const int id = (bx - (slice ? 113 : 105)) * 256 + t;   // 0..2047
        const float* src = Wpre + (size_t)slice * 128 * 128;
        ushort* dst = WxT + (size_t)slice * 128 * 128;
        const int col = id & 127;
        const int k0 = (id >> 7) * 8;
        ushort tmp[8];
        #pragma unroll
        for (int r = 0; r < 8; ++r) tmp[r] = f2bf(src[(size_t)(k0 + r) * 128 + col]);
        *(uint4*)(dst + (size_t)col * 128 + k0) = *(uint4*)tmp;
    } else {
        const int i = (bx - 121) * 256 + t;
        if (i < N_NODES) cnt[i] = 0;
    }
}

// ---------------- K_hx: fused hist + xgemm (both depend only on k_wprep) -------------
__global__ __launch_bounds__(256) void k_hx(
    const int* __restrict__ ei, int* __restrict__ cnt,
    const float* __restrict__ x, const ushort* __restrict__ WxT,
    const float* __restrict__ b_comb,
    ushort* __restrict__ Y1b, ushort* __restrict__ Y2b, float* __restrict__ out)
{
    const int t = threadIdx.x;
    if (blockIdx.x >= XGEMM_BLOCKS) {
        const int e = (blockIdx.x - XGEMM_BLOCKS) * 256 + t;
        if (e < N_EDGES) atomicAdd(&cnt[ei[N_EDGES + e]], 1);
        return;
    }

    __shared__ __align__(16) ushort Alds[128 * 136];
    __shared__ __align__(16) ushort Hlds[128 * 136];
    const int nb = blockIdx.x * 128;

    #pragma unroll
    for (int g = 0; g < 8; ++g) {
        const int idx = t + g * 256;
        const int row = idx >> 4, kk = (idx & 15) * 8;
        const int node = nb + row;
        uint4 v = make_uint4(0u, 0u, 0u, 0u);
        if (node < N_NODES) {
            const float4 f0 = *(const float4*)(x + (size_t)node * 128 + kk);
            const float4 f1 = *(const float4*)(x + (size_t)node * 128 + kk + 4);
            __hip_bfloat162 p0 = __float22bfloat162_rn(make_float2(f0.x, f0.y));
            __hip_bfloat162 p1 = __float22bfloat162_rn(make_float2(f0.z, f0.w));
            __hip_bfloat162 p2 = __float22bfloat162_rn(make_float2(f1.x, f1.y));
            __hip_bfloat162 p3 = __float22bfloat162_rn(make_float2(f1.z, f1.w));
            v.x = *(uint*)&p0; v.y = *(uint*)&p1; v.z = *(uint*)&p2; v.w = *(uint*)&p3;
        }
        *(uint4*)&Hlds[row * 136 + kk] = v;
    }

    const int w = t >> 6, l = t & 63;
    const int wr = w >> 1, wc = w & 1;
    const int quad = l >> 4, lr = l & 15;

    for (int sy = 0; sy < 3; ++sy) {
        __syncthreads();
        #pragma unroll
        for (int g = 0; g < 8; ++g) {
            const int idx = t + g * 256;
            const int row = idx >> 4, kk = (idx & 15) * 8;
            *(uint4*)&Alds[row * 136 + kk] =
                *(const uint4*)(WxT + ((size_t)sy * 128 + row) * 128 + kk);
        }
        __syncthreads();

        f32x4 acc[4][4];
        #pragma unroll
        for (int i = 0; i < 4; ++i)
            #pragma unroll
            for (int j = 0; j < 4; ++j) acc[i][j] = (f32x4){0.f, 0.f, 0.f, 0.f};

        #pragma unroll
        for (int s = 0; s < 4; ++s) {
            short8 av[4], bv[4];
            #pragma unroll
            for (int i = 0; i < 4; ++i)
                av[i] = *(const short8*)&Alds[(wr * 64 + i * 16 + lr) * 136 + s * 32 + quad * 8];
            #pragma unroll
            for (int j = 0; j < 4; ++j)
                bv[j] = *(const short8*)&Hlds[(wc * 64 + j * 16 + lr) * 136 + s * 32 + quad * 8];
            #pragma unroll
            for (int i = 0; i < 4; ++i)
                #pragma unroll
                for (int j = 0; j < 4; ++j)
                    acc[i][j] = __builtin_amdgcn_mfma_f32_16x16x32_bf16(av[i], bv[j], acc[i][j], 0, 0, 0);
        }

        #pragma unroll
        for (int i = 0; i < 4; ++i) {
            const int col = wr * 64 + i * 16 + quad * 4;
            #pragma unroll
            for (int j = 0; j < 4; ++j) {
                const int node = nb + wc * 64 + j * 16 + lr;
                if (node < N_NODES) {
                    const f32x4 v = acc[i][j];
                    if (sy == 2) {
                        *(float4*)(out + (size_t)node * 128 + col) =
                            make_float4(v.x + b_comb[col],     v.y + b_comb[col + 1],
                                        v.z + b_comb[col + 2], v.w + b_comb[col + 3]);
                    } else {
                        ushort* dst = (sy == 0) ? Y1b : Y2b;
                        ushort pk[4];
                        pk[0] = f2bf(v.x); pk[1] = f2bf(v.y);
                        pk[2] = f2bf(v.z); pk[3] = f2bf(v.w);
                        *(uint2*)(dst + (size_t)node * 128 + col) = *(uint2*)pk;
                    }
                }
            }
        }
    }
}

// ---------------- K8: CSR pull aggregation -> agg bf16 [N][512] ----------------
// Scalar-record structure (round 6) + W4 REGISTER-cached (this round): each lane
// owns channels (2l,2l+1) as float2 w4[10] = 20 VGPR, loaded once per wave from
// the L2-resident 5KB W4 array. No LDS in this kernel at all -> removes 10
// ds_read_b64 per edge plus the staging barrier.
__global__ __launch_bounds__(256) void k_pull(
    const uint4* __restrict__ csr_rec, const float* __restrict__ W4,
    const float* __restrict__ bp, const ushort* __restrict__ Y1b,
    const ushort* __restrict__ Y2b,
    const int* __restrict__ rowstart,
    ushort* __restrict__ aggB)
{
    const int t = threadIdx.x;
    const int wv = t >> 6, l = t & 63;
    const int n = blockIdx.x * 4 + wv;

    // per-lane W4 slice (coalesced 512B/wave loads, L2-hot)
    float2 w4[ED];
    #pragma unroll
    for (int r = 0; r < ED; ++r)
        w4[r] = *(const float2*)(W4 + r * D + 2 * l);

    const int r0 = __builtin_amdgcn_readfirstlane(rowstart[n]);
    const int r1 = __builtin_amdgcn_readfirstlane(rowstart[n + 1]);
    const int d = r1 - r0;

    float s0 = 0.f, s1 = 0.f, ss0 = 0.f, ss1 = 0.f;
    float mx0 = -FLT_MAX, mx1 = -FLT_MAX, mn0 = FLT_MAX, mn1 = FLT_MAX;
    const __hip_bfloat162* Y2p = (const __hip_bfloat162*)Y2b;

    uint4 ra, rb, rc;
    if (d > 0) {
        const uint4* rp = csr_rec + (size_t)r0 * 3;
        ra = rp[0]; rb = rp[1]; rc = rp[2];
    }
    for (int i = r0; i < r1; ++i) {
        const int inext = (i + 1 < r1) ? (i + 1) : i;   // uniform, branchless clamp
        const uint4* rp = csr_rec + (size_t)inext * 3;
        const uint4 na = rp[0], nb4 = rp[1], nc = rp[2];

        const int src = (int)rc.z;                       // uniform -> scalar row base
        const float2 y2 = __bfloat1622float2(Y2p[(size_t)src * 64 + l]);

        float ea[10];
        ea[0] = __uint_as_float(ra.x); ea[1] = __uint_as_float(ra.y);
        ea[2] = __uint_as_float(ra.z); ea[3] = __uint_as_float(ra.w);
        ea[4] = __uint_as_float(rb.x); ea[5] = __uint_as_float(rb.y);
        ea[6] = __uint_as_float(rb.z); ea[7] = __uint_as_float(rb.w);
        ea[8] = __uint_as_float(rc.x); ea[9] = __uint_as_float(rc.y);

        float q0 = 0.f, q1 = 0.f;
        #pragma unroll
        for (int r = 0; r < ED; ++r) {
            q0 += ea[r] * w4[r].x;      // v_fmac: 1 SGPR (ea) + 1 VGPR (w4) - legal
            q1 += ea[r] * w4[r].y;
        }
        const float z0 = y2.x + q0, z1 = y2.y + q1;
        s0 += z0; s1 += z1;
        ss0 += z0 * z0; ss1 += z1 * z1;
        mx0 = fmaxf(mx0, z0); mx1 = fmaxf(mx1, z1);
        mn0 = fminf(mn0, z0); mn1 = fminf(mn1, z1);

        ra = na; rb = nb4; rc = nc;
    }

    const float2 bpw = ((const float2*)bp)[l];
    const float2 y1 = __bfloat1622float2(((const __hip_bfloat162*)Y1b)[(size_t)n * 64 + l]);
    float mean0, mean1, vmx0, vmx1, vmn0, vmn1, st0, st1;
    if (d > 0) {
        const float inv = 1.f / (float)d;
        const float mz0 = s0 * inv, mz1 = s1 * inv;
        const float c0 = y1.x + bpw.x, c1 = y1.y + bpw.y;
        mean0 = mz0 + c0; mean1 = mz1 + c1;
        st0 = sqrtf(fmaxf(ss0 * inv - mz0 * mz0, 0.f) + EPS_PNA);
        st1 = sqrtf(fmaxf(ss1 * inv - mz1 * mz1, 0.f) + EPS_PNA);
        vmx0 = mx0 + c0; vmx1 = mx1 + c1;
        vmn0 = mn0 + c0; vmn1 = mn1 + c1;
    } else {
        mean0 = mean1 = 0.f;
        vmx0 = vmx1 = vmn0 = vmn1 = 0.f;
        st0 = st1 = sqrtf(EPS_PNA);
    }
    __hip_bfloat162* aggv = (__hip_bfloat162*)aggB;
    const size_t b0 = (size_t)n * 256;
    aggv[b0 + l]       = __float22bfloat162_rn(make_float2(mean0, mean1));
    aggv[b0 + 64 + l]  = __float22bfloat162_rn(make_float2(vmx0, vmx1));
    aggv[b0 + 128 + l] = __float22bfloat162_rn(make_float2(vmn0, vmn1));
    aggv[b0 + 192 + l] = __float22bfloat162_rn(make_float2(st0, st1));
}

// ---------------- K9: MFMA agg-GEMM v2 (round-7 proven) ---------------------------
__global__ __launch_bounds__(256) void k_agg(
    const ushort* __restrict__ aggB,  // [N][512] bf16
    const ushort* __restrict__ WaT,   // [384][512] bf16
    const int* __restrict__ cnt, const float* __restrict__ avglog,
    float* __restrict__ out)
{
    __shared__ __align__(16) ushort Alds[3][128 * 72];   // 55.3 KB
    __shared__ __align__(16) ushort Hlds[64 * 72];       //  9.2 KB
    __shared__ float r1s[64], r2s[64];

    const int t = threadIdx.x;
    const int nb = blockIdx.x * 64;
    if (t < 64) {
        const int node = nb + t;
        float deg = 1.f;
        if (node < N_NODES) deg = fmaxf((float)cnt[node], 1.f);
        const float sl = logf(deg + 1.f);
        const float al = avglog[0];
        r1s[t] = sl / al;
        r2s[t] = al / sl;
    }

    const int w = t >> 6, l = t & 63;
    const int wr = w >> 1, wc = w & 1;   // wr: col half (64), wc: node half (32)
    const int quad = l >> 4, lr = l & 15;

    f32x4 acc[3][4][2];
    #pragma unroll
    for (int sl = 0; sl < 3; ++sl)
        #pragma unroll
        for (int i = 0; i < 4; ++i)
            #pragma unroll
            for (int j = 0; j < 2; ++j) acc[sl][i][j] = (f32x4){0.f, 0.f, 0.f, 0.f};

    for (int kc = 0; kc < 8; ++kc) {
        const int k0 = kc * 64;
        __syncthreads();                       // prior epoch's LDS reads done
        #pragma unroll
        for (int g = 0; g < 2; ++g) {          // H: 64 rows x 64 k
            const int idx = t + g * 256;
            const int row = idx >> 3, kk = (idx & 7) * 8;
            const int node = nb + row;
            uint4 v = make_uint4(0u, 0u, 0u, 0u);
            if (node < N_NODES)
                v = *(const uint4*)(aggB + (size_t)node * 512 + k0 + kk);
            *(uint4*)&Hlds[row * 72 + kk] = v;
        }
        #pragma unroll
        for (int sl = 0; sl < 3; ++sl) {       // A: 3 x (128 rows x 64 k)
            #pragma unroll
            for (int g = 0; g < 4; ++g) {
                const int idx = t + g * 256;
                const int row = idx >> 3, kk = (idx & 7) * 8;
                *(uint4*)&Alds[sl][row * 72 + kk] =
                    *(const uint4*)(WaT + ((size_t)(sl * 128 + row)) * 512 + k0 + kk);
            }
        }
        __syncthreads();                       // staged data visible
        #pragma unroll
        for (int sl = 0; sl < 3; ++sl) {
            #pragma unroll
            for (int s = 0; s < 2; ++s) {
                short8 av[4], bv[2];
                #pragma unroll
                for (int i = 0; i < 4; ++i)
                    av[i] = *(const short8*)&Alds[sl][(wr * 64 + i * 16 + lr) * 72 + s * 32 + quad * 8];
                #pragma unroll
                for (int j = 0; j < 2; ++j)
                    bv[j] = *(const short8*)&Hlds[(wc * 32 + j * 16 + lr) * 72 + s * 32 + quad * 8];
                #pragma unroll
                for (int i = 0; i < 4; ++i)
                    #pragma unroll
                    for (int j = 0; j < 2; ++j)
                        acc[sl][i][j] = __builtin_amdgcn_mfma_f32_16x16x32_bf16(av[i], bv[j], acc[sl][i][j], 0, 0, 0);
            }
        }
    }

    #pragma unroll
    for (int i = 0; i < 4; ++i) {
        const int col = wr * 64 + i * 16 + quad * 4;
        #pragma unroll
        for (int j = 0; j < 2; ++j) {
            const int node = nb + wc * 32 + j * 16 + lr;
            if (node < N_NODES) {
                const int nl = wc * 32 + j * 16 + lr;
                const float r1 = r1s[nl], r2 = r2s[nl];
                float* op = out + (size_t)node * 128 + col;
                const float4 cur = *(const float4*)op;
                const f32x4 a0 = acc[0][i][j];
                const f32x4 a1 = acc[1][i][j];
                const f32x4 a2 = acc[2][i][j];
                *(float4*)op = make_float4(
                    cur.x + a0.x + r1 * a1.x + r2 * a2.x,
                    cur.y + a0.y + r1 * a1.y + r2 * a2.y,
                    cur.z + a0.z + r1 * a1.z + r2 * a2.z,
                    cur.w + a0.w + r1 * a1.w + r2 * a2.w);
            }
        }
    }
}

extern "C" void kernel_launch(void* const* d_in, const int* in_sizes, int n_in,
                              void* d_out, int out_size, void* d_ws, size_t ws_size,
                              hipStream_t stream) {
    const float* x     = (const float*)d_in[0];
    const float* eattr = (const float*)d_in[1];
    const float* Wee   = (const float*)d_in[2];
    const float* bee   = (const float*)d_in[3];
    const float* Wpre  = (const float*)d_in[4];
    const float* bpre  = (const float*)d_in[5];
    const float* Wpost = (const float*)d_in[6];
    const float* bpost = (const float*)d_in[7];
    const float* Wlin  = (const float*)d_in[8];
    const float* blin  = (const float*)d_in[9];
    const int*   ei    = (const int*)d_in[10];
    float* out = (float*)d_out;

    // workspace layout (~101.9 MB; ws_size >= 102.6 MB proven previously)
    ushort* aggB = (ushort*)d_ws;                         // N*512 bf16 (51.2 MB)
    ushort* Y1b  = aggB + (size_t)N_NODES * 512;          // N*128 bf16 (12.8 MB)
    ushort* Y2b  = Y1b  + (size_t)N_NODES * 128;          // N*128 bf16 (12.8 MB)
    ushort* WxT  = Y2b  + (size_t)N_NODES * 128;          // 384*128 bf16
    ushort* WaT  = WxT + 384 * 128;                       // 384*512 bf16
    float*  W4   = (float*)(WaT + 384 * 512);             // ED*D fp32
    float*  bp   = W4 + ED * D;                           // 128
    float*  b_comb = bp + D;                              // 128
    float*  avglog = b_comb + D;                          // 1 (+3 pad)
    int*   cnt      = (int*)(avglog + 4);                 // 50000
    int*   rowstart = cnt + N_NODES;                      // 50001 (+3 pad)
    int*   cursor   = rowstart + N_NODES + 4;             // 50000
    uint4* csr_rec  = (uint4*)(cursor + N_NODES);         // E*48B (24.0 MB), 16B-aligned
    int*   bsum     = (int*)(csr_rec + (size_t)N_EDGES * 3);  // 49
    float* blog     = (float*)(bsum + 64);                // 49

    k_wprep<<<317, 256, 0, stream>>>(Wee, bee, Wpre, bpre, Wpost, bpost, Wlin, blin,
                                     W4, bp, WxT, WaT, b_comb, cnt);
    k_hx<<<XGEMM_BLOCKS + HIST_BLOCKS, 256, 0, stream>>>(ei, cnt, x, WxT, b_comb,
                                                         Y1b, Y2b, out);
    k_scanA<<<SCAN_NTILES, 256, 0, stream>>>(cnt, bsum, blog);
    k_scanC<<<SCAN_NTILES, 256, 0, stream>>>(cnt, bsum, blog, rowstart, cursor, avglog);
    k_scatter<<<(N_EDGES + 255) / 256, 256, 0, stream>>>(ei, eattr, cursor, csr_rec);
    k_pull<<<N_NODES / 4, 256, 0, stream>>>(csr_rec, W4, bp, Y1b, Y2b,
                                            rowstart, aggB);
    k_agg<<<(N_NODES + 63) / 64, 256, 0, stream>>>(aggB, WaT, cnt, avglog, out);
}